// Round 1
// baseline (862.401 us; speedup 1.0000x reference)
//
#include <hip/hip_runtime.h>
#include <math.h>

#define NN 50000
#define NE 800000
#define ET (NE + NN)
#define FIN 128
#define HEADS 8
#define HID 32
#define C1 (HEADS * HID)   // 256
#define NG 64
#define NEG 0.2f

__device__ __forceinline__ float lrelu(float v) { return v > 0.f ? v : NEG * v; }
__device__ __forceinline__ float elu1(float v)  { return v > 0.f ? v : expm1f(v); }

// ---------------- CSR build ----------------
__global__ void hist_kernel(const int* __restrict__ ei, int* __restrict__ cnt) {
    int i = blockIdx.x * 256 + threadIdx.x;
    if (i >= ET) return;
    int d = (i < NE) ? ei[NE + i] : (i - NE);
    atomicAdd(&cnt[d], 1);
}

__global__ __launch_bounds__(1024) void scan_kernel(const int* __restrict__ cnt,
                                                    int* __restrict__ rowptr) {
    __shared__ int wsum[16];
    __shared__ int carry_s;
    int t = threadIdx.x, lane = t & 63, w = t >> 6;
    if (t == 0) carry_s = 0;
    __syncthreads();
    for (int base = 0; base < NN; base += 4096) {
        int idx = base + t * 4;
        int a0 = (idx + 0 < NN) ? cnt[idx + 0] : 0;
        int a1 = (idx + 1 < NN) ? cnt[idx + 1] : 0;
        int a2 = (idx + 2 < NN) ? cnt[idx + 2] : 0;
        int a3 = (idx + 3 < NN) ? cnt[idx + 3] : 0;
        int v = a0 + a1 + a2 + a3;
        int inc = v;
        #pragma unroll
        for (int off = 1; off < 64; off <<= 1) {
            int u = __shfl_up(inc, off, 64);
            if (lane >= off) inc += u;
        }
        if (lane == 63) wsum[w] = inc;
        __syncthreads();
        int woff = 0, total = 0;
        #pragma unroll
        for (int i = 0; i < 16; ++i) {
            if (i < w) woff += wsum[i];
            total += wsum[i];
        }
        int excl = carry_s + woff + (inc - v);
        if (idx + 0 < NN) rowptr[idx + 0] = excl;
        if (idx + 1 < NN) rowptr[idx + 1] = excl + a0;
        if (idx + 2 < NN) rowptr[idx + 2] = excl + a0 + a1;
        if (idx + 3 < NN) rowptr[idx + 3] = excl + a0 + a1 + a2;
        __syncthreads();
        if (t == 0) carry_s += total;
        __syncthreads();
    }
    if (t == 0) rowptr[NN] = carry_s;
}

__global__ void scatter_kernel(const int* __restrict__ ei, int* __restrict__ cursor,
                               int* __restrict__ ssrc) {
    int i = blockIdx.x * 256 + threadIdx.x;
    if (i >= ET) return;
    int s, d;
    if (i < NE) { s = ei[i]; d = ei[NE + i]; }
    else        { s = i - NE; d = s; }
    int pos = atomicAdd(&cursor[d], 1);
    ssrc[pos] = s;
}

// ---------------- GEMM1: h1 = x @ W1, fused a_src1/a_dst1 ----------------
// block = 256 threads, 32 nodes/block, full 256 cols.
// thread: tn = t>>5 (4 nodes), tc = t&31 (8 cols)
__global__ __launch_bounds__(256) void gemm1_kernel(
        const float* __restrict__ x, const float* __restrict__ W1,
        const float* __restrict__ attS, const float* __restrict__ attD,
        float* __restrict__ h1, float* __restrict__ aS, float* __restrict__ aD) {
    __shared__ float xs[32 * FIN];   // 16 KB
    __shared__ float ws[32 * C1];    // 32 KB (one K-chunk of W1)
    int t = threadIdx.x;
    int n0 = blockIdx.x * 32;
    // stage x rows
    {
        int f = t * 16, r = f >> 7, c = f & 127;
        float4* d4 = (float4*)(xs + r * FIN + c);
        if (n0 + r < NN) {
            const float4* xr = (const float4*)(x + (size_t)(n0 + r) * FIN + c);
            d4[0] = xr[0]; d4[1] = xr[1]; d4[2] = xr[2]; d4[3] = xr[3];
        } else {
            float4 z = make_float4(0.f, 0.f, 0.f, 0.f);
            d4[0] = z; d4[1] = z; d4[2] = z; d4[3] = z;
        }
    }
    int tc = t & 31, tn = t >> 5;
    float acc[4][8];
    #pragma unroll
    for (int i = 0; i < 4; ++i)
        #pragma unroll
        for (int j = 0; j < 8; ++j) acc[i][j] = 0.f;

    for (int kb = 0; kb < 4; ++kb) {
        __syncthreads();
        {   // stage 32 rows of W1: 8192 floats = 2048 float4, 8 per thread
            const float4* w4 = (const float4*)(W1 + kb * 32 * C1);
            float4* s4 = (float4*)ws;
            #pragma unroll
            for (int i = 0; i < 8; ++i) s4[t + i * 256] = w4[t + i * 256];
        }
        __syncthreads();
        for (int k = 0; k < 32; ++k) {
            float4 w0 = *(const float4*)&ws[k * C1 + tc * 8];
            float4 w1 = *(const float4*)&ws[k * C1 + tc * 8 + 4];
            #pragma unroll
            for (int i = 0; i < 4; ++i) {
                float xv = xs[(tn * 4 + i) * FIN + kb * 32 + k];
                acc[i][0] += xv * w0.x; acc[i][1] += xv * w0.y;
                acc[i][2] += xv * w0.z; acc[i][3] += xv * w0.w;
                acc[i][4] += xv * w1.x; acc[i][5] += xv * w1.y;
                acc[i][6] += xv * w1.z; acc[i][7] += xv * w1.w;
            }
        }
    }
    // epilogue: store h1, fused attention partial dots
    float as_[8], ad_[8];
    #pragma unroll
    for (int j = 0; j < 8; ++j) { as_[j] = attS[tc * 8 + j]; ad_[j] = attD[tc * 8 + j]; }
    int h = tc >> 2;
    #pragma unroll
    for (int i = 0; i < 4; ++i) {
        int n = n0 + tn * 4 + i;
        float ps = 0.f, pd = 0.f;
        #pragma unroll
        for (int j = 0; j < 8; ++j) { ps += acc[i][j] * as_[j]; pd += acc[i][j] * ad_[j]; }
        ps += __shfl_xor(ps, 1, 64); ps += __shfl_xor(ps, 2, 64);
        pd += __shfl_xor(pd, 1, 64); pd += __shfl_xor(pd, 2, 64);
        if (n < NN) {
            *(float4*)&h1[(size_t)n * C1 + tc * 8]     =
                make_float4(acc[i][0], acc[i][1], acc[i][2], acc[i][3]);
            *(float4*)&h1[(size_t)n * C1 + tc * 8 + 4] =
                make_float4(acc[i][4], acc[i][5], acc[i][6], acc[i][7]);
            if ((tc & 3) == 0) { aS[n * HEADS + h] = ps; aD[n * HEADS + h] = pd; }
        }
    }
}

// ---------------- Layer-1 aggregation: one wave per dst node ----------------
__global__ __launch_bounds__(256) void agg1_kernel(
        const int* __restrict__ rowptr, const int* __restrict__ ssrc,
        const float* __restrict__ aS, const float* __restrict__ aD,
        const float* __restrict__ h1, const float* __restrict__ b1,
        float* __restrict__ z1) {
    int gt = blockIdx.x * 256 + threadIdx.x;
    int d = gt >> 6;
    int lane = threadIdx.x & 63;
    if (d >= NN) return;
    int start = rowptr[d], end = rowptr[d + 1];
    float ad[HEADS], den[HEADS];
    #pragma unroll
    for (int h = 0; h < HEADS; ++h) { ad[h] = aD[d * HEADS + h]; den[h] = 0.f; }
    // pass 1: softmax denominator (no max-subtraction; e is O(1))
    for (int j = start + lane; j < end; j += 64) {
        int s = ssrc[j];
        #pragma unroll
        for (int h = 0; h < HEADS; ++h)
            den[h] += __expf(lrelu(aS[s * HEADS + h] + ad[h]));
    }
    #pragma unroll
    for (int h = 0; h < HEADS; ++h) {
        float v = den[h];
        #pragma unroll
        for (int off = 32; off; off >>= 1) v += __shfl_xor(v, off, 64);
        den[h] = 1.f / (v + 1e-16f);
    }
    // pass 2: weighted gather. lane covers channels [lane*4, lane*4+4), head = lane>>3
    int hh = lane >> 3;
    float invd = den[hh], adh = ad[hh];
    float4 acc = make_float4(0.f, 0.f, 0.f, 0.f);
    for (int j = start; j < end; ++j) {
        int s = ssrc[j];
        float alpha = __expf(lrelu(aS[s * HEADS + hh] + adh)) * invd;
        float4 hv = *(const float4*)&h1[(size_t)s * C1 + lane * 4];
        acc.x += alpha * hv.x; acc.y += alpha * hv.y;
        acc.z += alpha * hv.z; acc.w += alpha * hv.w;
    }
    float4 bb = *(const float4*)&b1[lane * 4];
    float4 o;
    o.x = elu1(acc.x + bb.x); o.y = elu1(acc.y + bb.y);
    o.z = elu1(acc.z + bb.z); o.w = elu1(acc.w + bb.w);
    *(float4*)&z1[(size_t)d * C1 + lane * 4] = o;
}

// ---------------- GEMM2: h2 = z1 @ W2, fused a_src2/a_dst2 ----------------
// block = 256: 32 nodes, 8 col-threads (4 cols each). tn = t>>3, tc = t&7
__global__ __launch_bounds__(256) void gemm2_kernel(
        const float* __restrict__ z1, const float* __restrict__ W2,
        const float* __restrict__ attS, const float* __restrict__ attD,
        float* __restrict__ h2, float* __restrict__ aS2, float* __restrict__ aD2) {
    __shared__ float zs[32 * 260];   // padded stride 260 (16B-aligned rows, bank-shifted)
    __shared__ float wc[64 * HID];   // one K-chunk of W2 (8 KB)
    int t = threadIdx.x;
    int n0 = blockIdx.x * 32;
    {
        int f = t * 32, r = f >> 8, c = f & 255;
        float4* d4 = (float4*)(zs + r * 260 + c);
        if (n0 + r < NN) {
            const float4* zr = (const float4*)(z1 + (size_t)(n0 + r) * C1 + c);
            #pragma unroll
            for (int i = 0; i < 8; ++i) d4[i] = zr[i];
        } else {
            float4 z = make_float4(0.f, 0.f, 0.f, 0.f);
            #pragma unroll
            for (int i = 0; i < 8; ++i) d4[i] = z;
        }
    }
    int tn = t >> 3, tc = t & 7;
    float acc[4] = {0.f, 0.f, 0.f, 0.f};
    for (int kb = 0; kb < 4; ++kb) {
        __syncthreads();
        {
            const float4* w4 = (const float4*)(W2 + kb * 64 * HID);
            float4* s4 = (float4*)wc;
            s4[t] = w4[t]; s4[t + 256] = w4[t + 256];
        }
        __syncthreads();
        for (int k = 0; k < 64; ++k) {
            float zv = zs[tn * 260 + kb * 64 + k];
            float4 w = *(const float4*)&wc[k * HID + tc * 4];
            acc[0] += zv * w.x; acc[1] += zv * w.y;
            acc[2] += zv * w.z; acc[3] += zv * w.w;
        }
    }
    int n = n0 + tn;
    float ps = 0.f, pd = 0.f;
    #pragma unroll
    for (int j = 0; j < 4; ++j) { ps += acc[j] * attS[tc * 4 + j]; pd += acc[j] * attD[tc * 4 + j]; }
    ps += __shfl_xor(ps, 1, 64); ps += __shfl_xor(ps, 2, 64); ps += __shfl_xor(ps, 4, 64);
    pd += __shfl_xor(pd, 1, 64); pd += __shfl_xor(pd, 2, 64); pd += __shfl_xor(pd, 4, 64);
    if (n < NN) {
        *(float4*)&h2[(size_t)n * HID + tc * 4] = make_float4(acc[0], acc[1], acc[2], acc[3]);
        if (tc == 0) { aS2[n] = ps; aD2[n] = pd; }
    }
}

// ---------------- Layer-2 aggregation + fused mean-pool accumulate ----------------
__global__ __launch_bounds__(256) void agg2_kernel(
        const int* __restrict__ rowptr, const int* __restrict__ ssrc,
        const float* __restrict__ aS, const float* __restrict__ aD,
        const float* __restrict__ h2, const float* __restrict__ b2,
        const int* __restrict__ batch, float* __restrict__ pooled,
        float* __restrict__ gcnt) {
    int gt = blockIdx.x * 256 + threadIdx.x;
    int d = gt >> 6;
    int lane = threadIdx.x & 63;
    if (d >= NN) return;
    int start = rowptr[d], end = rowptr[d + 1];
    float adv = aD[d];
    float den = 0.f;
    for (int j = start + lane; j < end; j += 64)
        den += __expf(lrelu(aS[ssrc[j]] + adv));
    #pragma unroll
    for (int off = 32; off; off >>= 1) den += __shfl_xor(den, off, 64);
    float invd = 1.f / (den + 1e-16f);
    if (lane < HID) {
        float acc = 0.f;
        for (int j = start; j < end; ++j) {
            int s = ssrc[j];
            float alpha = __expf(lrelu(aS[s] + adv)) * invd;
            acc += alpha * h2[(size_t)s * HID + lane];
        }
        float z = elu1(acc + b2[lane]);
        int g = batch[d];
        atomicAdd(&pooled[g * HID + lane], z);
        if (lane == 0) atomicAdd(&gcnt[g], 1.f);
    }
}

// ---------------- Final: mean + Wo + sigmoid ----------------
__global__ void final_kernel(const float* __restrict__ pooled, const float* __restrict__ gcnt,
                             const float* __restrict__ Wo, const float* __restrict__ bo,
                             float* __restrict__ out) {
    int g = threadIdx.x;
    if (g >= NG) return;
    float c = fmaxf(gcnt[g], 1.f);
    float acc = 0.f;
    for (int i = 0; i < HID; ++i) acc += (pooled[g * HID + i] / c) * Wo[i];
    acc += bo[0];
    out[g] = 1.f / (1.f + __expf(-acc));
}

extern "C" void kernel_launch(void* const* d_in, const int* in_sizes, int n_in,
                              void* d_out, int out_size, void* d_ws, size_t ws_size,
                              hipStream_t stream) {
    const float* x     = (const float*)d_in[0];
    const int*   ei    = (const int*)d_in[1];
    const int*   batch = (const int*)d_in[2];
    const float* W1    = (const float*)d_in[3];
    const float* attS1 = (const float*)d_in[4];
    const float* attD1 = (const float*)d_in[5];
    const float* b1    = (const float*)d_in[6];
    const float* W2    = (const float*)d_in[7];
    const float* attS2 = (const float*)d_in[8];
    const float* attD2 = (const float*)d_in[9];
    const float* b2    = (const float*)d_in[10];
    const float* Wo    = (const float*)d_in[11];
    const float* bo    = (const float*)d_in[12];
    float* out = (float*)d_out;

    char* p = (char*)d_ws;
    auto alloc = [&](size_t bytes) {
        char* r = p;
        p += (bytes + 255) & ~(size_t)255;
        return (void*)r;
    };
    float* h1     = (float*)alloc((size_t)NN * C1 * 4);
    float* z1     = (float*)alloc((size_t)NN * C1 * 4);
    float* aS1    = (float*)alloc((size_t)NN * HEADS * 4);
    float* aD1    = (float*)alloc((size_t)NN * HEADS * 4);
    float* h2     = (float*)alloc((size_t)NN * HID * 4);
    float* aS2    = (float*)alloc((size_t)NN * 4);
    float* aD2    = (float*)alloc((size_t)NN * 4);
    int*   rowptr = (int*)alloc((size_t)(NN + 1) * 4);
    int*   cursor = (int*)alloc((size_t)NN * 4);
    int*   ssrc   = (int*)alloc((size_t)ET * 4);
    // zero-init region: cnt + pooled + gcnt (contiguous)
    int*   cnt    = (int*)alloc((size_t)NN * 4);
    float* pooled = (float*)alloc((size_t)NG * HID * 4);
    float* gcnt   = (float*)alloc((size_t)NG * 4);
    size_t zero_bytes = (size_t)(p - (char*)cnt);

    hipMemsetAsync(cnt, 0, zero_bytes, stream);
    hist_kernel<<<(ET + 255) / 256, 256, 0, stream>>>(ei, cnt);
    scan_kernel<<<1, 1024, 0, stream>>>(cnt, rowptr);
    hipMemcpyAsync(cursor, rowptr, (size_t)NN * 4, hipMemcpyDeviceToDevice, stream);
    scatter_kernel<<<(ET + 255) / 256, 256, 0, stream>>>(ei, cursor, ssrc);
    gemm1_kernel<<<(NN + 31) / 32, 256, 0, stream>>>(x, W1, attS1, attD1, h1, aS1, aD1);
    agg1_kernel<<<(NN * 64) / 256, 256, 0, stream>>>(rowptr, ssrc, aS1, aD1, h1, b1, z1);
    gemm2_kernel<<<(NN + 31) / 32, 256, 0, stream>>>(z1, W2, attS2, attD2, h2, aS2, aD2);
    agg2_kernel<<<(NN * 64) / 256, 256, 0, stream>>>(rowptr, ssrc, aS2, aD2, h2, b2,
                                                     batch, pooled, gcnt);
    final_kernel<<<1, 64, 0, stream>>>(pooled, gcnt, Wo, bo, out);
}

// Round 2
// 509.039 us; speedup vs baseline: 1.6942x; 1.6942x over previous
//
#include <hip/hip_runtime.h>
#include <math.h>

#define NN 50000
#define NE 800000
#define ET (NE + NN)
#define FIN 128
#define HEADS 8
#define HID 32
#define C1 (HEADS * HID)   // 256
#define NG 64
#define NEG 0.2f

__device__ __forceinline__ float lrelu(float v) { return v > 0.f ? v : NEG * v; }
__device__ __forceinline__ float elu1(float v)  { return v > 0.f ? v : expm1f(v); }

// ---------------- CSR build ----------------
__global__ void hist_kernel(const int* __restrict__ ei, int* __restrict__ cnt) {
    int i = blockIdx.x * 256 + threadIdx.x;
    if (i >= ET) return;
    int d = (i < NE) ? ei[NE + i] : (i - NE);
    atomicAdd(&cnt[d], 1);
}

__global__ __launch_bounds__(1024) void scan_kernel(const int* __restrict__ cnt,
                                                    int* __restrict__ rowptr) {
    __shared__ int wsum[16];
    __shared__ int carry_s;
    int t = threadIdx.x, lane = t & 63, w = t >> 6;
    if (t == 0) carry_s = 0;
    __syncthreads();
    for (int base = 0; base < NN; base += 4096) {
        int idx = base + t * 4;
        int a0 = (idx + 0 < NN) ? cnt[idx + 0] : 0;
        int a1 = (idx + 1 < NN) ? cnt[idx + 1] : 0;
        int a2 = (idx + 2 < NN) ? cnt[idx + 2] : 0;
        int a3 = (idx + 3 < NN) ? cnt[idx + 3] : 0;
        int v = a0 + a1 + a2 + a3;
        int inc = v;
        #pragma unroll
        for (int off = 1; off < 64; off <<= 1) {
            int u = __shfl_up(inc, off, 64);
            if (lane >= off) inc += u;
        }
        if (lane == 63) wsum[w] = inc;
        __syncthreads();
        int woff = 0, total = 0;
        #pragma unroll
        for (int i = 0; i < 16; ++i) {
            if (i < w) woff += wsum[i];
            total += wsum[i];
        }
        int excl = carry_s + woff + (inc - v);
        if (idx + 0 < NN) rowptr[idx + 0] = excl;
        if (idx + 1 < NN) rowptr[idx + 1] = excl + a0;
        if (idx + 2 < NN) rowptr[idx + 2] = excl + a0 + a1;
        if (idx + 3 < NN) rowptr[idx + 3] = excl + a0 + a1 + a2;
        __syncthreads();
        if (t == 0) carry_s += total;
        __syncthreads();
    }
    if (t == 0) rowptr[NN] = carry_s;
}

__global__ void scatter_kernel(const int* __restrict__ ei, int* __restrict__ cursor,
                               int* __restrict__ ssrc) {
    int i = blockIdx.x * 256 + threadIdx.x;
    if (i >= ET) return;
    int s, d;
    if (i < NE) { s = ei[i]; d = ei[NE + i]; }
    else        { s = i - NE; d = s; }
    int pos = atomicAdd(&cursor[d], 1);
    ssrc[pos] = s;
}

// ---------------- GEMM1: h1 = x @ W1, fused a_src1/a_dst1 ----------------
__global__ __launch_bounds__(256) void gemm1_kernel(
        const float* __restrict__ x, const float* __restrict__ W1,
        const float* __restrict__ attS, const float* __restrict__ attD,
        float* __restrict__ h1, float* __restrict__ aS, float* __restrict__ aD) {
    __shared__ float xs[32 * FIN];   // 16 KB
    __shared__ float ws[32 * C1];    // 32 KB (one K-chunk of W1)
    int t = threadIdx.x;
    int n0 = blockIdx.x * 32;
    {
        int f = t * 16, r = f >> 7, c = f & 127;
        float4* d4 = (float4*)(xs + r * FIN + c);
        if (n0 + r < NN) {
            const float4* xr = (const float4*)(x + (size_t)(n0 + r) * FIN + c);
            d4[0] = xr[0]; d4[1] = xr[1]; d4[2] = xr[2]; d4[3] = xr[3];
        } else {
            float4 z = make_float4(0.f, 0.f, 0.f, 0.f);
            d4[0] = z; d4[1] = z; d4[2] = z; d4[3] = z;
        }
    }
    int tc = t & 31, tn = t >> 5;
    float acc[4][8];
    #pragma unroll
    for (int i = 0; i < 4; ++i)
        #pragma unroll
        for (int j = 0; j < 8; ++j) acc[i][j] = 0.f;

    for (int kb = 0; kb < 4; ++kb) {
        __syncthreads();
        {
            const float4* w4 = (const float4*)(W1 + kb * 32 * C1);
            float4* s4 = (float4*)ws;
            #pragma unroll
            for (int i = 0; i < 8; ++i) s4[t + i * 256] = w4[t + i * 256];
        }
        __syncthreads();
        for (int k = 0; k < 32; ++k) {
            float4 w0 = *(const float4*)&ws[k * C1 + tc * 8];
            float4 w1 = *(const float4*)&ws[k * C1 + tc * 8 + 4];
            #pragma unroll
            for (int i = 0; i < 4; ++i) {
                float xv = xs[(tn * 4 + i) * FIN + kb * 32 + k];
                acc[i][0] += xv * w0.x; acc[i][1] += xv * w0.y;
                acc[i][2] += xv * w0.z; acc[i][3] += xv * w0.w;
                acc[i][4] += xv * w1.x; acc[i][5] += xv * w1.y;
                acc[i][6] += xv * w1.z; acc[i][7] += xv * w1.w;
            }
        }
    }
    float as_[8], ad_[8];
    #pragma unroll
    for (int j = 0; j < 8; ++j) { as_[j] = attS[tc * 8 + j]; ad_[j] = attD[tc * 8 + j]; }
    int h = tc >> 2;
    #pragma unroll
    for (int i = 0; i < 4; ++i) {
        int n = n0 + tn * 4 + i;
        float ps = 0.f, pd = 0.f;
        #pragma unroll
        for (int j = 0; j < 8; ++j) { ps += acc[i][j] * as_[j]; pd += acc[i][j] * ad_[j]; }
        ps += __shfl_xor(ps, 1, 64); ps += __shfl_xor(ps, 2, 64);
        pd += __shfl_xor(pd, 1, 64); pd += __shfl_xor(pd, 2, 64);
        if (n < NN) {
            *(float4*)&h1[(size_t)n * C1 + tc * 8]     =
                make_float4(acc[i][0], acc[i][1], acc[i][2], acc[i][3]);
            *(float4*)&h1[(size_t)n * C1 + tc * 8 + 4] =
                make_float4(acc[i][4], acc[i][5], acc[i][6], acc[i][7]);
            if ((tc & 3) == 0) { aS[n * HEADS + h] = ps; aD[n * HEADS + h] = pd; }
        }
    }
}

// ---------------- Layer-1 aggregation: one wave per dst node ----------------
__global__ __launch_bounds__(256) void agg1_kernel(
        const int* __restrict__ rowptr, const int* __restrict__ ssrc,
        const float* __restrict__ aS, const float* __restrict__ aD,
        const float* __restrict__ h1, const float* __restrict__ b1,
        float* __restrict__ z1) {
    int gt = blockIdx.x * 256 + threadIdx.x;
    int d = gt >> 6;
    int lane = threadIdx.x & 63;
    if (d >= NN) return;
    int start = rowptr[d], end = rowptr[d + 1];
    float ad[HEADS], den[HEADS];
    #pragma unroll
    for (int h = 0; h < HEADS; ++h) { ad[h] = aD[d * HEADS + h]; den[h] = 0.f; }
    for (int j = start + lane; j < end; j += 64) {
        int s = ssrc[j];
        #pragma unroll
        for (int h = 0; h < HEADS; ++h)
            den[h] += __expf(lrelu(aS[s * HEADS + h] + ad[h]));
    }
    #pragma unroll
    for (int h = 0; h < HEADS; ++h) {
        float v = den[h];
        #pragma unroll
        for (int off = 32; off; off >>= 1) v += __shfl_xor(v, off, 64);
        den[h] = 1.f / (v + 1e-16f);
    }
    int hh = lane >> 3;
    float invd = den[hh], adh = ad[hh];
    float4 acc = make_float4(0.f, 0.f, 0.f, 0.f);
    for (int j = start; j < end; ++j) {
        int s = ssrc[j];
        float alpha = __expf(lrelu(aS[s * HEADS + hh] + adh)) * invd;
        float4 hv = *(const float4*)&h1[(size_t)s * C1 + lane * 4];
        acc.x += alpha * hv.x; acc.y += alpha * hv.y;
        acc.z += alpha * hv.z; acc.w += alpha * hv.w;
    }
    float4 bb = *(const float4*)&b1[lane * 4];
    float4 o;
    o.x = elu1(acc.x + bb.x); o.y = elu1(acc.y + bb.y);
    o.z = elu1(acc.z + bb.z); o.w = elu1(acc.w + bb.w);
    *(float4*)&z1[(size_t)d * C1 + lane * 4] = o;
}

// ---------------- GEMM2: h2 = z1 @ W2, fused a_src2/a_dst2 ----------------
__global__ __launch_bounds__(256) void gemm2_kernel(
        const float* __restrict__ z1, const float* __restrict__ W2,
        const float* __restrict__ attS, const float* __restrict__ attD,
        float* __restrict__ h2, float* __restrict__ aS2, float* __restrict__ aD2) {
    __shared__ float zs[32 * 260];
    __shared__ float wc[64 * HID];
    int t = threadIdx.x;
    int n0 = blockIdx.x * 32;
    {
        int f = t * 32, r = f >> 8, c = f & 255;
        float4* d4 = (float4*)(zs + r * 260 + c);
        if (n0 + r < NN) {
            const float4* zr = (const float4*)(z1 + (size_t)(n0 + r) * C1 + c);
            #pragma unroll
            for (int i = 0; i < 8; ++i) d4[i] = zr[i];
        } else {
            float4 z = make_float4(0.f, 0.f, 0.f, 0.f);
            #pragma unroll
            for (int i = 0; i < 8; ++i) d4[i] = z;
        }
    }
    int tn = t >> 3, tc = t & 7;
    float acc[4] = {0.f, 0.f, 0.f, 0.f};
    for (int kb = 0; kb < 4; ++kb) {
        __syncthreads();
        {
            const float4* w4 = (const float4*)(W2 + kb * 64 * HID);
            float4* s4 = (float4*)wc;
            s4[t] = w4[t]; s4[t + 256] = w4[t + 256];
        }
        __syncthreads();
        for (int k = 0; k < 64; ++k) {
            float zv = zs[tn * 260 + kb * 64 + k];
            float4 w = *(const float4*)&wc[k * HID + tc * 4];
            acc[0] += zv * w.x; acc[1] += zv * w.y;
            acc[2] += zv * w.z; acc[3] += zv * w.w;
        }
    }
    int n = n0 + tn;
    float ps = 0.f, pd = 0.f;
    #pragma unroll
    for (int j = 0; j < 4; ++j) { ps += acc[j] * attS[tc * 4 + j]; pd += acc[j] * attD[tc * 4 + j]; }
    ps += __shfl_xor(ps, 1, 64); ps += __shfl_xor(ps, 2, 64); ps += __shfl_xor(ps, 4, 64);
    pd += __shfl_xor(pd, 1, 64); pd += __shfl_xor(pd, 2, 64); pd += __shfl_xor(pd, 4, 64);
    if (n < NN) {
        *(float4*)&h2[(size_t)n * HID + tc * 4] = make_float4(acc[0], acc[1], acc[2], acc[3]);
        if (tc == 0) { aS2[n] = ps; aD2[n] = pd; }
    }
}

// ---------------- Layer-2 aggregation: 2 dst nodes per wave, NO atomics ----------------
__global__ __launch_bounds__(256) void agg2_kernel(
        const int* __restrict__ rowptr, const int* __restrict__ ssrc,
        const float* __restrict__ aS, const float* __restrict__ aD,
        const float* __restrict__ h2, const float* __restrict__ b2,
        float* __restrict__ z2) {
    int wid = (blockIdx.x * 256 + threadIdx.x) >> 6;   // wave id
    int lane = threadIdx.x & 63;
    int half = lane >> 5, hl = lane & 31;              // half-wave = one node
    int d = wid * 2 + half;
    if (d >= NN) return;
    int start = rowptr[d], end = rowptr[d + 1];
    float adv = aD[d];
    float den = 0.f;
    for (int j = start + hl; j < end; j += 32)
        den += __expf(lrelu(aS[ssrc[j]] + adv));
    #pragma unroll
    for (int off = 16; off; off >>= 1) den += __shfl_xor(den, off, 32);
    float invd = 1.f / (den + 1e-16f);
    // lane hl = channel hl; unroll x2 for two outstanding gather chains
    float acc = 0.f;
    int j = start;
    for (; j + 1 < end; j += 2) {
        int s0 = ssrc[j], s1 = ssrc[j + 1];
        float a0 = aS[s0], a1 = aS[s1];
        float v0 = h2[(size_t)s0 * HID + hl];
        float v1 = h2[(size_t)s1 * HID + hl];
        acc += __expf(lrelu(a0 + adv)) * v0;
        acc += __expf(lrelu(a1 + adv)) * v1;
    }
    if (j < end) {
        int s = ssrc[j];
        acc += __expf(lrelu(aS[s] + adv)) * h2[(size_t)s * HID + hl];
    }
    acc *= invd;
    z2[(size_t)d * HID + hl] = elu1(acc + b2[hl]);
}

// ---------------- Pool + Wo + sigmoid: one block per group, no atomics ----------------
__global__ __launch_bounds__(256) void pool_final_kernel(
        const float* __restrict__ z2, const int* __restrict__ batch,
        const float* __restrict__ Wo, const float* __restrict__ bo,
        float* __restrict__ out) {
    __shared__ float sm[256];
    int g = blockIdx.x;
    int t = threadIdx.x;
    // batch is sorted: binary-search group boundaries
    int lo = 0, hi = NN;
    while (lo < hi) { int mid = (lo + hi) >> 1; if (batch[mid] < g) lo = mid + 1; else hi = mid; }
    int start = lo;
    hi = NN;
    while (lo < hi) { int mid = (lo + hi) >> 1; if (batch[mid] < g + 1) lo = mid + 1; else hi = mid; }
    int end = lo;
    int c = t & 31, r = t >> 5;
    float acc = 0.f;
    for (int n = start + r; n < end; n += 8)
        acc += z2[(size_t)n * HID + c];
    sm[t] = acc;
    __syncthreads();
    if (t < 32) {
        float s = 0.f;
        #pragma unroll
        for (int i = 0; i < 8; ++i) s += sm[t + 32 * i];
        float cntf = fmaxf((float)(end - start), 1.f);
        float part = (s / cntf) * Wo[t];
        #pragma unroll
        for (int off = 16; off; off >>= 1) part += __shfl_xor(part, off, 32);
        if (t == 0) out[g] = 1.f / (1.f + __expf(-(part + bo[0])));
    }
}

extern "C" void kernel_launch(void* const* d_in, const int* in_sizes, int n_in,
                              void* d_out, int out_size, void* d_ws, size_t ws_size,
                              hipStream_t stream) {
    const float* x     = (const float*)d_in[0];
    const int*   ei    = (const int*)d_in[1];
    const int*   batch = (const int*)d_in[2];
    const float* W1    = (const float*)d_in[3];
    const float* attS1 = (const float*)d_in[4];
    const float* attD1 = (const float*)d_in[5];
    const float* b1    = (const float*)d_in[6];
    const float* W2    = (const float*)d_in[7];
    const float* attS2 = (const float*)d_in[8];
    const float* attD2 = (const float*)d_in[9];
    const float* b2    = (const float*)d_in[10];
    const float* Wo    = (const float*)d_in[11];
    const float* bo    = (const float*)d_in[12];
    float* out = (float*)d_out;

    char* p = (char*)d_ws;
    auto alloc = [&](size_t bytes) {
        char* r = p;
        p += (bytes + 255) & ~(size_t)255;
        return (void*)r;
    };
    float* h1     = (float*)alloc((size_t)NN * C1 * 4);
    float* z1     = (float*)alloc((size_t)NN * C1 * 4);
    float* aS1    = (float*)alloc((size_t)NN * HEADS * 4);
    float* aD1    = (float*)alloc((size_t)NN * HEADS * 4);
    float* h2     = (float*)alloc((size_t)NN * HID * 4);
    float* z2     = (float*)alloc((size_t)NN * HID * 4);
    float* aS2    = (float*)alloc((size_t)NN * 4);
    float* aD2    = (float*)alloc((size_t)NN * 4);
    int*   rowptr = (int*)alloc((size_t)(NN + 1) * 4);
    int*   cursor = (int*)alloc((size_t)NN * 4);
    int*   ssrc   = (int*)alloc((size_t)ET * 4);
    int*   cnt    = (int*)alloc((size_t)NN * 4);

    hipMemsetAsync(cnt, 0, (size_t)NN * 4, stream);
    hist_kernel<<<(ET + 255) / 256, 256, 0, stream>>>(ei, cnt);
    scan_kernel<<<1, 1024, 0, stream>>>(cnt, rowptr);
    hipMemcpyAsync(cursor, rowptr, (size_t)NN * 4, hipMemcpyDeviceToDevice, stream);
    scatter_kernel<<<(ET + 255) / 256, 256, 0, stream>>>(ei, cursor, ssrc);
    gemm1_kernel<<<(NN + 31) / 32, 256, 0, stream>>>(x, W1, attS1, attD1, h1, aS1, aD1);
    agg1_kernel<<<(NN * 64) / 256, 256, 0, stream>>>(rowptr, ssrc, aS1, aD1, h1, b1, z1);
    gemm2_kernel<<<(NN + 31) / 32, 256, 0, stream>>>(z1, W2, attS2, attD2, h2, aS2, aD2);
    agg2_kernel<<<(NN / 2 * 64 + 255) / 256, 256, 0, stream>>>(rowptr, ssrc, aS2, aD2, h2, b2, z2);
    pool_final_kernel<<<NG, 256, 0, stream>>>(z2, batch, Wo, bo, out);
}

// Round 3
// 445.541 us; speedup vs baseline: 1.9356x; 1.1425x over previous
//
#include <hip/hip_runtime.h>
#include <hip/hip_bf16.h>
#include <math.h>

#define NN 50000
#define NE 800000
#define ET (NE + NN)
#define FIN 128
#define HEADS 8
#define HID 32
#define C1 (HEADS * HID)   // 256
#define NG 64
#define NEG 0.2f

typedef __attribute__((ext_vector_type(8))) unsigned short ushort8_t;

__device__ __forceinline__ float lrelu(float v) { return v > 0.f ? v : NEG * v; }
__device__ __forceinline__ float elu1(float v)  { return v > 0.f ? v : expm1f(v); }
__device__ __forceinline__ unsigned short f2bf(float f) {
    __hip_bfloat16 b = __float2bfloat16(f);
    return *reinterpret_cast<unsigned short*>(&b);
}
__device__ __forceinline__ float bf2f(unsigned short u) {
    return __uint_as_float(((unsigned)u) << 16);
}

// ---------------- CSR build ----------------
__global__ void hist_kernel(const int* __restrict__ ei, int* __restrict__ cnt) {
    int i = blockIdx.x * 256 + threadIdx.x;
    if (i >= ET) return;
    int d = (i < NE) ? ei[NE + i] : (i - NE);
    atomicAdd(&cnt[d], 1);
}

__global__ __launch_bounds__(1024) void scan_kernel(const int* __restrict__ cnt,
                                                    int* __restrict__ rowptr) {
    __shared__ int wsum[16];
    __shared__ int carry_s;
    int t = threadIdx.x, lane = t & 63, w = t >> 6;
    if (t == 0) carry_s = 0;
    __syncthreads();
    for (int base = 0; base < NN; base += 4096) {
        int idx = base + t * 4;
        int a0 = (idx + 0 < NN) ? cnt[idx + 0] : 0;
        int a1 = (idx + 1 < NN) ? cnt[idx + 1] : 0;
        int a2 = (idx + 2 < NN) ? cnt[idx + 2] : 0;
        int a3 = (idx + 3 < NN) ? cnt[idx + 3] : 0;
        int v = a0 + a1 + a2 + a3;
        int inc = v;
        #pragma unroll
        for (int off = 1; off < 64; off <<= 1) {
            int u = __shfl_up(inc, off, 64);
            if (lane >= off) inc += u;
        }
        if (lane == 63) wsum[w] = inc;
        __syncthreads();
        int woff = 0, total = 0;
        #pragma unroll
        for (int i = 0; i < 16; ++i) {
            if (i < w) woff += wsum[i];
            total += wsum[i];
        }
        int excl = carry_s + woff + (inc - v);
        if (idx + 0 < NN) rowptr[idx + 0] = excl;
        if (idx + 1 < NN) rowptr[idx + 1] = excl + a0;
        if (idx + 2 < NN) rowptr[idx + 2] = excl + a0 + a1;
        if (idx + 3 < NN) rowptr[idx + 3] = excl + a0 + a1 + a2;
        __syncthreads();
        if (t == 0) carry_s += total;
        __syncthreads();
    }
    if (t == 0) rowptr[NN] = carry_s;
}

__global__ void scatter_kernel(const int* __restrict__ ei, int* __restrict__ cursor,
                               int* __restrict__ ssrc) {
    int i = blockIdx.x * 256 + threadIdx.x;
    if (i >= ET) return;
    int s, d;
    if (i < NE) { s = ei[i]; d = ei[NE + i]; }
    else        { s = i - NE; d = s; }
    int pos = atomicAdd(&cursor[d], 1);
    ssrc[pos] = s;
}

// ---------------- GEMM1: h1 = x @ W1 (bf16 out), fused a_src1/a_dst1 ----------------
__global__ __launch_bounds__(256) void gemm1_kernel(
        const float* __restrict__ x, const float* __restrict__ W1,
        const float* __restrict__ attS, const float* __restrict__ attD,
        unsigned short* __restrict__ h1b, float* __restrict__ aS, float* __restrict__ aD) {
    __shared__ float xs[32 * FIN];   // 16 KB
    __shared__ float ws[32 * C1];    // 32 KB (one K-chunk of W1)
    int t = threadIdx.x;
    int n0 = blockIdx.x * 32;
    {
        int f = t * 16, r = f >> 7, c = f & 127;
        float4* d4 = (float4*)(xs + r * FIN + c);
        if (n0 + r < NN) {
            const float4* xr = (const float4*)(x + (size_t)(n0 + r) * FIN + c);
            d4[0] = xr[0]; d4[1] = xr[1]; d4[2] = xr[2]; d4[3] = xr[3];
        } else {
            float4 z = make_float4(0.f, 0.f, 0.f, 0.f);
            d4[0] = z; d4[1] = z; d4[2] = z; d4[3] = z;
        }
    }
    int tc = t & 31, tn = t >> 5;
    float acc[4][8];
    #pragma unroll
    for (int i = 0; i < 4; ++i)
        #pragma unroll
        for (int j = 0; j < 8; ++j) acc[i][j] = 0.f;

    for (int kb = 0; kb < 4; ++kb) {
        __syncthreads();
        {
            const float4* w4 = (const float4*)(W1 + kb * 32 * C1);
            float4* s4 = (float4*)ws;
            #pragma unroll
            for (int i = 0; i < 8; ++i) s4[t + i * 256] = w4[t + i * 256];
        }
        __syncthreads();
        for (int k = 0; k < 32; ++k) {
            float4 w0 = *(const float4*)&ws[k * C1 + tc * 8];
            float4 w1 = *(const float4*)&ws[k * C1 + tc * 8 + 4];
            #pragma unroll
            for (int i = 0; i < 4; ++i) {
                float xv = xs[(tn * 4 + i) * FIN + kb * 32 + k];
                acc[i][0] += xv * w0.x; acc[i][1] += xv * w0.y;
                acc[i][2] += xv * w0.z; acc[i][3] += xv * w0.w;
                acc[i][4] += xv * w1.x; acc[i][5] += xv * w1.y;
                acc[i][6] += xv * w1.z; acc[i][7] += xv * w1.w;
            }
        }
    }
    float as_[8], ad_[8];
    #pragma unroll
    for (int j = 0; j < 8; ++j) { as_[j] = attS[tc * 8 + j]; ad_[j] = attD[tc * 8 + j]; }
    int h = tc >> 2;
    #pragma unroll
    for (int i = 0; i < 4; ++i) {
        int n = n0 + tn * 4 + i;
        float ps = 0.f, pd = 0.f;
        #pragma unroll
        for (int j = 0; j < 8; ++j) { ps += acc[i][j] * as_[j]; pd += acc[i][j] * ad_[j]; }
        ps += __shfl_xor(ps, 1, 64); ps += __shfl_xor(ps, 2, 64);
        pd += __shfl_xor(pd, 1, 64); pd += __shfl_xor(pd, 2, 64);
        if (n < NN) {
            ushort8_t hb;
            #pragma unroll
            for (int j = 0; j < 8; ++j) hb[j] = f2bf(acc[i][j]);
            *(ushort8_t*)&h1b[(size_t)n * C1 + tc * 8] = hb;
            if ((tc & 3) == 0) { aS[n * HEADS + h] = ps; aD[n * HEADS + h] = pd; }
        }
    }
}

// ---------------- Layer-1 aggregation: one wave per dst, half-wave per edge ----------------
__global__ __launch_bounds__(256) void agg1_kernel(
        const int* __restrict__ rowptr, const int* __restrict__ ssrc,
        const float* __restrict__ aS, const float* __restrict__ aD,
        const unsigned short* __restrict__ h1b, const float* __restrict__ b1,
        float* __restrict__ z1) {
    int d = (blockIdx.x * 256 + threadIdx.x) >> 6;
    int lane = threadIdx.x & 63;
    if (d >= NN) return;
    int start = rowptr[d], end = rowptr[d + 1];
    float ad[HEADS], den[HEADS];
    #pragma unroll
    for (int h = 0; h < HEADS; ++h) { ad[h] = aD[d * HEADS + h]; den[h] = 0.f; }
    // pass 1: softmax denominators (all 64 lanes stride edges)
    for (int j = start + lane; j < end; j += 64) {
        int s = ssrc[j];
        #pragma unroll
        for (int h = 0; h < HEADS; ++h)
            den[h] += __expf(lrelu(aS[s * HEADS + h] + ad[h]));
    }
    #pragma unroll
    for (int h = 0; h < HEADS; ++h) {
        float v = den[h];
        #pragma unroll
        for (int off = 32; off; off >>= 1) v += __shfl_xor(v, off, 64);
        den[h] = 1.f / (v + 1e-16f);
    }
    // pass 2: half-wave = one edge; lane covers 8 channels (16B bf16 load)
    int half = lane >> 5, hl = lane & 31;
    int h = hl >> 2;                    // head of channels [hl*8, hl*8+8)
    float adh = ad[h], invd = den[h];
    float acc[8];
    #pragma unroll
    for (int i = 0; i < 8; ++i) acc[i] = 0.f;
    for (int j = start + half; j < end; j += 2) {
        int s = ssrc[j];
        float alpha = __expf(lrelu(aS[s * HEADS + h] + adh)) * invd;
        ushort8_t hv = *(const ushort8_t*)&h1b[(size_t)s * C1 + hl * 8];
        #pragma unroll
        for (int i = 0; i < 8; ++i) acc[i] += alpha * bf2f(hv[i]);
    }
    #pragma unroll
    for (int i = 0; i < 8; ++i) acc[i] += __shfl_xor(acc[i], 32, 64);
    // store: half 0 writes channels [hl*8, hl*8+4), half 1 writes [hl*8+4, hl*8+8)
    int cbase = hl * 8 + half * 4;
    float4 bb = *(const float4*)&b1[cbase];
    float4 o;
    o.x = elu1(acc[half * 4 + 0] + bb.x);
    o.y = elu1(acc[half * 4 + 1] + bb.y);
    o.z = elu1(acc[half * 4 + 2] + bb.z);
    o.w = elu1(acc[half * 4 + 3] + bb.w);
    *(float4*)&z1[(size_t)d * C1 + cbase] = o;
}

// ---------------- GEMM2: h2 = z1 @ W2, fused a_src2/a_dst2 ----------------
__global__ __launch_bounds__(256) void gemm2_kernel(
        const float* __restrict__ z1, const float* __restrict__ W2,
        const float* __restrict__ attS, const float* __restrict__ attD,
        float* __restrict__ h2, float* __restrict__ aS2, float* __restrict__ aD2) {
    __shared__ float zs[32 * 260];
    __shared__ float wc[64 * HID];
    int t = threadIdx.x;
    int n0 = blockIdx.x * 32;
    {
        int f = t * 32, r = f >> 8, c = f & 255;
        float4* d4 = (float4*)(zs + r * 260 + c);
        if (n0 + r < NN) {
            const float4* zr = (const float4*)(z1 + (size_t)(n0 + r) * C1 + c);
            #pragma unroll
            for (int i = 0; i < 8; ++i) d4[i] = zr[i];
        } else {
            float4 z = make_float4(0.f, 0.f, 0.f, 0.f);
            #pragma unroll
            for (int i = 0; i < 8; ++i) d4[i] = z;
        }
    }
    int tn = t >> 3, tc = t & 7;
    float acc[4] = {0.f, 0.f, 0.f, 0.f};
    for (int kb = 0; kb < 4; ++kb) {
        __syncthreads();
        {
            const float4* w4 = (const float4*)(W2 + kb * 64 * HID);
            float4* s4 = (float4*)wc;
            s4[t] = w4[t]; s4[t + 256] = w4[t + 256];
        }
        __syncthreads();
        for (int k = 0; k < 64; ++k) {
            float zv = zs[tn * 260 + kb * 64 + k];
            float4 w = *(const float4*)&wc[k * HID + tc * 4];
            acc[0] += zv * w.x; acc[1] += zv * w.y;
            acc[2] += zv * w.z; acc[3] += zv * w.w;
        }
    }
    int n = n0 + tn;
    float ps = 0.f, pd = 0.f;
    #pragma unroll
    for (int j = 0; j < 4; ++j) { ps += acc[j] * attS[tc * 4 + j]; pd += acc[j] * attD[tc * 4 + j]; }
    ps += __shfl_xor(ps, 1, 64); ps += __shfl_xor(ps, 2, 64); ps += __shfl_xor(ps, 4, 64);
    pd += __shfl_xor(pd, 1, 64); pd += __shfl_xor(pd, 2, 64); pd += __shfl_xor(pd, 4, 64);
    if (n < NN) {
        *(float4*)&h2[(size_t)n * HID + tc * 4] = make_float4(acc[0], acc[1], acc[2], acc[3]);
        if (tc == 0) { aS2[n] = ps; aD2[n] = pd; }
    }
}

// ---------------- Layer-2 aggregation: 2 dst nodes per wave, NO atomics ----------------
__global__ __launch_bounds__(256) void agg2_kernel(
        const int* __restrict__ rowptr, const int* __restrict__ ssrc,
        const float* __restrict__ aS, const float* __restrict__ aD,
        const float* __restrict__ h2, const float* __restrict__ b2,
        float* __restrict__ z2) {
    int wid = (blockIdx.x * 256 + threadIdx.x) >> 6;
    int lane = threadIdx.x & 63;
    int half = lane >> 5, hl = lane & 31;
    int d = wid * 2 + half;
    if (d >= NN) return;
    int start = rowptr[d], end = rowptr[d + 1];
    float adv = aD[d];
    float den = 0.f;
    for (int j = start + hl; j < end; j += 32)
        den += __expf(lrelu(aS[ssrc[j]] + adv));
    #pragma unroll
    for (int off = 16; off; off >>= 1) den += __shfl_xor(den, off, 32);
    float invd = 1.f / (den + 1e-16f);
    float acc = 0.f;
    int j = start;
    for (; j + 1 < end; j += 2) {
        int s0 = ssrc[j], s1 = ssrc[j + 1];
        float a0 = aS[s0], a1 = aS[s1];
        float v0 = h2[(size_t)s0 * HID + hl];
        float v1 = h2[(size_t)s1 * HID + hl];
        acc += __expf(lrelu(a0 + adv)) * v0;
        acc += __expf(lrelu(a1 + adv)) * v1;
    }
    if (j < end) {
        int s = ssrc[j];
        acc += __expf(lrelu(aS[s] + adv)) * h2[(size_t)s * HID + hl];
    }
    acc *= invd;
    z2[(size_t)d * HID + hl] = elu1(acc + b2[hl]);
}

// ---------------- Pool + Wo + sigmoid: one block per group, no atomics ----------------
__global__ __launch_bounds__(256) void pool_final_kernel(
        const float* __restrict__ z2, const int* __restrict__ batch,
        const float* __restrict__ Wo, const float* __restrict__ bo,
        float* __restrict__ out) {
    __shared__ float sm[256];
    int g = blockIdx.x;
    int t = threadIdx.x;
    int lo = 0, hi = NN;
    while (lo < hi) { int mid = (lo + hi) >> 1; if (batch[mid] < g) lo = mid + 1; else hi = mid; }
    int start = lo;
    hi = NN;
    while (lo < hi) { int mid = (lo + hi) >> 1; if (batch[mid] < g + 1) lo = mid + 1; else hi = mid; }
    int end = lo;
    int c = t & 31, r = t >> 5;
    float acc = 0.f;
    for (int n = start + r; n < end; n += 8)
        acc += z2[(size_t)n * HID + c];
    sm[t] = acc;
    __syncthreads();
    if (t < 32) {
        float s = 0.f;
        #pragma unroll
        for (int i = 0; i < 8; ++i) s += sm[t + 32 * i];
        float cntf = fmaxf((float)(end - start), 1.f);
        float part = (s / cntf) * Wo[t];
        #pragma unroll
        for (int off = 16; off; off >>= 1) part += __shfl_xor(part, off, 32);
        if (t == 0) out[g] = 1.f / (1.f + __expf(-(part + bo[0])));
    }
}

extern "C" void kernel_launch(void* const* d_in, const int* in_sizes, int n_in,
                              void* d_out, int out_size, void* d_ws, size_t ws_size,
                              hipStream_t stream) {
    const float* x     = (const float*)d_in[0];
    const int*   ei    = (const int*)d_in[1];
    const int*   batch = (const int*)d_in[2];
    const float* W1    = (const float*)d_in[3];
    const float* attS1 = (const float*)d_in[4];
    const float* attD1 = (const float*)d_in[5];
    const float* b1    = (const float*)d_in[6];
    const float* W2    = (const float*)d_in[7];
    const float* attS2 = (const float*)d_in[8];
    const float* attD2 = (const float*)d_in[9];
    const float* b2    = (const float*)d_in[10];
    const float* Wo    = (const float*)d_in[11];
    const float* bo    = (const float*)d_in[12];
    float* out = (float*)d_out;

    char* p = (char*)d_ws;
    auto alloc = [&](size_t bytes) {
        char* r = p;
        p += (bytes + 255) & ~(size_t)255;
        return (void*)r;
    };
    unsigned short* h1b = (unsigned short*)alloc((size_t)NN * C1 * 2);
    float* z1     = (float*)alloc((size_t)NN * C1 * 4);
    float* aS1    = (float*)alloc((size_t)NN * HEADS * 4);
    float* aD1    = (float*)alloc((size_t)NN * HEADS * 4);
    float* h2     = (float*)alloc((size_t)NN * HID * 4);
    float* z2     = (float*)alloc((size_t)NN * HID * 4);
    float* aS2    = (float*)alloc((size_t)NN * 4);
    float* aD2    = (float*)alloc((size_t)NN * 4);
    int*   rowptr = (int*)alloc((size_t)(NN + 1) * 4);
    int*   cursor = (int*)alloc((size_t)NN * 4);
    int*   ssrc   = (int*)alloc((size_t)ET * 4);
    int*   cnt    = (int*)alloc((size_t)NN * 4);

    hipMemsetAsync(cnt, 0, (size_t)NN * 4, stream);
    hist_kernel<<<(ET + 255) / 256, 256, 0, stream>>>(ei, cnt);
    scan_kernel<<<1, 1024, 0, stream>>>(cnt, rowptr);
    hipMemcpyAsync(cursor, rowptr, (size_t)NN * 4, hipMemcpyDeviceToDevice, stream);
    scatter_kernel<<<(ET + 255) / 256, 256, 0, stream>>>(ei, cursor, ssrc);
    gemm1_kernel<<<(NN + 31) / 32, 256, 0, stream>>>(x, W1, attS1, attD1, h1b, aS1, aD1);
    agg1_kernel<<<(NN * 64) / 256, 256, 0, stream>>>(rowptr, ssrc, aS1, aD1, h1b, b1, z1);
    gemm2_kernel<<<(NN + 31) / 32, 256, 0, stream>>>(z1, W2, attS2, attD2, h2, aS2, aD2);
    agg2_kernel<<<(NN / 2 * 64 + 255) / 256, 256, 0, stream>>>(rowptr, ssrc, aS2, aD2, h2, b2, z2);
    pool_final_kernel<<<NG, 256, 0, stream>>>(z2, batch, Wo, bo, out);
}

// Round 4
// 392.147 us; speedup vs baseline: 2.1992x; 1.1362x over previous
//
#include <hip/hip_runtime.h>
#include <hip/hip_bf16.h>
#include <math.h>

#define NN 50000
#define NE 800000
#define ET (NE + NN)
#define FIN 128
#define HEADS 8
#define HID 32
#define C1 (HEADS * HID)   // 256
#define NG 64
#define NEG 0.2f
#define NB_SCAN 196        // ceil(NN/256)

typedef __attribute__((ext_vector_type(8))) unsigned short ushort8_t;
typedef __attribute__((ext_vector_type(4))) unsigned short ushort4_t;
typedef __attribute__((ext_vector_type(2))) float float2_t;

__device__ __forceinline__ float lrelu(float v) { return v > 0.f ? v : NEG * v; }
__device__ __forceinline__ float elu1(float v)  { return v > 0.f ? v : expm1f(v); }
__device__ __forceinline__ unsigned short f2bf(float f) {
    __hip_bfloat16 b = __float2bfloat16(f);
    return *reinterpret_cast<unsigned short*>(&b);
}
__device__ __forceinline__ float bf2f(unsigned short u) {
    return __uint_as_float(((unsigned)u) << 16);
}

// ---------------- CSR build ----------------
__global__ void hist_kernel(const int* __restrict__ ei, int* __restrict__ cnt) {
    int i = blockIdx.x * 256 + threadIdx.x;
    if (i >= ET) return;
    int d = (i < NE) ? ei[NE + i] : (i - NE);
    atomicAdd(&cnt[d], 1);
}

// block-level exclusive scan: rowptr[gid] = excl-within-block, bsum[b] = block total
__global__ __launch_bounds__(256) void scan_a_kernel(const int* __restrict__ cnt,
                                                     int* __restrict__ rowptr,
                                                     int* __restrict__ bsum) {
    __shared__ int ws[4];
    int t = threadIdx.x, b = blockIdx.x, gid = b * 256 + t;
    int lane = t & 63, w = t >> 6;
    int v = (gid < NN) ? cnt[gid] : 0;
    int inc = v;
    #pragma unroll
    for (int off = 1; off < 64; off <<= 1) {
        int u = __shfl_up(inc, off, 64);
        if (lane >= off) inc += u;
    }
    if (lane == 63) ws[w] = inc;
    __syncthreads();
    int woff = 0;
    #pragma unroll
    for (int i = 0; i < 4; ++i) if (i < w) woff += ws[i];
    if (gid < NN) rowptr[gid] = woff + inc - v;
    if (t == 255) bsum[b] = woff + inc;
}

// scan the 196 block sums (single small block)
__global__ __launch_bounds__(256) void scan_b_kernel(const int* __restrict__ bsum,
                                                     int* __restrict__ boff,
                                                     int* __restrict__ rowptr) {
    __shared__ int ws[4];
    int t = threadIdx.x, lane = t & 63, w = t >> 6;
    int v = (t < NB_SCAN) ? bsum[t] : 0;
    int inc = v;
    #pragma unroll
    for (int off = 1; off < 64; off <<= 1) {
        int u = __shfl_up(inc, off, 64);
        if (lane >= off) inc += u;
    }
    if (lane == 63) ws[w] = inc;
    __syncthreads();
    int woff = 0;
    #pragma unroll
    for (int i = 0; i < 4; ++i) if (i < w) woff += ws[i];
    if (t < NB_SCAN) boff[t] = woff + inc - v;
    if (t == 255) rowptr[NN] = woff + inc;   // grand total = ET
}

// add block offsets; also initialize cursor
__global__ __launch_bounds__(256) void scan_c_kernel(int* __restrict__ rowptr,
                                                     const int* __restrict__ boff,
                                                     int* __restrict__ cursor) {
    int gid = blockIdx.x * 256 + threadIdx.x;
    if (gid >= NN) return;
    int r = rowptr[gid] + boff[blockIdx.x];
    rowptr[gid] = r;
    cursor[gid] = r;
}

__global__ void scatter_kernel(const int* __restrict__ ei, int* __restrict__ cursor,
                               int* __restrict__ ssrc) {
    int i = blockIdx.x * 256 + threadIdx.x;
    if (i >= ET) return;
    int s, d;
    if (i < NE) { s = ei[i]; d = ei[NE + i]; }
    else        { s = i - NE; d = s; }
    int pos = atomicAdd(&cursor[d], 1);
    ssrc[pos] = s;
}

// ---------------- GEMM1: h1 = x @ W1 (fp8 out), fused a_src1/a_dst1 ----------------
__global__ __launch_bounds__(256) void gemm1_kernel(
        const float* __restrict__ x, const float* __restrict__ W1,
        const float* __restrict__ attS, const float* __restrict__ attD,
        unsigned char* __restrict__ h1f8, float* __restrict__ aS, float* __restrict__ aD) {
    __shared__ float xs[32 * FIN];   // 16 KB
    __shared__ float ws[32 * C1];    // 32 KB (one K-chunk of W1)
    int t = threadIdx.x;
    int n0 = blockIdx.x * 32;
    {
        int f = t * 16, r = f >> 7, c = f & 127;
        float4* d4 = (float4*)(xs + r * FIN + c);
        if (n0 + r < NN) {
            const float4* xr = (const float4*)(x + (size_t)(n0 + r) * FIN + c);
            d4[0] = xr[0]; d4[1] = xr[1]; d4[2] = xr[2]; d4[3] = xr[3];
        } else {
            float4 z = make_float4(0.f, 0.f, 0.f, 0.f);
            d4[0] = z; d4[1] = z; d4[2] = z; d4[3] = z;
        }
    }
    int tc = t & 31, tn = t >> 5;
    float acc[4][8];
    #pragma unroll
    for (int i = 0; i < 4; ++i)
        #pragma unroll
        for (int j = 0; j < 8; ++j) acc[i][j] = 0.f;

    for (int kb = 0; kb < 4; ++kb) {
        __syncthreads();
        {
            const float4* w4 = (const float4*)(W1 + kb * 32 * C1);
            float4* s4 = (float4*)ws;
            #pragma unroll
            for (int i = 0; i < 8; ++i) s4[t + i * 256] = w4[t + i * 256];
        }
        __syncthreads();
        for (int k = 0; k < 32; ++k) {
            float4 w0 = *(const float4*)&ws[k * C1 + tc * 8];
            float4 w1 = *(const float4*)&ws[k * C1 + tc * 8 + 4];
            #pragma unroll
            for (int i = 0; i < 4; ++i) {
                float xv = xs[(tn * 4 + i) * FIN + kb * 32 + k];
                acc[i][0] += xv * w0.x; acc[i][1] += xv * w0.y;
                acc[i][2] += xv * w0.z; acc[i][3] += xv * w0.w;
                acc[i][4] += xv * w1.x; acc[i][5] += xv * w1.y;
                acc[i][6] += xv * w1.z; acc[i][7] += xv * w1.w;
            }
        }
    }
    float as_[8], ad_[8];
    #pragma unroll
    for (int j = 0; j < 8; ++j) { as_[j] = attS[tc * 8 + j]; ad_[j] = attD[tc * 8 + j]; }
    int h = tc >> 2;
    #pragma unroll
    for (int i = 0; i < 4; ++i) {
        int n = n0 + tn * 4 + i;
        float ps = 0.f, pd = 0.f;
        #pragma unroll
        for (int j = 0; j < 8; ++j) { ps += acc[i][j] * as_[j]; pd += acc[i][j] * ad_[j]; }
        ps += __shfl_xor(ps, 1, 64); ps += __shfl_xor(ps, 2, 64);
        pd += __shfl_xor(pd, 1, 64); pd += __shfl_xor(pd, 2, 64);
        if (n < NN) {
            int p0 = __builtin_amdgcn_cvt_pk_fp8_f32(acc[i][0], acc[i][1], 0, false);
            p0 = __builtin_amdgcn_cvt_pk_fp8_f32(acc[i][2], acc[i][3], p0, true);
            int p1 = __builtin_amdgcn_cvt_pk_fp8_f32(acc[i][4], acc[i][5], 0, false);
            p1 = __builtin_amdgcn_cvt_pk_fp8_f32(acc[i][6], acc[i][7], p1, true);
            *(uint2*)&h1f8[(size_t)n * C1 + tc * 8] = make_uint2((unsigned)p0, (unsigned)p1);
            if ((tc & 3) == 0) { aS[n * HEADS + h] = ps; aD[n * HEADS + h] = pd; }
        }
    }
}

// ---------------- Layer-1 aggregation: one wave per dst, half-wave per edge ----------------
__global__ __launch_bounds__(256) void agg1_kernel(
        const int* __restrict__ rowptr, const int* __restrict__ ssrc,
        const float* __restrict__ aS, const float* __restrict__ aD,
        const unsigned char* __restrict__ h1f8, const float* __restrict__ b1,
        unsigned short* __restrict__ z1b) {
    int d = (blockIdx.x * 256 + threadIdx.x) >> 6;
    int lane = threadIdx.x & 63;
    if (d >= NN) return;
    int start = rowptr[d], end = rowptr[d + 1];
    float ad[HEADS], den[HEADS];
    #pragma unroll
    for (int h = 0; h < HEADS; ++h) { ad[h] = aD[d * HEADS + h]; den[h] = 0.f; }
    // pass 1: softmax denominators (all 64 lanes stride edges)
    for (int j = start + lane; j < end; j += 64) {
        int s = ssrc[j];
        #pragma unroll
        for (int h = 0; h < HEADS; ++h)
            den[h] += __expf(lrelu(aS[s * HEADS + h] + ad[h]));
    }
    #pragma unroll
    for (int h = 0; h < HEADS; ++h) {
        float v = den[h];
        #pragma unroll
        for (int off = 32; off; off >>= 1) v += __shfl_xor(v, off, 64);
        den[h] = 1.f / (v + 1e-16f);
    }
    // pass 2: half-wave = one edge; lane covers 8 channels (8B fp8 load)
    int half = lane >> 5, hl = lane & 31;
    int h = hl >> 2;                    // head of channels [hl*8, hl*8+8)
    float adh = ad[h], invd = den[h];
    float acc[8];
    #pragma unroll
    for (int i = 0; i < 8; ++i) acc[i] = 0.f;
    for (int j = start + half; j < end; j += 2) {
        int s = ssrc[j];
        float alpha = __expf(lrelu(aS[s * HEADS + h] + adh)) * invd;
        uint2 raw = *(const uint2*)&h1f8[(size_t)s * C1 + hl * 8];
        float2_t f01 = __builtin_amdgcn_cvt_pk_f32_fp8((int)raw.x, false);
        float2_t f23 = __builtin_amdgcn_cvt_pk_f32_fp8((int)raw.x, true);
        float2_t f45 = __builtin_amdgcn_cvt_pk_f32_fp8((int)raw.y, false);
        float2_t f67 = __builtin_amdgcn_cvt_pk_f32_fp8((int)raw.y, true);
        acc[0] += alpha * f01.x; acc[1] += alpha * f01.y;
        acc[2] += alpha * f23.x; acc[3] += alpha * f23.y;
        acc[4] += alpha * f45.x; acc[5] += alpha * f45.y;
        acc[6] += alpha * f67.x; acc[7] += alpha * f67.y;
    }
    #pragma unroll
    for (int i = 0; i < 8; ++i) acc[i] += __shfl_xor(acc[i], 32, 64);
    // store: half 0 writes channels [hl*8, hl*8+4), half 1 writes [hl*8+4, hl*8+8)
    int cbase = hl * 8 + half * 4;
    float4 bb = *(const float4*)&b1[cbase];
    ushort4_t o;
    o[0] = f2bf(elu1(acc[half * 4 + 0] + bb.x));
    o[1] = f2bf(elu1(acc[half * 4 + 1] + bb.y));
    o[2] = f2bf(elu1(acc[half * 4 + 2] + bb.z));
    o[3] = f2bf(elu1(acc[half * 4 + 3] + bb.w));
    *(ushort4_t*)&z1b[(size_t)d * C1 + cbase] = o;
}

// ---------------- GEMM2: h2 = z1 @ W2 (bf16 in/out), fused a_src2/a_dst2 ----------------
__global__ __launch_bounds__(256) void gemm2_kernel(
        const unsigned short* __restrict__ z1b, const float* __restrict__ W2,
        const float* __restrict__ attS, const float* __restrict__ attD,
        unsigned short* __restrict__ h2b, float* __restrict__ aS2, float* __restrict__ aD2) {
    __shared__ float zs[32 * 260];
    __shared__ float wc[64 * HID];
    int t = threadIdx.x;
    int n0 = blockIdx.x * 32;
    {
        int f = t * 32, r = f >> 8, c = f & 255;
        if (n0 + r < NN) {
            const ushort8_t* zr = (const ushort8_t*)&z1b[(size_t)(n0 + r) * C1 + c];
            #pragma unroll
            for (int i = 0; i < 4; ++i) {
                ushort8_t u = zr[i];
                *(float4*)&zs[r * 260 + c + i * 8] =
                    make_float4(bf2f(u[0]), bf2f(u[1]), bf2f(u[2]), bf2f(u[3]));
                *(float4*)&zs[r * 260 + c + i * 8 + 4] =
                    make_float4(bf2f(u[4]), bf2f(u[5]), bf2f(u[6]), bf2f(u[7]));
            }
        } else {
            float4 z = make_float4(0.f, 0.f, 0.f, 0.f);
            #pragma unroll
            for (int i = 0; i < 8; ++i) *(float4*)&zs[r * 260 + c + i * 4] = z;
        }
    }
    int tn = t >> 3, tc = t & 7;
    float acc[4] = {0.f, 0.f, 0.f, 0.f};
    for (int kb = 0; kb < 4; ++kb) {
        __syncthreads();
        {
            const float4* w4 = (const float4*)(W2 + kb * 64 * HID);
            float4* s4 = (float4*)wc;
            s4[t] = w4[t]; s4[t + 256] = w4[t + 256];
        }
        __syncthreads();
        for (int k = 0; k < 64; ++k) {
            float zv = zs[tn * 260 + kb * 64 + k];
            float4 w = *(const float4*)&wc[k * HID + tc * 4];
            acc[0] += zv * w.x; acc[1] += zv * w.y;
            acc[2] += zv * w.z; acc[3] += zv * w.w;
        }
    }
    int n = n0 + tn;
    float ps = 0.f, pd = 0.f;
    #pragma unroll
    for (int j = 0; j < 4; ++j) { ps += acc[j] * attS[tc * 4 + j]; pd += acc[j] * attD[tc * 4 + j]; }
    ps += __shfl_xor(ps, 1, 64); ps += __shfl_xor(ps, 2, 64); ps += __shfl_xor(ps, 4, 64);
    pd += __shfl_xor(pd, 1, 64); pd += __shfl_xor(pd, 2, 64); pd += __shfl_xor(pd, 4, 64);
    if (n < NN) {
        ushort4_t o;
        o[0] = f2bf(acc[0]); o[1] = f2bf(acc[1]); o[2] = f2bf(acc[2]); o[3] = f2bf(acc[3]);
        *(ushort4_t*)&h2b[(size_t)n * HID + tc * 4] = o;
        if (tc == 0) { aS2[n] = ps; aD2[n] = pd; }
    }
}

// ---------------- Layer-2 aggregation: 2 dst nodes per wave ----------------
__global__ __launch_bounds__(256) void agg2_kernel(
        const int* __restrict__ rowptr, const int* __restrict__ ssrc,
        const float* __restrict__ aS, const float* __restrict__ aD,
        const unsigned short* __restrict__ h2b, const float* __restrict__ b2,
        float* __restrict__ z2) {
    int wid = (blockIdx.x * 256 + threadIdx.x) >> 6;
    int lane = threadIdx.x & 63;
    int half = lane >> 5, hl = lane & 31;
    int d = wid * 2 + half;
    if (d >= NN) return;
    int start = rowptr[d], end = rowptr[d + 1];
    float adv = aD[d];
    float den = 0.f;
    for (int j = start + hl; j < end; j += 32)
        den += __expf(lrelu(aS[ssrc[j]] + adv));
    #pragma unroll
    for (int off = 16; off; off >>= 1) den += __shfl_xor(den, off, 32);
    float invd = 1.f / (den + 1e-16f);
    float acc = 0.f;
    int j = start;
    for (; j + 1 < end; j += 2) {
        int s0 = ssrc[j], s1 = ssrc[j + 1];
        float a0 = aS[s0], a1 = aS[s1];
        float v0 = bf2f(h2b[(size_t)s0 * HID + hl]);
        float v1 = bf2f(h2b[(size_t)s1 * HID + hl]);
        acc += __expf(lrelu(a0 + adv)) * v0;
        acc += __expf(lrelu(a1 + adv)) * v1;
    }
    if (j < end) {
        int s = ssrc[j];
        acc += __expf(lrelu(aS[s] + adv)) * bf2f(h2b[(size_t)s * HID + hl]);
    }
    acc *= invd;
    z2[(size_t)d * HID + hl] = elu1(acc + b2[hl]);
}

// ---------------- Pool partial: 16 blocks per group, LDS reduce + few atomics ----------------
__global__ __launch_bounds__(256) void pool_partial_kernel(
        const float* __restrict__ z2, const int* __restrict__ batch,
        float* __restrict__ pooled) {
    __shared__ float sm[256];
    int g = blockIdx.x >> 4, slice = blockIdx.x & 15;
    int t = threadIdx.x;
    int lo = 0, hi = NN;
    while (lo < hi) { int m = (lo + hi) >> 1; if (batch[m] < g) lo = m + 1; else hi = m; }
    int start = lo;
    hi = NN;
    while (lo < hi) { int m = (lo + hi) >> 1; if (batch[m] < g + 1) lo = m + 1; else hi = m; }
    int end = lo;
    int len = end - start;
    int s0 = start + (int)(((long long)len * slice) >> 4);
    int s1 = start + (int)(((long long)len * (slice + 1)) >> 4);
    int c = t & 31, r = t >> 5;
    float acc = 0.f;
    for (int n = s0 + r; n < s1; n += 8)
        acc += z2[(size_t)n * HID + c];
    sm[t] = acc;
    __syncthreads();
    if (t < 32) {
        float s = 0.f;
        #pragma unroll
        for (int i = 0; i < 8; ++i) s += sm[t + 32 * i];
        atomicAdd(&pooled[g * HID + t], s);
    }
}

// ---------------- Finish: mean + Wo + sigmoid ----------------
__global__ void pool_finish_kernel(const float* __restrict__ pooled,
                                   const int* __restrict__ batch,
                                   const float* __restrict__ Wo, const float* __restrict__ bo,
                                   float* __restrict__ out) {
    int g = threadIdx.x;
    if (g >= NG) return;
    int lo = 0, hi = NN;
    while (lo < hi) { int m = (lo + hi) >> 1; if (batch[m] < g) lo = m + 1; else hi = m; }
    int start = lo;
    hi = NN;
    while (lo < hi) { int m = (lo + hi) >> 1; if (batch[m] < g + 1) lo = m + 1; else hi = m; }
    int end = lo;
    float c = fmaxf((float)(end - start), 1.f);
    float acc = 0.f;
    for (int i = 0; i < HID; ++i) acc += (pooled[g * HID + i] / c) * Wo[i];
    acc += bo[0];
    out[g] = 1.f / (1.f + __expf(-acc));
}

extern "C" void kernel_launch(void* const* d_in, const int* in_sizes, int n_in,
                              void* d_out, int out_size, void* d_ws, size_t ws_size,
                              hipStream_t stream) {
    const float* x     = (const float*)d_in[0];
    const int*   ei    = (const int*)d_in[1];
    const int*   batch = (const int*)d_in[2];
    const float* W1    = (const float*)d_in[3];
    const float* attS1 = (const float*)d_in[4];
    const float* attD1 = (const float*)d_in[5];
    const float* b1    = (const float*)d_in[6];
    const float* W2    = (const float*)d_in[7];
    const float* attS2 = (const float*)d_in[8];
    const float* attD2 = (const float*)d_in[9];
    const float* b2    = (const float*)d_in[10];
    const float* Wo    = (const float*)d_in[11];
    const float* bo    = (const float*)d_in[12];
    float* out = (float*)d_out;

    char* p = (char*)d_ws;
    auto alloc = [&](size_t bytes) {
        char* r = p;
        p += (bytes + 255) & ~(size_t)255;
        return (void*)r;
    };
    unsigned char*  h1f8 = (unsigned char*)alloc((size_t)NN * C1);
    unsigned short* z1b  = (unsigned short*)alloc((size_t)NN * C1 * 2);
    unsigned short* h2b  = (unsigned short*)alloc((size_t)NN * HID * 2);
    float* aS1    = (float*)alloc((size_t)NN * HEADS * 4);
    float* aD1    = (float*)alloc((size_t)NN * HEADS * 4);
    float* z2     = (float*)alloc((size_t)NN * HID * 4);
    float* aS2    = (float*)alloc((size_t)NN * 4);
    float* aD2    = (float*)alloc((size_t)NN * 4);
    int*   rowptr = (int*)alloc((size_t)(NN + 1) * 4);
    int*   cursor = (int*)alloc((size_t)NN * 4);
    int*   ssrc   = (int*)alloc((size_t)ET * 4);
    int*   bsum   = (int*)alloc((size_t)NB_SCAN * 4);
    int*   boff   = (int*)alloc((size_t)NB_SCAN * 4);
    // zero-init region: cnt + pooled (contiguous)
    int*   cnt    = (int*)alloc((size_t)NN * 4);
    float* pooled = (float*)alloc((size_t)NG * HID * 4);
    size_t zero_bytes = (size_t)(p - (char*)cnt);

    hipMemsetAsync(cnt, 0, zero_bytes, stream);
    hist_kernel<<<(ET + 255) / 256, 256, 0, stream>>>(ei, cnt);
    scan_a_kernel<<<NB_SCAN, 256, 0, stream>>>(cnt, rowptr, bsum);
    scan_b_kernel<<<1, 256, 0, stream>>>(bsum, boff, rowptr);
    scan_c_kernel<<<NB_SCAN, 256, 0, stream>>>(rowptr, boff, cursor);
    scatter_kernel<<<(ET + 255) / 256, 256, 0, stream>>>(ei, cursor, ssrc);
    gemm1_kernel<<<(NN + 31) / 32, 256, 0, stream>>>(x, W1, attS1, attD1, h1f8, aS1, aD1);
    agg1_kernel<<<(NN * 64) / 256, 256, 0, stream>>>(rowptr, ssrc, aS1, aD1, h1f8, b1, z1b);
    gemm2_kernel<<<(NN + 31) / 32, 256, 0, stream>>>(z1b, W2, attS2, attD2, h2b, aS2, aD2);
    agg2_kernel<<<(NN / 2 * 64 + 255) / 256, 256, 0, stream>>>(rowptr, ssrc, aS2, aD2, h2b, b2, z2);
    pool_partial_kernel<<<NG * 16, 256, 0, stream>>>(z2, batch, pooled);
    pool_finish_kernel<<<1, 64, 0, stream>>>(pooled, batch, Wo, bo, out);
}

// Round 5
// 364.085 us; speedup vs baseline: 2.3687x; 1.0771x over previous
//
#include <hip/hip_runtime.h>
#include <hip/hip_bf16.h>
#include <math.h>

#define NN 50000
#define NE 800000
#define ET (NE + NN)
#define FIN 128
#define HEADS 8
#define HID 32
#define C1 (HEADS * HID)   // 256
#define NG 64
#define NEG 0.2f
#define NB_SCAN 196        // ceil(NN/256)

typedef __attribute__((ext_vector_type(8))) unsigned short ushort8_t;
typedef __attribute__((ext_vector_type(4))) unsigned short ushort4_t;
typedef __attribute__((ext_vector_type(2))) float float2_t;

__device__ __forceinline__ float lrelu(float v) { return v > 0.f ? v : NEG * v; }
__device__ __forceinline__ float elu1(float v)  { return v > 0.f ? v : expm1f(v); }
__device__ __forceinline__ unsigned short f2bf(float f) {
    __hip_bfloat16 b = __float2bfloat16(f);
    return *reinterpret_cast<unsigned short*>(&b);
}
__device__ __forceinline__ float bf2f(unsigned short u) {
    return __uint_as_float(((unsigned)u) << 16);
}

// ---------------- CSR build ----------------
__global__ void hist_kernel(const int* __restrict__ ei, int* __restrict__ cnt) {
    int i = blockIdx.x * 256 + threadIdx.x;
    if (i >= ET) return;
    int d = (i < NE) ? ei[NE + i] : (i - NE);
    atomicAdd(&cnt[d], 1);
}

__global__ __launch_bounds__(256) void scan_a_kernel(const int* __restrict__ cnt,
                                                     int* __restrict__ rowptr,
                                                     int* __restrict__ bsum) {
    __shared__ int ws[4];
    int t = threadIdx.x, b = blockIdx.x, gid = b * 256 + t;
    int lane = t & 63, w = t >> 6;
    int v = (gid < NN) ? cnt[gid] : 0;
    int inc = v;
    #pragma unroll
    for (int off = 1; off < 64; off <<= 1) {
        int u = __shfl_up(inc, off, 64);
        if (lane >= off) inc += u;
    }
    if (lane == 63) ws[w] = inc;
    __syncthreads();
    int woff = 0;
    #pragma unroll
    for (int i = 0; i < 4; ++i) if (i < w) woff += ws[i];
    if (gid < NN) rowptr[gid] = woff + inc - v;
    if (t == 255) bsum[b] = woff + inc;
}

__global__ __launch_bounds__(256) void scan_b_kernel(const int* __restrict__ bsum,
                                                     int* __restrict__ boff,
                                                     int* __restrict__ rowptr) {
    __shared__ int ws[4];
    int t = threadIdx.x, lane = t & 63, w = t >> 6;
    int v = (t < NB_SCAN) ? bsum[t] : 0;
    int inc = v;
    #pragma unroll
    for (int off = 1; off < 64; off <<= 1) {
        int u = __shfl_up(inc, off, 64);
        if (lane >= off) inc += u;
    }
    if (lane == 63) ws[w] = inc;
    __syncthreads();
    int woff = 0;
    #pragma unroll
    for (int i = 0; i < 4; ++i) if (i < w) woff += ws[i];
    if (t < NB_SCAN) boff[t] = woff + inc - v;
    if (t == 255) rowptr[NN] = woff + inc;   // grand total = ET
}

__global__ __launch_bounds__(256) void scan_c_kernel(int* __restrict__ rowptr,
                                                     const int* __restrict__ boff,
                                                     int* __restrict__ cursor) {
    int gid = blockIdx.x * 256 + threadIdx.x;
    if (gid >= NN) return;
    int r = rowptr[gid] + boff[blockIdx.x];
    rowptr[gid] = r;
    cursor[gid] = r;
}

__global__ void scatter_kernel(const int* __restrict__ ei, int* __restrict__ cursor,
                               int* __restrict__ ssrc) {
    int i = blockIdx.x * 256 + threadIdx.x;
    if (i >= ET) return;
    int s, d;
    if (i < NE) { s = ei[i]; d = ei[NE + i]; }
    else        { s = i - NE; d = s; }
    int pos = atomicAdd(&cursor[d], 1);
    ssrc[pos] = s;
}

// ---------------- GEMM1: h1 = x @ W1 (fp8 out), fused a_src1/a_dst1 ----------------
__global__ __launch_bounds__(256) void gemm1_kernel(
        const float* __restrict__ x, const float* __restrict__ W1,
        const float* __restrict__ attS, const float* __restrict__ attD,
        unsigned char* __restrict__ h1f8, float* __restrict__ aS, float* __restrict__ aD) {
    __shared__ float xs[32 * FIN];   // 16 KB
    __shared__ float ws[32 * C1];    // 32 KB (one K-chunk of W1)
    int t = threadIdx.x;
    int n0 = blockIdx.x * 32;
    {
        int f = t * 16, r = f >> 7, c = f & 127;
        float4* d4 = (float4*)(xs + r * FIN + c);
        if (n0 + r < NN) {
            const float4* xr = (const float4*)(x + (size_t)(n0 + r) * FIN + c);
            d4[0] = xr[0]; d4[1] = xr[1]; d4[2] = xr[2]; d4[3] = xr[3];
        } else {
            float4 z = make_float4(0.f, 0.f, 0.f, 0.f);
            d4[0] = z; d4[1] = z; d4[2] = z; d4[3] = z;
        }
    }
    int tc = t & 31, tn = t >> 5;
    float acc[4][8];
    #pragma unroll
    for (int i = 0; i < 4; ++i)
        #pragma unroll
        for (int j = 0; j < 8; ++j) acc[i][j] = 0.f;

    for (int kb = 0; kb < 4; ++kb) {
        __syncthreads();
        {
            const float4* w4 = (const float4*)(W1 + kb * 32 * C1);
            float4* s4 = (float4*)ws;
            #pragma unroll
            for (int i = 0; i < 8; ++i) s4[t + i * 256] = w4[t + i * 256];
        }
        __syncthreads();
        for (int k = 0; k < 32; ++k) {
            float4 w0 = *(const float4*)&ws[k * C1 + tc * 8];
            float4 w1 = *(const float4*)&ws[k * C1 + tc * 8 + 4];
            #pragma unroll
            for (int i = 0; i < 4; ++i) {
                float xv = xs[(tn * 4 + i) * FIN + kb * 32 + k];
                acc[i][0] += xv * w0.x; acc[i][1] += xv * w0.y;
                acc[i][2] += xv * w0.z; acc[i][3] += xv * w0.w;
                acc[i][4] += xv * w1.x; acc[i][5] += xv * w1.y;
                acc[i][6] += xv * w1.z; acc[i][7] += xv * w1.w;
            }
        }
    }
    float as_[8], ad_[8];
    #pragma unroll
    for (int j = 0; j < 8; ++j) { as_[j] = attS[tc * 8 + j]; ad_[j] = attD[tc * 8 + j]; }
    int h = tc >> 2;
    #pragma unroll
    for (int i = 0; i < 4; ++i) {
        int n = n0 + tn * 4 + i;
        float ps = 0.f, pd = 0.f;
        #pragma unroll
        for (int j = 0; j < 8; ++j) { ps += acc[i][j] * as_[j]; pd += acc[i][j] * ad_[j]; }
        ps += __shfl_xor(ps, 1, 64); ps += __shfl_xor(ps, 2, 64);
        pd += __shfl_xor(pd, 1, 64); pd += __shfl_xor(pd, 2, 64);
        if (n < NN) {
            int p0 = __builtin_amdgcn_cvt_pk_fp8_f32(acc[i][0], acc[i][1], 0, false);
            p0 = __builtin_amdgcn_cvt_pk_fp8_f32(acc[i][2], acc[i][3], p0, true);
            int p1 = __builtin_amdgcn_cvt_pk_fp8_f32(acc[i][4], acc[i][5], 0, false);
            p1 = __builtin_amdgcn_cvt_pk_fp8_f32(acc[i][6], acc[i][7], p1, true);
            *(uint2*)&h1f8[(size_t)n * C1 + tc * 8] = make_uint2((unsigned)p0, (unsigned)p1);
            if ((tc & 3) == 0) { aS[n * HEADS + h] = ps; aD[n * HEADS + h] = pd; }
        }
    }
}

// ---------------- Layer-1 aggregation: SINGLE PASS (num+den), half-wave per edge ----------------
__global__ __launch_bounds__(256) void agg1_kernel(
        const int* __restrict__ rowptr, const int* __restrict__ ssrc,
        const float* __restrict__ aS, const float* __restrict__ aD,
        const unsigned char* __restrict__ h1f8, const float* __restrict__ b1,
        unsigned short* __restrict__ z1b) {
    int d = (blockIdx.x * 256 + threadIdx.x) >> 6;
    int lane = threadIdx.x & 63;
    if (d >= NN) return;
    int start = rowptr[d], end = rowptr[d + 1];
    int half = lane >> 5, hl = lane & 31;
    int h = hl >> 2;                    // head of channels [hl*8, hl*8+8)
    float adh = aD[d * HEADS + h];
    float acc[8];
    #pragma unroll
    for (int i = 0; i < 8; ++i) acc[i] = 0.f;
    float den = 0.f;
    int j = start + half;
    // unroll x2: 2 gathers in flight per half-wave (4 per wave)
    for (; j + 2 < end; j += 4) {
        int s0 = ssrc[j], s1 = ssrc[j + 2];
        uint2 r0 = *(const uint2*)&h1f8[(size_t)s0 * C1 + hl * 8];
        uint2 r1 = *(const uint2*)&h1f8[(size_t)s1 * C1 + hl * 8];
        float e0 = __expf(lrelu(aS[s0 * HEADS + h] + adh));
        float e1 = __expf(lrelu(aS[s1 * HEADS + h] + adh));
        den += e0 + e1;
        {
            float2_t f01 = __builtin_amdgcn_cvt_pk_f32_fp8((int)r0.x, false);
            float2_t f23 = __builtin_amdgcn_cvt_pk_f32_fp8((int)r0.x, true);
            float2_t f45 = __builtin_amdgcn_cvt_pk_f32_fp8((int)r0.y, false);
            float2_t f67 = __builtin_amdgcn_cvt_pk_f32_fp8((int)r0.y, true);
            acc[0] += e0 * f01.x; acc[1] += e0 * f01.y;
            acc[2] += e0 * f23.x; acc[3] += e0 * f23.y;
            acc[4] += e0 * f45.x; acc[5] += e0 * f45.y;
            acc[6] += e0 * f67.x; acc[7] += e0 * f67.y;
        }
        {
            float2_t f01 = __builtin_amdgcn_cvt_pk_f32_fp8((int)r1.x, false);
            float2_t f23 = __builtin_amdgcn_cvt_pk_f32_fp8((int)r1.x, true);
            float2_t f45 = __builtin_amdgcn_cvt_pk_f32_fp8((int)r1.y, false);
            float2_t f67 = __builtin_amdgcn_cvt_pk_f32_fp8((int)r1.y, true);
            acc[0] += e1 * f01.x; acc[1] += e1 * f01.y;
            acc[2] += e1 * f23.x; acc[3] += e1 * f23.y;
            acc[4] += e1 * f45.x; acc[5] += e1 * f45.y;
            acc[6] += e1 * f67.x; acc[7] += e1 * f67.y;
        }
    }
    for (; j < end; j += 2) {
        int s = ssrc[j];
        uint2 raw = *(const uint2*)&h1f8[(size_t)s * C1 + hl * 8];
        float e = __expf(lrelu(aS[s * HEADS + h] + adh));
        den += e;
        float2_t f01 = __builtin_amdgcn_cvt_pk_f32_fp8((int)raw.x, false);
        float2_t f23 = __builtin_amdgcn_cvt_pk_f32_fp8((int)raw.x, true);
        float2_t f45 = __builtin_amdgcn_cvt_pk_f32_fp8((int)raw.y, false);
        float2_t f67 = __builtin_amdgcn_cvt_pk_f32_fp8((int)raw.y, true);
        acc[0] += e * f01.x; acc[1] += e * f01.y;
        acc[2] += e * f23.x; acc[3] += e * f23.y;
        acc[4] += e * f45.x; acc[5] += e * f45.y;
        acc[6] += e * f67.x; acc[7] += e * f67.y;
    }
    // combine the two halves (each covered alternating edges)
    den += __shfl_xor(den, 32, 64);
    #pragma unroll
    for (int i = 0; i < 8; ++i) acc[i] += __shfl_xor(acc[i], 32, 64);
    float invd = 1.f / (den + 1e-16f);
    // store: half 0 writes channels [hl*8, hl*8+4), half 1 writes [hl*8+4, hl*8+8)
    int cbase = hl * 8 + half * 4;
    float4 bb = *(const float4*)&b1[cbase];
    ushort4_t o;
    o[0] = f2bf(elu1(acc[half * 4 + 0] * invd + bb.x));
    o[1] = f2bf(elu1(acc[half * 4 + 1] * invd + bb.y));
    o[2] = f2bf(elu1(acc[half * 4 + 2] * invd + bb.z));
    o[3] = f2bf(elu1(acc[half * 4 + 3] * invd + bb.w));
    *(ushort4_t*)&z1b[(size_t)d * C1 + cbase] = o;
}

// ---------------- GEMM2: h2 = z1 @ W2 (bf16 in/out), fused a_src2/a_dst2 ----------------
__global__ __launch_bounds__(256) void gemm2_kernel(
        const unsigned short* __restrict__ z1b, const float* __restrict__ W2,
        const float* __restrict__ attS, const float* __restrict__ attD,
        unsigned short* __restrict__ h2b, float* __restrict__ aS2, float* __restrict__ aD2) {
    __shared__ float zs[32 * 260];
    __shared__ float wc[64 * HID];
    int t = threadIdx.x;
    int n0 = blockIdx.x * 32;
    {
        int f = t * 32, r = f >> 8, c = f & 255;
        if (n0 + r < NN) {
            const ushort8_t* zr = (const ushort8_t*)&z1b[(size_t)(n0 + r) * C1 + c];
            #pragma unroll
            for (int i = 0; i < 4; ++i) {
                ushort8_t u = zr[i];
                *(float4*)&zs[r * 260 + c + i * 8] =
                    make_float4(bf2f(u[0]), bf2f(u[1]), bf2f(u[2]), bf2f(u[3]));
                *(float4*)&zs[r * 260 + c + i * 8 + 4] =
                    make_float4(bf2f(u[4]), bf2f(u[5]), bf2f(u[6]), bf2f(u[7]));
            }
        } else {
            float4 z = make_float4(0.f, 0.f, 0.f, 0.f);
            #pragma unroll
            for (int i = 0; i < 8; ++i) *(float4*)&zs[r * 260 + c + i * 4] = z;
        }
    }
    int tn = t >> 3, tc = t & 7;
    float acc[4] = {0.f, 0.f, 0.f, 0.f};
    for (int kb = 0; kb < 4; ++kb) {
        __syncthreads();
        {
            const float4* w4 = (const float4*)(W2 + kb * 64 * HID);
            float4* s4 = (float4*)wc;
            s4[t] = w4[t]; s4[t + 256] = w4[t + 256];
        }
        __syncthreads();
        for (int k = 0; k < 64; ++k) {
            float zv = zs[tn * 260 + kb * 64 + k];
            float4 w = *(const float4*)&wc[k * HID + tc * 4];
            acc[0] += zv * w.x; acc[1] += zv * w.y;
            acc[2] += zv * w.z; acc[3] += zv * w.w;
        }
    }
    int n = n0 + tn;
    float ps = 0.f, pd = 0.f;
    #pragma unroll
    for (int j = 0; j < 4; ++j) { ps += acc[j] * attS[tc * 4 + j]; pd += acc[j] * attD[tc * 4 + j]; }
    ps += __shfl_xor(ps, 1, 64); ps += __shfl_xor(ps, 2, 64); ps += __shfl_xor(ps, 4, 64);
    pd += __shfl_xor(pd, 1, 64); pd += __shfl_xor(pd, 2, 64); pd += __shfl_xor(pd, 4, 64);
    if (n < NN) {
        ushort4_t o;
        o[0] = f2bf(acc[0]); o[1] = f2bf(acc[1]); o[2] = f2bf(acc[2]); o[3] = f2bf(acc[3]);
        *(ushort4_t*)&h2b[(size_t)n * HID + tc * 4] = o;
        if (tc == 0) { aS2[n] = ps; aD2[n] = pd; }
    }
}

// ---------------- Layer-2 aggregation: SINGLE PASS, 2 dst nodes per wave ----------------
__global__ __launch_bounds__(256) void agg2_kernel(
        const int* __restrict__ rowptr, const int* __restrict__ ssrc,
        const float* __restrict__ aS, const float* __restrict__ aD,
        const unsigned short* __restrict__ h2b, const float* __restrict__ b2,
        float* __restrict__ z2) {
    int wid = (blockIdx.x * 256 + threadIdx.x) >> 6;
    int lane = threadIdx.x & 63;
    int half = lane >> 5, hl = lane & 31;
    int d = wid * 2 + half;
    if (d >= NN) return;
    int start = rowptr[d], end = rowptr[d + 1];
    float adv = aD[d];
    float acc = 0.f, den = 0.f;
    int j = start;
    for (; j + 1 < end; j += 2) {
        int s0 = ssrc[j], s1 = ssrc[j + 1];
        float v0 = bf2f(h2b[(size_t)s0 * HID + hl]);
        float v1 = bf2f(h2b[(size_t)s1 * HID + hl]);
        float e0 = __expf(lrelu(aS[s0] + adv));
        float e1 = __expf(lrelu(aS[s1] + adv));
        acc += e0 * v0; acc += e1 * v1;
        den += e0 + e1;
    }
    if (j < end) {
        int s = ssrc[j];
        float e = __expf(lrelu(aS[s] + adv));
        acc += e * bf2f(h2b[(size_t)s * HID + hl]);
        den += e;
    }
    float invd = 1.f / (den + 1e-16f);
    z2[(size_t)d * HID + hl] = elu1(acc * invd + b2[hl]);
}

// ---------------- Pool partial: 16 blocks per group, LDS reduce + few atomics ----------------
__global__ __launch_bounds__(256) void pool_partial_kernel(
        const float* __restrict__ z2, const int* __restrict__ batch,
        float* __restrict__ pooled) {
    __shared__ float sm[256];
    int g = blockIdx.x >> 4, slice = blockIdx.x & 15;
    int t = threadIdx.x;
    int lo = 0, hi = NN;
    while (lo < hi) { int m = (lo + hi) >> 1; if (batch[m] < g) lo = m + 1; else hi = m; }
    int start = lo;
    hi = NN;
    while (lo < hi) { int m = (lo + hi) >> 1; if (batch[m] < g + 1) lo = m + 1; else hi = m; }
    int end = lo;
    int len = end - start;
    int s0 = start + (int)(((long long)len * slice) >> 4);
    int s1 = start + (int)(((long long)len * (slice + 1)) >> 4);
    int c = t & 31, r = t >> 5;
    float acc = 0.f;
    for (int n = s0 + r; n < s1; n += 8)
        acc += z2[(size_t)n * HID + c];
    sm[t] = acc;
    __syncthreads();
    if (t < 32) {
        float s = 0.f;
        #pragma unroll
        for (int i = 0; i < 8; ++i) s += sm[t + 32 * i];
        atomicAdd(&pooled[g * HID + t], s);
    }
}

// ---------------- Finish: mean + Wo + sigmoid ----------------
__global__ void pool_finish_kernel(const float* __restrict__ pooled,
                                   const int* __restrict__ batch,
                                   const float* __restrict__ Wo, const float* __restrict__ bo,
                                   float* __restrict__ out) {
    int g = threadIdx.x;
    if (g >= NG) return;
    int lo = 0, hi = NN;
    while (lo < hi) { int m = (lo + hi) >> 1; if (batch[m] < g) lo = m + 1; else hi = m; }
    int start = lo;
    hi = NN;
    while (lo < hi) { int m = (lo + hi) >> 1; if (batch[m] < g + 1) lo = m + 1; else hi = m; }
    int end = lo;
    float c = fmaxf((float)(end - start), 1.f);
    float acc = 0.f;
    for (int i = 0; i < HID; ++i) acc += (pooled[g * HID + i] / c) * Wo[i];
    acc += bo[0];
    out[g] = 1.f / (1.f + __expf(-acc));
}

extern "C" void kernel_launch(void* const* d_in, const int* in_sizes, int n_in,
                              void* d_out, int out_size, void* d_ws, size_t ws_size,
                              hipStream_t stream) {
    const float* x     = (const float*)d_in[0];
    const int*   ei    = (const int*)d_in[1];
    const int*   batch = (const int*)d_in[2];
    const float* W1    = (const float*)d_in[3];
    const float* attS1 = (const float*)d_in[4];
    const float* attD1 = (const float*)d_in[5];
    const float* b1    = (const float*)d_in[6];
    const float* W2    = (const float*)d_in[7];
    const float* attS2 = (const float*)d_in[8];
    const float* attD2 = (const float*)d_in[9];
    const float* b2    = (const float*)d_in[10];
    const float* Wo    = (const float*)d_in[11];
    const float* bo    = (const float*)d_in[12];
    float* out = (float*)d_out;

    char* p = (char*)d_ws;
    auto alloc = [&](size_t bytes) {
        char* r = p;
        p += (bytes + 255) & ~(size_t)255;
        return (void*)r;
    };
    unsigned char*  h1f8 = (unsigned char*)alloc((size_t)NN * C1);
    unsigned short* z1b  = (unsigned short*)alloc((size_t)NN * C1 * 2);
    unsigned short* h2b  = (unsigned short*)alloc((size_t)NN * HID * 2);
    float* aS1    = (float*)alloc((size_t)NN * HEADS * 4);
    float* aD1    = (float*)alloc((size_t)NN * HEADS * 4);
    float* z2     = (float*)alloc((size_t)NN * HID * 4);
    float* aS2    = (float*)alloc((size_t)NN * 4);
    float* aD2    = (float*)alloc((size_t)NN * 4);
    int*   rowptr = (int*)alloc((size_t)(NN + 1) * 4);
    int*   cursor = (int*)alloc((size_t)NN * 4);
    int*   ssrc   = (int*)alloc((size_t)ET * 4);
    int*   bsum   = (int*)alloc((size_t)NB_SCAN * 4);
    int*   boff   = (int*)alloc((size_t)NB_SCAN * 4);
    // zero-init region: cnt + pooled (contiguous)
    int*   cnt    = (int*)alloc((size_t)NN * 4);
    float* pooled = (float*)alloc((size_t)NG * HID * 4);
    size_t zero_bytes = (size_t)(p - (char*)cnt);

    hipMemsetAsync(cnt, 0, zero_bytes, stream);
    hist_kernel<<<(ET + 255) / 256, 256, 0, stream>>>(ei, cnt);
    scan_a_kernel<<<NB_SCAN, 256, 0, stream>>>(cnt, rowptr, bsum);
    scan_b_kernel<<<1, 256, 0, stream>>>(bsum, boff, rowptr);
    scan_c_kernel<<<NB_SCAN, 256, 0, stream>>>(rowptr, boff, cursor);
    scatter_kernel<<<(ET + 255) / 256, 256, 0, stream>>>(ei, cursor, ssrc);
    gemm1_kernel<<<(NN + 31) / 32, 256, 0, stream>>>(x, W1, attS1, attD1, h1f8, aS1, aD1);
    agg1_kernel<<<(NN * 64) / 256, 256, 0, stream>>>(rowptr, ssrc, aS1, aD1, h1f8, b1, z1b);
    gemm2_kernel<<<(NN + 31) / 32, 256, 0, stream>>>(z1b, W2, attS2, attD2, h2b, aS2, aD2);
    agg2_kernel<<<(NN / 2 * 64 + 255) / 256, 256, 0, stream>>>(rowptr, ssrc, aS2, aD2, h2b, b2, z2);
    pool_partial_kernel<<<NG * 16, 256, 0, stream>>>(z2, batch, pooled);
    pool_finish_kernel<<<1, 64, 0, stream>>>(pooled, batch, Wo, bo, out);
}

// Round 6
// 342.987 us; speedup vs baseline: 2.5144x; 1.0615x over previous
//
#include <hip/hip_runtime.h>
#include <hip/hip_bf16.h>
#include <math.h>

#define NN 50000
#define NE 800000
#define ET (NE + NN)
#define FIN 128
#define HEADS 8
#define HID 32
#define C1 (HEADS * HID)   // 256
#define NG 64
#define NEG 0.2f
#define NB_SCAN 196        // ceil(NN/256)

typedef __attribute__((ext_vector_type(8))) unsigned short ushort8_t;
typedef __attribute__((ext_vector_type(4))) unsigned short ushort4_t;
typedef __attribute__((ext_vector_type(2))) float float2_t;
typedef __attribute__((ext_vector_type(8))) short bf16x8;
typedef __attribute__((ext_vector_type(4))) float f32x4;

__device__ __forceinline__ float lrelu(float v) { return v > 0.f ? v : NEG * v; }
__device__ __forceinline__ float elu1(float v)  { return v > 0.f ? v : expm1f(v); }
__device__ __forceinline__ unsigned short f2bf(float f) {
    __hip_bfloat16 b = __float2bfloat16(f);
    return *reinterpret_cast<unsigned short*>(&b);
}
__device__ __forceinline__ float bf2f(unsigned short u) {
    return __uint_as_float(((unsigned)u) << 16);
}

// ---------------- CSR build ----------------
__global__ void hist_kernel(const int* __restrict__ ei, int* __restrict__ cnt) {
    int i = blockIdx.x * 256 + threadIdx.x;
    if (i >= ET) return;
    int d = (i < NE) ? ei[NE + i] : (i - NE);
    atomicAdd(&cnt[d], 1);
}

__global__ __launch_bounds__(256) void scan_a_kernel(const int* __restrict__ cnt,
                                                     int* __restrict__ rowptr,
                                                     int* __restrict__ bsum) {
    __shared__ int ws[4];
    int t = threadIdx.x, b = blockIdx.x, gid = b * 256 + t;
    int lane = t & 63, w = t >> 6;
    int v = (gid < NN) ? cnt[gid] : 0;
    int inc = v;
    #pragma unroll
    for (int off = 1; off < 64; off <<= 1) {
        int u = __shfl_up(inc, off, 64);
        if (lane >= off) inc += u;
    }
    if (lane == 63) ws[w] = inc;
    __syncthreads();
    int woff = 0;
    #pragma unroll
    for (int i = 0; i < 4; ++i) if (i < w) woff += ws[i];
    if (gid < NN) rowptr[gid] = woff + inc - v;
    if (t == 255) bsum[b] = woff + inc;
}

__global__ __launch_bounds__(256) void scan_b_kernel(const int* __restrict__ bsum,
                                                     int* __restrict__ boff,
                                                     int* __restrict__ rowptr) {
    __shared__ int ws[4];
    int t = threadIdx.x, lane = t & 63, w = t >> 6;
    int v = (t < NB_SCAN) ? bsum[t] : 0;
    int inc = v;
    #pragma unroll
    for (int off = 1; off < 64; off <<= 1) {
        int u = __shfl_up(inc, off, 64);
        if (lane >= off) inc += u;
    }
    if (lane == 63) ws[w] = inc;
    __syncthreads();
    int woff = 0;
    #pragma unroll
    for (int i = 0; i < 4; ++i) if (i < w) woff += ws[i];
    if (t < NB_SCAN) boff[t] = woff + inc - v;
    if (t == 255) rowptr[NN] = woff + inc;   // grand total = ET
}

__global__ __launch_bounds__(256) void scan_c_kernel(int* __restrict__ rowptr,
                                                     const int* __restrict__ boff,
                                                     int* __restrict__ cursor) {
    int gid = blockIdx.x * 256 + threadIdx.x;
    if (gid >= NN) return;
    int r = rowptr[gid] + boff[blockIdx.x];
    rowptr[gid] = r;
    cursor[gid] = r;
}

__global__ void scatter_kernel(const int* __restrict__ ei, int* __restrict__ cursor,
                               int* __restrict__ ssrc) {
    int i = blockIdx.x * 256 + threadIdx.x;
    if (i >= ET) return;
    int s, d;
    if (i < NE) { s = ei[i]; d = ei[NE + i]; }
    else        { s = i - NE; d = s; }
    int pos = atomicAdd(&cursor[d], 1);
    ssrc[pos] = s;
}

// ---------------- x fp32 -> bf16 row-major ----------------
__global__ __launch_bounds__(256) void cvt_x_kernel(const float* __restrict__ x,
                                                    unsigned short* __restrict__ xb) {
    int i = (blockIdx.x * 256 + threadIdx.x) * 8;
    if (i >= NN * FIN) return;
    float4 f0 = *(const float4*)&x[i];
    float4 f1 = *(const float4*)&x[i + 4];
    ushort8_t o;
    o[0] = f2bf(f0.x); o[1] = f2bf(f0.y); o[2] = f2bf(f0.z); o[3] = f2bf(f0.w);
    o[4] = f2bf(f1.x); o[5] = f2bf(f1.y); o[6] = f2bf(f1.z); o[7] = f2bf(f1.w);
    *(ushort8_t*)&xb[i] = o;
}

// ---------------- W1 fp32 -> bf16 swizzled B-fragments ----------------
// frag (tnt 0..15, ks 0..3): lane L holds B[k=ks*32+(L>>4)*8+j][n=tnt*16+(L&15)], j=0..7
__global__ __launch_bounds__(256) void cvt_w1_kernel(const float* __restrict__ W1,
                                                     unsigned short* __restrict__ w1swz) {
    int t = blockIdx.x * 256 + threadIdx.x;   // 4096 threads
    int fid = t >> 6, lane = t & 63;
    int tnt = fid >> 2, ks = fid & 3;
    int n = tnt * 16 + (lane & 15);
    int k0 = ks * 32 + (lane >> 4) * 8;
    ushort8_t o;
    #pragma unroll
    for (int j = 0; j < 8; ++j) o[j] = f2bf(W1[(k0 + j) * C1 + n]);
    *(ushort8_t*)&w1swz[(size_t)(fid * 64 + lane) * 8] = o;
}

// ---------------- GEMM1 (MFMA bf16): h1 = x @ W1 (fp8 out), fused a_src1/a_dst1 ----------------
// block = 256 (4 waves). Block tile 64 rows x 256 cols. wave: mh=w&1 (32 rows), nh=w>>1 (128 cols).
__global__ __launch_bounds__(256) void gemm1_kernel(
        const unsigned short* __restrict__ xb, const unsigned short* __restrict__ w1swz,
        const float* __restrict__ attS, const float* __restrict__ attD,
        unsigned char* __restrict__ h1f8, float* __restrict__ aS, float* __restrict__ aD) {
    __shared__ float lds[4 * 16 * 132];   // per-wave 16x132 transpose tile (33 KB)
    int t = threadIdx.x, w = t >> 6, lane = t & 63;
    int mh = w & 1, nh = w >> 1;
    int m0 = blockIdx.x * 64 + mh * 32;
    int l15 = lane & 15, l4 = lane >> 4;

    f32x4 acc[2][8];
    #pragma unroll
    for (int mt = 0; mt < 2; ++mt)
        #pragma unroll
        for (int nt = 0; nt < 8; ++nt)
            acc[mt][nt] = (f32x4){0.f, 0.f, 0.f, 0.f};

    int ra = m0 + l15;       if (ra >= NN) ra = NN - 1;
    int rb = m0 + 16 + l15;  if (rb >= NN) rb = NN - 1;
    const unsigned short* a0p = xb + (size_t)ra * FIN + l4 * 8;
    const unsigned short* a1p = xb + (size_t)rb * FIN + l4 * 8;

    #pragma unroll
    for (int ks = 0; ks < 4; ++ks) {
        bf16x8 af0 = *(const bf16x8*)(a0p + ks * 32);
        bf16x8 af1 = *(const bf16x8*)(a1p + ks * 32);
        #pragma unroll
        for (int nt = 0; nt < 8; ++nt) {
            bf16x8 bf = *(const bf16x8*)&w1swz[(size_t)(((nh * 8 + nt) * 4 + ks) * 64 + lane) * 8];
            acc[0][nt] = __builtin_amdgcn_mfma_f32_16x16x32_bf16(af0, bf, acc[0][nt], 0, 0, 0);
            acc[1][nt] = __builtin_amdgcn_mfma_f32_16x16x32_bf16(af1, bf, acc[1][nt], 0, 0, 0);
        }
    }

    // epilogue: per mt, transpose through LDS; lane -> one row x 32 cols (= one head)
    float* wl = lds + w * 16 * 132;
    #pragma unroll
    for (int mt = 0; mt < 2; ++mt) {
        __syncthreads();
        #pragma unroll
        for (int nt = 0; nt < 8; ++nt)
            #pragma unroll
            for (int r = 0; r < 4; ++r)
                wl[(l4 * 4 + r) * 132 + nt * 16 + l15] = acc[mt][nt][r];
        __syncthreads();
        int row_g = m0 + mt * 16 + l15;       // lane&15 = row
        int cch = l4;                          // col chunk of 32 = head within nh
        float v[32];
        #pragma unroll
        for (int i = 0; i < 8; ++i) {
            float4 f = *(const float4*)&wl[l15 * 132 + cch * 32 + i * 4];
            v[i * 4 + 0] = f.x; v[i * 4 + 1] = f.y; v[i * 4 + 2] = f.z; v[i * 4 + 3] = f.w;
        }
        if (row_g < NN) {
            unsigned pk[8];
            #pragma unroll
            for (int i = 0; i < 8; ++i) {
                int p = __builtin_amdgcn_cvt_pk_fp8_f32(v[i * 4 + 0], v[i * 4 + 1], 0, false);
                p = __builtin_amdgcn_cvt_pk_fp8_f32(v[i * 4 + 2], v[i * 4 + 3], p, true);
                pk[i] = (unsigned)p;
            }
            size_t base = (size_t)row_g * C1 + nh * 128 + cch * 32;
            *(uint4*)&h1f8[base]      = make_uint4(pk[0], pk[1], pk[2], pk[3]);
            *(uint4*)&h1f8[base + 16] = make_uint4(pk[4], pk[5], pk[6], pk[7]);
            int h = nh * 4 + cch;
            float ps = 0.f, pd = 0.f;
            #pragma unroll
            for (int i = 0; i < 32; ++i) {
                ps += v[i] * attS[h * 32 + i];
                pd += v[i] * attD[h * 32 + i];
            }
            aS[row_g * HEADS + h] = ps;
            aD[row_g * HEADS + h] = pd;
        }
    }
}

// ---------------- Layer-1 aggregation: SINGLE PASS (num+den), half-wave per edge ----------------
__global__ __launch_bounds__(256) void agg1_kernel(
        const int* __restrict__ rowptr, const int* __restrict__ ssrc,
        const float* __restrict__ aS, const float* __restrict__ aD,
        const unsigned char* __restrict__ h1f8, const float* __restrict__ b1,
        unsigned short* __restrict__ z1b) {
    int d = (blockIdx.x * 256 + threadIdx.x) >> 6;
    int lane = threadIdx.x & 63;
    if (d >= NN) return;
    int start = rowptr[d], end = rowptr[d + 1];
    int half = lane >> 5, hl = lane & 31;
    int h = hl >> 2;                    // head of channels [hl*8, hl*8+8)
    float adh = aD[d * HEADS + h];
    float acc[8];
    #pragma unroll
    for (int i = 0; i < 8; ++i) acc[i] = 0.f;
    float den = 0.f;
    int j = start + half;
    for (; j + 2 < end; j += 4) {
        int s0 = ssrc[j], s1 = ssrc[j + 2];
        uint2 r0 = *(const uint2*)&h1f8[(size_t)s0 * C1 + hl * 8];
        uint2 r1 = *(const uint2*)&h1f8[(size_t)s1 * C1 + hl * 8];
        float e0 = __expf(lrelu(aS[s0 * HEADS + h] + adh));
        float e1 = __expf(lrelu(aS[s1 * HEADS + h] + adh));
        den += e0 + e1;
        {
            float2_t f01 = __builtin_amdgcn_cvt_pk_f32_fp8((int)r0.x, false);
            float2_t f23 = __builtin_amdgcn_cvt_pk_f32_fp8((int)r0.x, true);
            float2_t f45 = __builtin_amdgcn_cvt_pk_f32_fp8((int)r0.y, false);
            float2_t f67 = __builtin_amdgcn_cvt_pk_f32_fp8((int)r0.y, true);
            acc[0] += e0 * f01.x; acc[1] += e0 * f01.y;
            acc[2] += e0 * f23.x; acc[3] += e0 * f23.y;
            acc[4] += e0 * f45.x; acc[5] += e0 * f45.y;
            acc[6] += e0 * f67.x; acc[7] += e0 * f67.y;
        }
        {
            float2_t f01 = __builtin_amdgcn_cvt_pk_f32_fp8((int)r1.x, false);
            float2_t f23 = __builtin_amdgcn_cvt_pk_f32_fp8((int)r1.x, true);
            float2_t f45 = __builtin_amdgcn_cvt_pk_f32_fp8((int)r1.y, false);
            float2_t f67 = __builtin_amdgcn_cvt_pk_f32_fp8((int)r1.y, true);
            acc[0] += e1 * f01.x; acc[1] += e1 * f01.y;
            acc[2] += e1 * f23.x; acc[3] += e1 * f23.y;
            acc[4] += e1 * f45.x; acc[5] += e1 * f45.y;
            acc[6] += e1 * f67.x; acc[7] += e1 * f67.y;
        }
    }
    for (; j < end; j += 2) {
        int s = ssrc[j];
        uint2 raw = *(const uint2*)&h1f8[(size_t)s * C1 + hl * 8];
        float e = __expf(lrelu(aS[s * HEADS + h] + adh));
        den += e;
        float2_t f01 = __builtin_amdgcn_cvt_pk_f32_fp8((int)raw.x, false);
        float2_t f23 = __builtin_amdgcn_cvt_pk_f32_fp8((int)raw.x, true);
        float2_t f45 = __builtin_amdgcn_cvt_pk_f32_fp8((int)raw.y, false);
        float2_t f67 = __builtin_amdgcn_cvt_pk_f32_fp8((int)raw.y, true);
        acc[0] += e * f01.x; acc[1] += e * f01.y;
        acc[2] += e * f23.x; acc[3] += e * f23.y;
        acc[4] += e * f45.x; acc[5] += e * f45.y;
        acc[6] += e * f67.x; acc[7] += e * f67.y;
    }
    den += __shfl_xor(den, 32, 64);
    #pragma unroll
    for (int i = 0; i < 8; ++i) acc[i] += __shfl_xor(acc[i], 32, 64);
    float invd = 1.f / (den + 1e-16f);
    int cbase = hl * 8 + half * 4;
    float4 bb = *(const float4*)&b1[cbase];
    ushort4_t o;
    o[0] = f2bf(elu1(acc[half * 4 + 0] * invd + bb.x));
    o[1] = f2bf(elu1(acc[half * 4 + 1] * invd + bb.y));
    o[2] = f2bf(elu1(acc[half * 4 + 2] * invd + bb.z));
    o[3] = f2bf(elu1(acc[half * 4 + 3] * invd + bb.w));
    *(ushort4_t*)&z1b[(size_t)d * C1 + cbase] = o;
}

// ---------------- GEMM2: h2 = z1 @ W2 (bf16 in/out), fused a_src2/a_dst2 ----------------
__global__ __launch_bounds__(256) void gemm2_kernel(
        const unsigned short* __restrict__ z1b, const float* __restrict__ W2,
        const float* __restrict__ attS, const float* __restrict__ attD,
        unsigned short* __restrict__ h2b, float* __restrict__ aS2, float* __restrict__ aD2) {
    __shared__ float zs[32 * 260];
    __shared__ float wc[64 * HID];
    int t = threadIdx.x;
    int n0 = blockIdx.x * 32;
    {
        int f = t * 32, r = f >> 8, c = f & 255;
        if (n0 + r < NN) {
            const ushort8_t* zr = (const ushort8_t*)&z1b[(size_t)(n0 + r) * C1 + c];
            #pragma unroll
            for (int i = 0; i < 4; ++i) {
                ushort8_t u = zr[i];
                *(float4*)&zs[r * 260 + c + i * 8] =
                    make_float4(bf2f(u[0]), bf2f(u[1]), bf2f(u[2]), bf2f(u[3]));
                *(float4*)&zs[r * 260 + c + i * 8 + 4] =
                    make_float4(bf2f(u[4]), bf2f(u[5]), bf2f(u[6]), bf2f(u[7]));
            }
        } else {
            float4 z = make_float4(0.f, 0.f, 0.f, 0.f);
            #pragma unroll
            for (int i = 0; i < 8; ++i) *(float4*)&zs[r * 260 + c + i * 4] = z;
        }
    }
    int tn = t >> 3, tc = t & 7;
    float acc[4] = {0.f, 0.f, 0.f, 0.f};
    for (int kb = 0; kb < 4; ++kb) {
        __syncthreads();
        {
            const float4* w4 = (const float4*)(W2 + kb * 64 * HID);
            float4* s4 = (float4*)wc;
            s4[t] = w4[t]; s4[t + 256] = w4[t + 256];
        }
        __syncthreads();
        for (int k = 0; k < 64; ++k) {
            float zv = zs[tn * 260 + kb * 64 + k];
            float4 w = *(const float4*)&wc[k * HID + tc * 4];
            acc[0] += zv * w.x; acc[1] += zv * w.y;
            acc[2] += zv * w.z; acc[3] += zv * w.w;
        }
    }
    int n = n0 + tn;
    float ps = 0.f, pd = 0.f;
    #pragma unroll
    for (int j = 0; j < 4; ++j) { ps += acc[j] * attS[tc * 4 + j]; pd += acc[j] * attD[tc * 4 + j]; }
    ps += __shfl_xor(ps, 1, 64); ps += __shfl_xor(ps, 2, 64); ps += __shfl_xor(ps, 4, 64);
    pd += __shfl_xor(pd, 1, 64); pd += __shfl_xor(pd, 2, 64); pd += __shfl_xor(pd, 4, 64);
    if (n < NN) {
        ushort4_t o;
        o[0] = f2bf(acc[0]); o[1] = f2bf(acc[1]); o[2] = f2bf(acc[2]); o[3] = f2bf(acc[3]);
        *(ushort4_t*)&h2b[(size_t)n * HID + tc * 4] = o;
        if (tc == 0) { aS2[n] = ps; aD2[n] = pd; }
    }
}

// ---------------- Layer-2 aggregation: SINGLE PASS, 2 dst nodes per wave ----------------
__global__ __launch_bounds__(256) void agg2_kernel(
        const int* __restrict__ rowptr, const int* __restrict__ ssrc,
        const float* __restrict__ aS, const float* __restrict__ aD,
        const unsigned short* __restrict__ h2b, const float* __restrict__ b2,
        float* __restrict__ z2) {
    int wid = (blockIdx.x * 256 + threadIdx.x) >> 6;
    int lane = threadIdx.x & 63;
    int half = lane >> 5, hl = lane & 31;
    int d = wid * 2 + half;
    if (d >= NN) return;
    int start = rowptr[d], end = rowptr[d + 1];
    float adv = aD[d];
    float acc = 0.f, den = 0.f;
    int j = start;
    for (; j + 1 < end; j += 2) {
        int s0 = ssrc[j], s1 = ssrc[j + 1];
        float v0 = bf2f(h2b[(size_t)s0 * HID + hl]);
        float v1 = bf2f(h2b[(size_t)s1 * HID + hl]);
        float e0 = __expf(lrelu(aS[s0] + adv));
        float e1 = __expf(lrelu(aS[s1] + adv));
        acc += e0 * v0; acc += e1 * v1;
        den += e0 + e1;
    }
    if (j < end) {
        int s = ssrc[j];
        float e = __expf(lrelu(aS[s] + adv));
        acc += e * bf2f(h2b[(size_t)s * HID + hl]);
        den += e;
    }
    float invd = 1.f / (den + 1e-16f);
    z2[(size_t)d * HID + hl] = elu1(acc * invd + b2[hl]);
}

// ---------------- Pool partial: 16 blocks per group, LDS reduce + few atomics ----------------
__global__ __launch_bounds__(256) void pool_partial_kernel(
        const float* __restrict__ z2, const int* __restrict__ batch,
        float* __restrict__ pooled) {
    __shared__ float sm[256];
    int g = blockIdx.x >> 4, slice = blockIdx.x & 15;
    int t = threadIdx.x;
    int lo = 0, hi = NN;
    while (lo < hi) { int m = (lo + hi) >> 1; if (batch[m] < g) lo = m + 1; else hi = m; }
    int start = lo;
    hi = NN;
    while (lo < hi) { int m = (lo + hi) >> 1; if (batch[m] < g + 1) lo = m + 1; else hi = m; }
    int end = lo;
    int len = end - start;
    int s0 = start + (int)(((long long)len * slice) >> 4);
    int s1 = start + (int)(((long long)len * (slice + 1)) >> 4);
    int c = t & 31, r = t >> 5;
    float acc = 0.f;
    for (int n = s0 + r; n < s1; n += 8)
        acc += z2[(size_t)n * HID + c];
    sm[t] = acc;
    __syncthreads();
    if (t < 32) {
        float s = 0.f;
        #pragma unroll
        for (int i = 0; i < 8; ++i) s += sm[t + 32 * i];
        atomicAdd(&pooled[g * HID + t], s);
    }
}

// ---------------- Finish: mean + Wo + sigmoid ----------------
__global__ void pool_finish_kernel(const float* __restrict__ pooled,
                                   const int* __restrict__ batch,
                                   const float* __restrict__ Wo, const float* __restrict__ bo,
                                   float* __restrict__ out) {
    int g = threadIdx.x;
    if (g >= NG) return;
    int lo = 0, hi = NN;
    while (lo < hi) { int m = (lo + hi) >> 1; if (batch[m] < g) lo = m + 1; else hi = m; }
    int start = lo;
    hi = NN;
    while (lo < hi) { int m = (lo + hi) >> 1; if (batch[m] < g + 1) lo = m + 1; else hi = m; }
    int end = lo;
    float c = fmaxf((float)(end - start), 1.f);
    float acc = 0.f;
    for (int i = 0; i < HID; ++i) acc += (pooled[g * HID + i] / c) * Wo[i];
    acc += bo[0];
    out[g] = 1.f / (1.f + __expf(-acc));
}

extern "C" void kernel_launch(void* const* d_in, const int* in_sizes, int n_in,
                              void* d_out, int out_size, void* d_ws, size_t ws_size,
                              hipStream_t stream) {
    const float* x     = (const float*)d_in[0];
    const int*   ei    = (const int*)d_in[1];
    const int*   batch = (const int*)d_in[2];
    const float* W1    = (const float*)d_in[3];
    const float* attS1 = (const float*)d_in[4];
    const float* attD1 = (const float*)d_in[5];
    const float* b1    = (const float*)d_in[6];
    const float* W2    = (const float*)d_in[7];
    const float* attS2 = (const float*)d_in[8];
    const float* attD2 = (const float*)d_in[9];
    const float* b2    = (const float*)d_in[10];
    const float* Wo    = (const float*)d_in[11];
    const float* bo    = (const float*)d_in[12];
    float* out = (float*)d_out;

    char* p = (char*)d_ws;
    auto alloc = [&](size_t bytes) {
        char* r = p;
        p += (bytes + 255) & ~(size_t)255;
        return (void*)r;
    };
    unsigned char*  h1f8  = (unsigned char*)alloc((size_t)NN * C1);
    unsigned short* xb    = (unsigned short*)alloc((size_t)NN * FIN * 2);
    unsigned short* w1swz = (unsigned short*)alloc((size_t)FIN * C1 * 2);
    unsigned short* z1b   = (unsigned short*)alloc((size_t)NN * C1 * 2);
    unsigned short* h2b   = (unsigned short*)alloc((size_t)NN * HID * 2);
    float* aS1    = (float*)alloc((size_t)NN * HEADS * 4);
    float* aD1    = (float*)alloc((size_t)NN * HEADS * 4);
    float* z2     = (float*)alloc((size_t)NN * HID * 4);
    float* aS2    = (float*)alloc((size_t)NN * 4);
    float* aD2    = (float*)alloc((size_t)NN * 4);
    int*   rowptr = (int*)alloc((size_t)(NN + 1) * 4);
    int*   cursor = (int*)alloc((size_t)NN * 4);
    int*   ssrc   = (int*)alloc((size_t)ET * 4);
    int*   bsum   = (int*)alloc((size_t)NB_SCAN * 4);
    int*   boff   = (int*)alloc((size_t)NB_SCAN * 4);
    // zero-init region: cnt + pooled (contiguous)
    int*   cnt    = (int*)alloc((size_t)NN * 4);
    float* pooled = (float*)alloc((size_t)NG * HID * 4);
    size_t zero_bytes = (size_t)(p - (char*)cnt);

    hipMemsetAsync(cnt, 0, zero_bytes, stream);
    hist_kernel<<<(ET + 255) / 256, 256, 0, stream>>>(ei, cnt);
    scan_a_kernel<<<NB_SCAN, 256, 0, stream>>>(cnt, rowptr, bsum);
    scan_b_kernel<<<1, 256, 0, stream>>>(bsum, boff, rowptr);
    scan_c_kernel<<<NB_SCAN, 256, 0, stream>>>(rowptr, boff, cursor);
    scatter_kernel<<<(ET + 255) / 256, 256, 0, stream>>>(ei, cursor, ssrc);
    cvt_x_kernel<<<(NN * FIN / 8 + 255) / 256, 256, 0, stream>>>(x, xb);
    cvt_w1_kernel<<<16, 256, 0, stream>>>(W1, w1swz);
    gemm1_kernel<<<(NN + 63) / 64, 256, 0, stream>>>(xb, w1swz, attS1, attD1, h1f8, aS1, aD1);
    agg1_kernel<<<(NN * 64) / 256, 256, 0, stream>>>(rowptr, ssrc, aS1, aD1, h1f8, b1, z1b);
    gemm2_kernel<<<(NN + 31) / 32, 256, 0, stream>>>(z1b, W2, attS2, attD2, h2b, aS2, aD2);
    agg2_kernel<<<(NN / 2 * 64 + 255) / 256, 256, 0, stream>>>(rowptr, ssrc, aS2, aD2, h2b, b2, z2);
    pool_partial_kernel<<<NG * 16, 256, 0, stream>>>(z2, batch, pooled);
    pool_finish_kernel<<<1, 64, 0, stream>>>(pooled, batch, Wo, bo, out);
}

// Round 7
// 271.589 us; speedup vs baseline: 3.1754x; 1.2629x over previous
//
#include <hip/hip_runtime.h>
#include <hip/hip_bf16.h>
#include <math.h>

#define NN 50000
#define NE 800000
#define ET (NE + NN)
#define FIN 128
#define HEADS 8
#define HID 32
#define C1 (HEADS * HID)   // 256
#define NG 64
#define NEG 0.2f

#define EPB 2048           // edges per block in bucket scatter
#define NBKT 782           // ceil(NN/64)
#define CAP 2048           // slots per bucket (expected ~1087, 2048 is ~29 sigma)

typedef __attribute__((ext_vector_type(8))) unsigned short ushort8_t;
typedef __attribute__((ext_vector_type(4))) unsigned short ushort4_t;
typedef __attribute__((ext_vector_type(2))) float float2_t;
typedef __attribute__((ext_vector_type(8))) short bf16x8;
typedef __attribute__((ext_vector_type(4))) float f32x4;

__device__ __forceinline__ float lrelu(float v) { return v > 0.f ? v : NEG * v; }
__device__ __forceinline__ float elu1(float v)  { return v > 0.f ? v : expm1f(v); }
__device__ __forceinline__ unsigned short f2bf(float f) {
    __hip_bfloat16 b = __float2bfloat16(f);
    return *reinterpret_cast<unsigned short*>(&b);
}
__device__ __forceinline__ float bf2f(unsigned short u) {
    return __uint_as_float(((unsigned)u) << 16);
}

// ---------------- CSR build: two-level counting sort ----------------
// Pass A: bucket edges by dst>>6 into fixed-cap regions.
__global__ __launch_bounds__(256) void bkt_scatter_kernel(const int* __restrict__ ei,
                                                          int* __restrict__ bcur,
                                                          uint2* __restrict__ bkt) {
    __shared__ int es[EPB];    // 8 KB
    __shared__ int ed[EPB];    // 8 KB
    __shared__ int lh[NBKT];   // 3.1 KB: count -> global base -> cursor
    int t = threadIdx.x;
    int base = blockIdx.x * EPB;
    int nloc = ET - base; if (nloc > EPB) nloc = EPB;
    for (int i = t; i < NBKT; i += 256) lh[i] = 0;
    __syncthreads();
    for (int k = t; k < nloc; k += 256) {
        int i = base + k;
        int s, d;
        if (i < NE) { s = ei[i]; d = ei[NE + i]; }
        else        { s = i - NE; d = s; }
        es[k] = s; ed[k] = d;
        atomicAdd(&lh[d >> 6], 1);
    }
    __syncthreads();
    for (int i = t; i < NBKT; i += 256) {
        int c = lh[i];
        lh[i] = c ? atomicAdd(&bcur[i], c) : 0;
    }
    __syncthreads();
    for (int k = t; k < nloc; k += 256) {
        int d = ed[k];
        int b = d >> 6;
        int pos = atomicAdd(&lh[b], 1);
        if (pos < CAP) bkt[(size_t)b * CAP + pos] = make_uint2((unsigned)es[k], (unsigned)d);
    }
}

// scan 782 bucket totals -> global bases; also rowptr[NN] = ET
__global__ __launch_bounds__(256) void bkt_scan_kernel(const int* __restrict__ bcur,
                                                       int* __restrict__ bbase,
                                                       int* __restrict__ rowptr) {
    __shared__ int wsum[4];
    int t = threadIdx.x, lane = t & 63, w = t >> 6;
    int idx = t * 4;
    int a0 = (idx + 0 < NBKT) ? bcur[idx + 0] : 0;
    int a1 = (idx + 1 < NBKT) ? bcur[idx + 1] : 0;
    int a2 = (idx + 2 < NBKT) ? bcur[idx + 2] : 0;
    int a3 = (idx + 3 < NBKT) ? bcur[idx + 3] : 0;
    int v = a0 + a1 + a2 + a3;
    int inc = v;
    #pragma unroll
    for (int off = 1; off < 64; off <<= 1) {
        int u = __shfl_up(inc, off, 64);
        if (lane >= off) inc += u;
    }
    if (lane == 63) wsum[w] = inc;
    __syncthreads();
    int woff = 0;
    #pragma unroll
    for (int i = 0; i < 4; ++i) if (i < w) woff += wsum[i];
    int excl = woff + inc - v;
    if (idx + 0 < NBKT) bbase[idx + 0] = excl;
    if (idx + 1 < NBKT) bbase[idx + 1] = excl + a0;
    if (idx + 2 < NBKT) bbase[idx + 2] = excl + a0 + a1;
    if (idx + 3 < NBKT) bbase[idx + 3] = excl + a0 + a1 + a2;
    if (t == 255) rowptr[NN] = woff + inc;   // = ET
}

// Pass B: one block per bucket -> rowptr + ssrc (contiguous window per bucket)
__global__ __launch_bounds__(256) void csr_kernel(const uint2* __restrict__ bkt,
                                                  const int* __restrict__ bcur,
                                                  const int* __restrict__ bbase,
                                                  int* __restrict__ rowptr,
                                                  int* __restrict__ ssrc) {
    __shared__ int nb[64];
    __shared__ int nc[64];
    int b = blockIdx.x, t = threadIdx.x;
    int cnt = bcur[b]; if (cnt > CAP) cnt = CAP;
    int gbase = bbase[b];
    if (t < 64) nc[t] = 0;
    __syncthreads();
    const uint2* e = bkt + (size_t)b * CAP;
    for (int k = t; k < cnt; k += 256)
        atomicAdd(&nc[e[k].y & 63], 1);
    __syncthreads();
    if (t < 64) {
        int v = nc[t];
        int inc = v;
        #pragma unroll
        for (int off = 1; off < 64; off <<= 1) {
            int u = __shfl_up(inc, off, 64);
            if (t >= off) inc += u;
        }
        int start = gbase + inc - v;
        nb[t] = start;
        int node = b * 64 + t;
        if (node < NN) rowptr[node] = start;
    }
    __syncthreads();
    for (int k = t; k < cnt; k += 256) {
        uint2 ed = e[k];
        int pos = atomicAdd(&nb[ed.y & 63], 1);
        ssrc[pos] = (int)ed.x;
    }
}

// ---------------- x fp32 -> bf16 row-major ----------------
__global__ __launch_bounds__(256) void cvt_x_kernel(const float* __restrict__ x,
                                                    unsigned short* __restrict__ xb) {
    int i = (blockIdx.x * 256 + threadIdx.x) * 8;
    if (i >= NN * FIN) return;
    float4 f0 = *(const float4*)&x[i];
    float4 f1 = *(const float4*)&x[i + 4];
    ushort8_t o;
    o[0] = f2bf(f0.x); o[1] = f2bf(f0.y); o[2] = f2bf(f0.z); o[3] = f2bf(f0.w);
    o[4] = f2bf(f1.x); o[5] = f2bf(f1.y); o[6] = f2bf(f1.z); o[7] = f2bf(f1.w);
    *(ushort8_t*)&xb[i] = o;
}

// ---------------- W1 fp32 -> bf16 swizzled B-fragments ----------------
__global__ __launch_bounds__(256) void cvt_w1_kernel(const float* __restrict__ W1,
                                                     unsigned short* __restrict__ w1swz) {
    int t = blockIdx.x * 256 + threadIdx.x;   // 4096 threads
    int fid = t >> 6, lane = t & 63;
    int tnt = fid >> 2, ks = fid & 3;
    int n = tnt * 16 + (lane & 15);
    int k0 = ks * 32 + (lane >> 4) * 8;
    ushort8_t o;
    #pragma unroll
    for (int j = 0; j < 8; ++j) o[j] = f2bf(W1[(k0 + j) * C1 + n]);
    *(ushort8_t*)&w1swz[(size_t)(fid * 64 + lane) * 8] = o;
}

// ---------------- GEMM1 (MFMA bf16): h1 = x @ W1 (fp8 out), fused a_src1/a_dst1 ----------------
__global__ __launch_bounds__(256) void gemm1_kernel(
        const unsigned short* __restrict__ xb, const unsigned short* __restrict__ w1swz,
        const float* __restrict__ attS, const float* __restrict__ attD,
        unsigned char* __restrict__ h1f8, float* __restrict__ aS, float* __restrict__ aD) {
    __shared__ float lds[4 * 16 * 132];
    int t = threadIdx.x, w = t >> 6, lane = t & 63;
    int mh = w & 1, nh = w >> 1;
    int m0 = blockIdx.x * 64 + mh * 32;
    int l15 = lane & 15, l4 = lane >> 4;

    f32x4 acc[2][8];
    #pragma unroll
    for (int mt = 0; mt < 2; ++mt)
        #pragma unroll
        for (int nt = 0; nt < 8; ++nt)
            acc[mt][nt] = (f32x4){0.f, 0.f, 0.f, 0.f};

    int ra = m0 + l15;       if (ra >= NN) ra = NN - 1;
    int rb = m0 + 16 + l15;  if (rb >= NN) rb = NN - 1;
    const unsigned short* a0p = xb + (size_t)ra * FIN + l4 * 8;
    const unsigned short* a1p = xb + (size_t)rb * FIN + l4 * 8;

    #pragma unroll
    for (int ks = 0; ks < 4; ++ks) {
        bf16x8 af0 = *(const bf16x8*)(a0p + ks * 32);
        bf16x8 af1 = *(const bf16x8*)(a1p + ks * 32);
        #pragma unroll
        for (int nt = 0; nt < 8; ++nt) {
            bf16x8 bf = *(const bf16x8*)&w1swz[(size_t)(((nh * 8 + nt) * 4 + ks) * 64 + lane) * 8];
            acc[0][nt] = __builtin_amdgcn_mfma_f32_16x16x32_bf16(af0, bf, acc[0][nt], 0, 0, 0);
            acc[1][nt] = __builtin_amdgcn_mfma_f32_16x16x32_bf16(af1, bf, acc[1][nt], 0, 0, 0);
        }
    }

    float* wl = lds + w * 16 * 132;
    #pragma unroll
    for (int mt = 0; mt < 2; ++mt) {
        __syncthreads();
        #pragma unroll
        for (int nt = 0; nt < 8; ++nt)
            #pragma unroll
            for (int r = 0; r < 4; ++r)
                wl[(l4 * 4 + r) * 132 + nt * 16 + l15] = acc[mt][nt][r];
        __syncthreads();
        int row_g = m0 + mt * 16 + l15;
        int cch = l4;
        float v[32];
        #pragma unroll
        for (int i = 0; i < 8; ++i) {
            float4 f = *(const float4*)&wl[l15 * 132 + cch * 32 + i * 4];
            v[i * 4 + 0] = f.x; v[i * 4 + 1] = f.y; v[i * 4 + 2] = f.z; v[i * 4 + 3] = f.w;
        }
        if (row_g < NN) {
            unsigned pk[8];
            #pragma unroll
            for (int i = 0; i < 8; ++i) {
                int p = __builtin_amdgcn_cvt_pk_fp8_f32(v[i * 4 + 0], v[i * 4 + 1], 0, false);
                p = __builtin_amdgcn_cvt_pk_fp8_f32(v[i * 4 + 2], v[i * 4 + 3], p, true);
                pk[i] = (unsigned)p;
            }
            size_t base = (size_t)row_g * C1 + nh * 128 + cch * 32;
            *(uint4*)&h1f8[base]      = make_uint4(pk[0], pk[1], pk[2], pk[3]);
            *(uint4*)&h1f8[base + 16] = make_uint4(pk[4], pk[5], pk[6], pk[7]);
            int h = nh * 4 + cch;
            float ps = 0.f, pd = 0.f;
            #pragma unroll
            for (int i = 0; i < 32; ++i) {
                ps += v[i] * attS[h * 32 + i];
                pd += v[i] * attD[h * 32 + i];
            }
            aS[row_g * HEADS + h] = ps;
            aD[row_g * HEADS + h] = pd;
        }
    }
}

// ---------------- Layer-1 aggregation: SINGLE PASS (num+den), half-wave per edge ----------------
__global__ __launch_bounds__(256) void agg1_kernel(
        const int* __restrict__ rowptr, const int* __restrict__ ssrc,
        const float* __restrict__ aS, const float* __restrict__ aD,
        const unsigned char* __restrict__ h1f8, const float* __restrict__ b1,
        unsigned short* __restrict__ z1b) {
    int d = (blockIdx.x * 256 + threadIdx.x) >> 6;
    int lane = threadIdx.x & 63;
    if (d >= NN) return;
    int start = rowptr[d], end = rowptr[d + 1];
    int half = lane >> 5, hl = lane & 31;
    int h = hl >> 2;
    float adh = aD[d * HEADS + h];
    float acc[8];
    #pragma unroll
    for (int i = 0; i < 8; ++i) acc[i] = 0.f;
    float den = 0.f;
    int j = start + half;
    for (; j + 2 < end; j += 4) {
        int s0 = ssrc[j], s1 = ssrc[j + 2];
        uint2 r0 = *(const uint2*)&h1f8[(size_t)s0 * C1 + hl * 8];
        uint2 r1 = *(const uint2*)&h1f8[(size_t)s1 * C1 + hl * 8];
        float e0 = __expf(lrelu(aS[s0 * HEADS + h] + adh));
        float e1 = __expf(lrelu(aS[s1 * HEADS + h] + adh));
        den += e0 + e1;
        {
            float2_t f01 = __builtin_amdgcn_cvt_pk_f32_fp8((int)r0.x, false);
            float2_t f23 = __builtin_amdgcn_cvt_pk_f32_fp8((int)r0.x, true);
            float2_t f45 = __builtin_amdgcn_cvt_pk_f32_fp8((int)r0.y, false);
            float2_t f67 = __builtin_amdgcn_cvt_pk_f32_fp8((int)r0.y, true);
            acc[0] += e0 * f01.x; acc[1] += e0 * f01.y;
            acc[2] += e0 * f23.x; acc[3] += e0 * f23.y;
            acc[4] += e0 * f45.x; acc[5] += e0 * f45.y;
            acc[6] += e0 * f67.x; acc[7] += e0 * f67.y;
        }
        {
            float2_t f01 = __builtin_amdgcn_cvt_pk_f32_fp8((int)r1.x, false);
            float2_t f23 = __builtin_amdgcn_cvt_pk_f32_fp8((int)r1.x, true);
            float2_t f45 = __builtin_amdgcn_cvt_pk_f32_fp8((int)r1.y, false);
            float2_t f67 = __builtin_amdgcn_cvt_pk_f32_fp8((int)r1.y, true);
            acc[0] += e1 * f01.x; acc[1] += e1 * f01.y;
            acc[2] += e1 * f23.x; acc[3] += e1 * f23.y;
            acc[4] += e1 * f45.x; acc[5] += e1 * f45.y;
            acc[6] += e1 * f67.x; acc[7] += e1 * f67.y;
        }
    }
    for (; j < end; j += 2) {
        int s = ssrc[j];
        uint2 raw = *(const uint2*)&h1f8[(size_t)s * C1 + hl * 8];
        float e = __expf(lrelu(aS[s * HEADS + h] + adh));
        den += e;
        float2_t f01 = __builtin_amdgcn_cvt_pk_f32_fp8((int)raw.x, false);
        float2_t f23 = __builtin_amdgcn_cvt_pk_f32_fp8((int)raw.x, true);
        float2_t f45 = __builtin_amdgcn_cvt_pk_f32_fp8((int)raw.y, false);
        float2_t f67 = __builtin_amdgcn_cvt_pk_f32_fp8((int)raw.y, true);
        acc[0] += e * f01.x; acc[1] += e * f01.y;
        acc[2] += e * f23.x; acc[3] += e * f23.y;
        acc[4] += e * f45.x; acc[5] += e * f45.y;
        acc[6] += e * f67.x; acc[7] += e * f67.y;
    }
    den += __shfl_xor(den, 32, 64);
    #pragma unroll
    for (int i = 0; i < 8; ++i) acc[i] += __shfl_xor(acc[i], 32, 64);
    float invd = 1.f / (den + 1e-16f);
    int cbase = hl * 8 + half * 4;
    float4 bb = *(const float4*)&b1[cbase];
    ushort4_t o;
    o[0] = f2bf(elu1(acc[half * 4 + 0] * invd + bb.x));
    o[1] = f2bf(elu1(acc[half * 4 + 1] * invd + bb.y));
    o[2] = f2bf(elu1(acc[half * 4 + 2] * invd + bb.z));
    o[3] = f2bf(elu1(acc[half * 4 + 3] * invd + bb.w));
    *(ushort4_t*)&z1b[(size_t)d * C1 + cbase] = o;
}

// ---------------- GEMM2: h2 = z1 @ W2 (bf16 in/out), fused a_src2/a_dst2 ----------------
__global__ __launch_bounds__(256) void gemm2_kernel(
        const unsigned short* __restrict__ z1b, const float* __restrict__ W2,
        const float* __restrict__ attS, const float* __restrict__ attD,
        unsigned short* __restrict__ h2b, float* __restrict__ aS2, float* __restrict__ aD2) {
    __shared__ float zs[32 * 260];
    __shared__ float wc[64 * HID];
    int t = threadIdx.x;
    int n0 = blockIdx.x * 32;
    {
        int f = t * 32, r = f >> 8, c = f & 255;
        if (n0 + r < NN) {
            const ushort8_t* zr = (const ushort8_t*)&z1b[(size_t)(n0 + r) * C1 + c];
            #pragma unroll
            for (int i = 0; i < 4; ++i) {
                ushort8_t u = zr[i];
                *(float4*)&zs[r * 260 + c + i * 8] =
                    make_float4(bf2f(u[0]), bf2f(u[1]), bf2f(u[2]), bf2f(u[3]));
                *(float4*)&zs[r * 260 + c + i * 8 + 4] =
                    make_float4(bf2f(u[4]), bf2f(u[5]), bf2f(u[6]), bf2f(u[7]));
            }
        } else {
            float4 z = make_float4(0.f, 0.f, 0.f, 0.f);
            #pragma unroll
            for (int i = 0; i < 8; ++i) *(float4*)&zs[r * 260 + c + i * 4] = z;
        }
    }
    int tn = t >> 3, tc = t & 7;
    float acc[4] = {0.f, 0.f, 0.f, 0.f};
    for (int kb = 0; kb < 4; ++kb) {
        __syncthreads();
        {
            const float4* w4 = (const float4*)(W2 + kb * 64 * HID);
            float4* s4 = (float4*)wc;
            s4[t] = w4[t]; s4[t + 256] = w4[t + 256];
        }
        __syncthreads();
        for (int k = 0; k < 64; ++k) {
            float zv = zs[tn * 260 + kb * 64 + k];
            float4 w = *(const float4*)&wc[k * HID + tc * 4];
            acc[0] += zv * w.x; acc[1] += zv * w.y;
            acc[2] += zv * w.z; acc[3] += zv * w.w;
        }
    }
    int n = n0 + tn;
    float ps = 0.f, pd = 0.f;
    #pragma unroll
    for (int j = 0; j < 4; ++j) { ps += acc[j] * attS[tc * 4 + j]; pd += acc[j] * attD[tc * 4 + j]; }
    ps += __shfl_xor(ps, 1, 64); ps += __shfl_xor(ps, 2, 64); ps += __shfl_xor(ps, 4, 64);
    pd += __shfl_xor(pd, 1, 64); pd += __shfl_xor(pd, 2, 64); pd += __shfl_xor(pd, 4, 64);
    if (n < NN) {
        ushort4_t o;
        o[0] = f2bf(acc[0]); o[1] = f2bf(acc[1]); o[2] = f2bf(acc[2]); o[3] = f2bf(acc[3]);
        *(ushort4_t*)&h2b[(size_t)n * HID + tc * 4] = o;
        if (tc == 0) { aS2[n] = ps; aD2[n] = pd; }
    }
}

// ---------------- Layer-2 aggregation: SINGLE PASS, 2 dst nodes per wave ----------------
__global__ __launch_bounds__(256) void agg2_kernel(
        const int* __restrict__ rowptr, const int* __restrict__ ssrc,
        const float* __restrict__ aS, const float* __restrict__ aD,
        const unsigned short* __restrict__ h2b, const float* __restrict__ b2,
        float* __restrict__ z2) {
    int wid = (blockIdx.x * 256 + threadIdx.x) >> 6;
    int lane = threadIdx.x & 63;
    int half = lane >> 5, hl = lane & 31;
    int d = wid * 2 + half;
    if (d >= NN) return;
    int start = rowptr[d], end = rowptr[d + 1];
    float adv = aD[d];
    float acc = 0.f, den = 0.f;
    int j = start;
    for (; j + 1 < end; j += 2) {
        int s0 = ssrc[j], s1 = ssrc[j + 1];
        float v0 = bf2f(h2b[(size_t)s0 * HID + hl]);
        float v1 = bf2f(h2b[(size_t)s1 * HID + hl]);
        float e0 = __expf(lrelu(aS[s0] + adv));
        float e1 = __expf(lrelu(aS[s1] + adv));
        acc += e0 * v0; acc += e1 * v1;
        den += e0 + e1;
    }
    if (j < end) {
        int s = ssrc[j];
        float e = __expf(lrelu(aS[s] + adv));
        acc += e * bf2f(h2b[(size_t)s * HID + hl]);
        den += e;
    }
    float invd = 1.f / (den + 1e-16f);
    z2[(size_t)d * HID + hl] = elu1(acc * invd + b2[hl]);
}

// ---------------- Pool partial: 16 blocks per group, LDS reduce + few atomics ----------------
__global__ __launch_bounds__(256) void pool_partial_kernel(
        const float* __restrict__ z2, const int* __restrict__ batch,
        float* __restrict__ pooled) {
    __shared__ float sm[256];
    int g = blockIdx.x >> 4, slice = blockIdx.x & 15;
    int t = threadIdx.x;
    int lo = 0, hi = NN;
    while (lo < hi) { int m = (lo + hi) >> 1; if (batch[m] < g) lo = m + 1; else hi = m; }
    int start = lo;
    hi = NN;
    while (lo < hi) { int m = (lo + hi) >> 1; if (batch[m] < g + 1) lo = m + 1; else hi = m; }
    int end = lo;
    int len = end - start;
    int s0 = start + (int)(((long long)len * slice) >> 4);
    int s1 = start + (int)(((long long)len * (slice + 1)) >> 4);
    int c = t & 31, r = t >> 5;
    float acc = 0.f;
    for (int n = s0 + r; n < s1; n += 8)
        acc += z2[(size_t)n * HID + c];
    sm[t] = acc;
    __syncthreads();
    if (t < 32) {
        float s = 0.f;
        #pragma unroll
        for (int i = 0; i < 8; ++i) s += sm[t + 32 * i];
        atomicAdd(&pooled[g * HID + t], s);
    }
}

// ---------------- Finish: mean + Wo + sigmoid ----------------
__global__ void pool_finish_kernel(const float* __restrict__ pooled,
                                   const int* __restrict__ batch,
                                   const float* __restrict__ Wo, const float* __restrict__ bo,
                                   float* __restrict__ out) {
    int g = threadIdx.x;
    if (g >= NG) return;
    int lo = 0, hi = NN;
    while (lo < hi) { int m = (lo + hi) >> 1; if (batch[m] < g) lo = m + 1; else hi = m; }
    int start = lo;
    hi = NN;
    while (lo < hi) { int m = (lo + hi) >> 1; if (batch[m] < g + 1) lo = m + 1; else hi = m; }
    int end = lo;
    float c = fmaxf((float)(end - start), 1.f);
    float acc = 0.f;
    for (int i = 0; i < HID; ++i) acc += (pooled[g * HID + i] / c) * Wo[i];
    acc += bo[0];
    out[g] = 1.f / (1.f + __expf(-acc));
}

extern "C" void kernel_launch(void* const* d_in, const int* in_sizes, int n_in,
                              void* d_out, int out_size, void* d_ws, size_t ws_size,
                              hipStream_t stream) {
    const float* x     = (const float*)d_in[0];
    const int*   ei    = (const int*)d_in[1];
    const int*   batch = (const int*)d_in[2];
    const float* W1    = (const float*)d_in[3];
    const float* attS1 = (const float*)d_in[4];
    const float* attD1 = (const float*)d_in[5];
    const float* b1    = (const float*)d_in[6];
    const float* W2    = (const float*)d_in[7];
    const float* attS2 = (const float*)d_in[8];
    const float* attD2 = (const float*)d_in[9];
    const float* b2    = (const float*)d_in[10];
    const float* Wo    = (const float*)d_in[11];
    const float* bo    = (const float*)d_in[12];
    float* out = (float*)d_out;

    char* p = (char*)d_ws;
    auto alloc = [&](size_t bytes) {
        char* r = p;
        p += (bytes + 255) & ~(size_t)255;
        return (void*)r;
    };
    unsigned char*  h1f8  = (unsigned char*)alloc((size_t)NN * C1);
    unsigned short* xb    = (unsigned short*)alloc((size_t)NN * FIN * 2);
    unsigned short* w1swz = (unsigned short*)alloc((size_t)FIN * C1 * 2);
    unsigned short* z1b   = (unsigned short*)alloc((size_t)NN * C1 * 2);
    unsigned short* h2b   = (unsigned short*)alloc((size_t)NN * HID * 2);
    float* aS1    = (float*)alloc((size_t)NN * HEADS * 4);
    float* aD1    = (float*)alloc((size_t)NN * HEADS * 4);
    float* z2     = (float*)alloc((size_t)NN * HID * 4);
    float* aS2    = (float*)alloc((size_t)NN * 4);
    float* aD2    = (float*)alloc((size_t)NN * 4);
    int*   rowptr = (int*)alloc((size_t)(NN + 1) * 4);
    int*   ssrc   = (int*)alloc((size_t)ET * 4);
    uint2* bkt    = (uint2*)alloc((size_t)NBKT * CAP * 8);
    int*   bbase  = (int*)alloc((size_t)NBKT * 4);
    // zero-init region: bcur + pooled (contiguous)
    int*   bcur   = (int*)alloc((size_t)NBKT * 4);
    float* pooled = (float*)alloc((size_t)NG * HID * 4);
    size_t zero_bytes = (size_t)(p - (char*)bcur);

    hipMemsetAsync(bcur, 0, zero_bytes, stream);
    bkt_scatter_kernel<<<(ET + EPB - 1) / EPB, 256, 0, stream>>>(ei, bcur, bkt);
    bkt_scan_kernel<<<1, 256, 0, stream>>>(bcur, bbase, rowptr);
    csr_kernel<<<NBKT, 256, 0, stream>>>(bkt, bcur, bbase, rowptr, ssrc);
    cvt_x_kernel<<<(NN * FIN / 8 + 255) / 256, 256, 0, stream>>>(x, xb);
    cvt_w1_kernel<<<16, 256, 0, stream>>>(W1, w1swz);
    gemm1_kernel<<<(NN + 63) / 64, 256, 0, stream>>>(xb, w1swz, attS1, attD1, h1f8, aS1, aD1);
    agg1_kernel<<<(NN * 64) / 256, 256, 0, stream>>>(rowptr, ssrc, aS1, aD1, h1f8, b1, z1b);
    gemm2_kernel<<<(NN + 31) / 32, 256, 0, stream>>>(z1b, W2, attS2, attD2, h2b, aS2, aD2);
    agg2_kernel<<<(NN / 2 * 64 + 255) / 256, 256, 0, stream>>>(rowptr, ssrc, aS2, aD2, h2b, b2, z2);
    pool_partial_kernel<<<NG * 16, 256, 0, stream>>>(z2, batch, pooled);
    pool_finish_kernel<<<1, 64, 0, stream>>>(pooled, batch, Wo, bo, out);
}

// Round 8
// 266.932 us; speedup vs baseline: 3.2308x; 1.0174x over previous
//
#include <hip/hip_runtime.h>
#include <hip/hip_bf16.h>
#include <math.h>

#define NN 50000
#define NE 800000
#define ET (NE + NN)
#define FIN 128
#define HEADS 8
#define HID 32
#define C1 (HEADS * HID)   // 256
#define NG 64
#define NEG 0.2f

#define EPB 2048           // edges per block in bucket scatter
#define NBKT 782           // ceil(NN/64)
#define CAP 2048           // slots per bucket (expected ~1087, 2048 is ~29 sigma)

typedef __attribute__((ext_vector_type(8))) unsigned short ushort8_t;
typedef __attribute__((ext_vector_type(4))) unsigned short ushort4_t;
typedef __attribute__((ext_vector_type(2))) float float2_t;
typedef __attribute__((ext_vector_type(8))) short bf16x8;
typedef __attribute__((ext_vector_type(4))) float f32x4;

__device__ __forceinline__ float lrelu(float v) { return v > 0.f ? v : NEG * v; }
__device__ __forceinline__ float elu1(float v)  { return v > 0.f ? v : expm1f(v); }
__device__ __forceinline__ unsigned short f2bf(float f) {
    __hip_bfloat16 b = __float2bfloat16(f);
    return *reinterpret_cast<unsigned short*>(&b);
}
__device__ __forceinline__ float bf2f(unsigned short u) {
    return __uint_as_float(((unsigned)u) << 16);
}
// decode 16 fp8 (uint4) and accumulate e*val into acc[0..16)
__device__ __forceinline__ void dec_fma16(uint4 r, float e, float* acc) {
    float2_t f;
    f = __builtin_amdgcn_cvt_pk_f32_fp8((int)r.x, false); acc[0] += e * f.x; acc[1] += e * f.y;
    f = __builtin_amdgcn_cvt_pk_f32_fp8((int)r.x, true);  acc[2] += e * f.x; acc[3] += e * f.y;
    f = __builtin_amdgcn_cvt_pk_f32_fp8((int)r.y, false); acc[4] += e * f.x; acc[5] += e * f.y;
    f = __builtin_amdgcn_cvt_pk_f32_fp8((int)r.y, true);  acc[6] += e * f.x; acc[7] += e * f.y;
    f = __builtin_amdgcn_cvt_pk_f32_fp8((int)r.z, false); acc[8] += e * f.x; acc[9] += e * f.y;
    f = __builtin_amdgcn_cvt_pk_f32_fp8((int)r.z, true);  acc[10] += e * f.x; acc[11] += e * f.y;
    f = __builtin_amdgcn_cvt_pk_f32_fp8((int)r.w, false); acc[12] += e * f.x; acc[13] += e * f.y;
    f = __builtin_amdgcn_cvt_pk_f32_fp8((int)r.w, true);  acc[14] += e * f.x; acc[15] += e * f.y;
}

// ---------------- CSR build: two-level counting sort ----------------
__global__ __launch_bounds__(256) void bkt_scatter_kernel(const int* __restrict__ ei,
                                                          int* __restrict__ bcur,
                                                          uint2* __restrict__ bkt) {
    __shared__ int es[EPB];
    __shared__ int ed[EPB];
    __shared__ int lh[NBKT];
    int t = threadIdx.x;
    int base = blockIdx.x * EPB;
    int nloc = ET - base; if (nloc > EPB) nloc = EPB;
    for (int i = t; i < NBKT; i += 256) lh[i] = 0;
    __syncthreads();
    for (int k = t; k < nloc; k += 256) {
        int i = base + k;
        int s, d;
        if (i < NE) { s = ei[i]; d = ei[NE + i]; }
        else        { s = i - NE; d = s; }
        es[k] = s; ed[k] = d;
        atomicAdd(&lh[d >> 6], 1);
    }
    __syncthreads();
    for (int i = t; i < NBKT; i += 256) {
        int c = lh[i];
        lh[i] = c ? atomicAdd(&bcur[i], c) : 0;
    }
    __syncthreads();
    for (int k = t; k < nloc; k += 256) {
        int d = ed[k];
        int b = d >> 6;
        int pos = atomicAdd(&lh[b], 1);
        if (pos < CAP) bkt[(size_t)b * CAP + pos] = make_uint2((unsigned)es[k], (unsigned)d);
    }
}

__global__ __launch_bounds__(256) void bkt_scan_kernel(const int* __restrict__ bcur,
                                                       int* __restrict__ bbase,
                                                       int* __restrict__ rowptr) {
    __shared__ int wsum[4];
    int t = threadIdx.x, lane = t & 63, w = t >> 6;
    int idx = t * 4;
    int a0 = (idx + 0 < NBKT) ? bcur[idx + 0] : 0;
    int a1 = (idx + 1 < NBKT) ? bcur[idx + 1] : 0;
    int a2 = (idx + 2 < NBKT) ? bcur[idx + 2] : 0;
    int a3 = (idx + 3 < NBKT) ? bcur[idx + 3] : 0;
    int v = a0 + a1 + a2 + a3;
    int inc = v;
    #pragma unroll
    for (int off = 1; off < 64; off <<= 1) {
        int u = __shfl_up(inc, off, 64);
        if (lane >= off) inc += u;
    }
    if (lane == 63) wsum[w] = inc;
    __syncthreads();
    int woff = 0;
    #pragma unroll
    for (int i = 0; i < 4; ++i) if (i < w) woff += wsum[i];
    int excl = woff + inc - v;
    if (idx + 0 < NBKT) bbase[idx + 0] = excl;
    if (idx + 1 < NBKT) bbase[idx + 1] = excl + a0;
    if (idx + 2 < NBKT) bbase[idx + 2] = excl + a0 + a1;
    if (idx + 3 < NBKT) bbase[idx + 3] = excl + a0 + a1 + a2;
    if (t == 255) rowptr[NN] = woff + inc;   // = ET
}

__global__ __launch_bounds__(256) void csr_kernel(const uint2* __restrict__ bkt,
                                                  const int* __restrict__ bcur,
                                                  const int* __restrict__ bbase,
                                                  int* __restrict__ rowptr,
                                                  int* __restrict__ ssrc) {
    __shared__ int nb[64];
    __shared__ int nc[64];
    int b = blockIdx.x, t = threadIdx.x;
    int cnt = bcur[b]; if (cnt > CAP) cnt = CAP;
    int gbase = bbase[b];
    if (t < 64) nc[t] = 0;
    __syncthreads();
    const uint2* e = bkt + (size_t)b * CAP;
    for (int k = t; k < cnt; k += 256)
        atomicAdd(&nc[e[k].y & 63], 1);
    __syncthreads();
    if (t < 64) {
        int v = nc[t];
        int inc = v;
        #pragma unroll
        for (int off = 1; off < 64; off <<= 1) {
            int u = __shfl_up(inc, off, 64);
            if (t >= off) inc += u;
        }
        int start = gbase + inc - v;
        nb[t] = start;
        int node = b * 64 + t;
        if (node < NN) rowptr[node] = start;
    }
    __syncthreads();
    for (int k = t; k < cnt; k += 256) {
        uint2 ed = e[k];
        int pos = atomicAdd(&nb[ed.y & 63], 1);
        ssrc[pos] = (int)ed.x;
    }
}

// ---------------- x fp32 -> bf16 row-major ----------------
__global__ __launch_bounds__(256) void cvt_x_kernel(const float* __restrict__ x,
                                                    unsigned short* __restrict__ xb) {
    int i = (blockIdx.x * 256 + threadIdx.x) * 8;
    if (i >= NN * FIN) return;
    float4 f0 = *(const float4*)&x[i];
    float4 f1 = *(const float4*)&x[i + 4];
    ushort8_t o;
    o[0] = f2bf(f0.x); o[1] = f2bf(f0.y); o[2] = f2bf(f0.z); o[3] = f2bf(f0.w);
    o[4] = f2bf(f1.x); o[5] = f2bf(f1.y); o[6] = f2bf(f1.z); o[7] = f2bf(f1.w);
    *(ushort8_t*)&xb[i] = o;
}

// ---------------- W1 fp32 -> bf16 swizzled B-fragments ----------------
__global__ __launch_bounds__(256) void cvt_w1_kernel(const float* __restrict__ W1,
                                                     unsigned short* __restrict__ w1swz) {
    int t = blockIdx.x * 256 + threadIdx.x;
    int fid = t >> 6, lane = t & 63;
    int tnt = fid >> 2, ks = fid & 3;
    int n = tnt * 16 + (lane & 15);
    int k0 = ks * 32 + (lane >> 4) * 8;
    ushort8_t o;
    #pragma unroll
    for (int j = 0; j < 8; ++j) o[j] = f2bf(W1[(k0 + j) * C1 + n]);
    *(ushort8_t*)&w1swz[(size_t)(fid * 64 + lane) * 8] = o;
}

// ---------------- GEMM1 (MFMA bf16): h1 = x @ W1 (fp8 out), fused a_src1/a_dst1 ----------------
__global__ __launch_bounds__(256) void gemm1_kernel(
        const unsigned short* __restrict__ xb, const unsigned short* __restrict__ w1swz,
        const float* __restrict__ attS, const float* __restrict__ attD,
        unsigned char* __restrict__ h1f8, float* __restrict__ aS, float* __restrict__ aD) {
    __shared__ float lds[4 * 16 * 132];
    int t = threadIdx.x, w = t >> 6, lane = t & 63;
    int mh = w & 1, nh = w >> 1;
    int m0 = blockIdx.x * 64 + mh * 32;
    int l15 = lane & 15, l4 = lane >> 4;

    f32x4 acc[2][8];
    #pragma unroll
    for (int mt = 0; mt < 2; ++mt)
        #pragma unroll
        for (int nt = 0; nt < 8; ++nt)
            acc[mt][nt] = (f32x4){0.f, 0.f, 0.f, 0.f};

    int ra = m0 + l15;       if (ra >= NN) ra = NN - 1;
    int rb = m0 + 16 + l15;  if (rb >= NN) rb = NN - 1;
    const unsigned short* a0p = xb + (size_t)ra * FIN + l4 * 8;
    const unsigned short* a1p = xb + (size_t)rb * FIN + l4 * 8;

    #pragma unroll
    for (int ks = 0; ks < 4; ++ks) {
        bf16x8 af0 = *(const bf16x8*)(a0p + ks * 32);
        bf16x8 af1 = *(const bf16x8*)(a1p + ks * 32);
        #pragma unroll
        for (int nt = 0; nt < 8; ++nt) {
            bf16x8 bf = *(const bf16x8*)&w1swz[(size_t)(((nh * 8 + nt) * 4 + ks) * 64 + lane) * 8];
            acc[0][nt] = __builtin_amdgcn_mfma_f32_16x16x32_bf16(af0, bf, acc[0][nt], 0, 0, 0);
            acc[1][nt] = __builtin_amdgcn_mfma_f32_16x16x32_bf16(af1, bf, acc[1][nt], 0, 0, 0);
        }
    }

    float* wl = lds + w * 16 * 132;
    #pragma unroll
    for (int mt = 0; mt < 2; ++mt) {
        __syncthreads();
        #pragma unroll
        for (int nt = 0; nt < 8; ++nt)
            #pragma unroll
            for (int r = 0; r < 4; ++r)
                wl[(l4 * 4 + r) * 132 + nt * 16 + l15] = acc[mt][nt][r];
        __syncthreads();
        int row_g = m0 + mt * 16 + l15;
        int cch = l4;
        float v[32];
        #pragma unroll
        for (int i = 0; i < 8; ++i) {
            float4 f = *(const float4*)&wl[l15 * 132 + cch * 32 + i * 4];
            v[i * 4 + 0] = f.x; v[i * 4 + 1] = f.y; v[i * 4 + 2] = f.z; v[i * 4 + 3] = f.w;
        }
        if (row_g < NN) {
            unsigned pk[8];
            #pragma unroll
            for (int i = 0; i < 8; ++i) {
                int p = __builtin_amdgcn_cvt_pk_fp8_f32(v[i * 4 + 0], v[i * 4 + 1], 0, false);
                p = __builtin_amdgcn_cvt_pk_fp8_f32(v[i * 4 + 2], v[i * 4 + 3], p, true);
                pk[i] = (unsigned)p;
            }
            size_t base = (size_t)row_g * C1 + nh * 128 + cch * 32;
            *(uint4*)&h1f8[base]      = make_uint4(pk[0], pk[1], pk[2], pk[3]);
            *(uint4*)&h1f8[base + 16] = make_uint4(pk[4], pk[5], pk[6], pk[7]);
            int h = nh * 4 + cch;
            float ps = 0.f, pd = 0.f;
            #pragma unroll
            for (int i = 0; i < 32; ++i) {
                ps += v[i] * attS[h * 32 + i];
                pd += v[i] * attD[h * 32 + i];
            }
            aS[row_g * HEADS + h] = ps;
            aD[row_g * HEADS + h] = pd;
        }
    }
}

// ---------------- Layer-1 aggregation: quarter-wave per edge, 16B fp8 loads ----------------
__global__ __launch_bounds__(256) void agg1_kernel(
        const int* __restrict__ rowptr, const int* __restrict__ ssrc,
        const float* __restrict__ aS, const float* __restrict__ aD,
        const unsigned char* __restrict__ h1f8, const float* __restrict__ b1,
        unsigned short* __restrict__ z1b) {
    int d = (blockIdx.x * 256 + threadIdx.x) >> 6;
    int lane = threadIdx.x & 63;
    if (d >= NN) return;
    int start = rowptr[d], end = rowptr[d + 1];
    int q = lane >> 4, sl = lane & 15;      // quarter = edge slot, sl = 16-channel chunk
    int h = sl >> 1;                        // head of channels [sl*16, sl*16+16)
    float adh = aD[d * HEADS + h];
    float acc[16];
    #pragma unroll
    for (int i = 0; i < 16; ++i) acc[i] = 0.f;
    float den = 0.f;
    int j = start + q;
    // unroll x2: 2 gathers in flight per quarter (8 per wave)
    for (; j + 4 < end; j += 8) {
        int s0 = ssrc[j], s1 = ssrc[j + 4];
        uint4 r0 = *(const uint4*)&h1f8[(size_t)s0 * C1 + sl * 16];
        uint4 r1 = *(const uint4*)&h1f8[(size_t)s1 * C1 + sl * 16];
        float e0 = __expf(lrelu(aS[s0 * HEADS + h] + adh));
        float e1 = __expf(lrelu(aS[s1 * HEADS + h] + adh));
        den += e0 + e1;
        dec_fma16(r0, e0, acc);
        dec_fma16(r1, e1, acc);
    }
    for (; j < end; j += 4) {
        int s = ssrc[j];
        uint4 r = *(const uint4*)&h1f8[(size_t)s * C1 + sl * 16];
        float e = __expf(lrelu(aS[s * HEADS + h] + adh));
        den += e;
        dec_fma16(r, e, acc);
    }
    // combine quarters
    den += __shfl_xor(den, 16, 64);
    den += __shfl_xor(den, 32, 64);
    #pragma unroll
    for (int i = 0; i < 16; ++i) {
        acc[i] += __shfl_xor(acc[i], 16, 64);
        acc[i] += __shfl_xor(acc[i], 32, 64);
    }
    float invd = 1.f / (den + 1e-16f);
    // store: lane (q,sl) writes channels [sl*16 + q*4, +4)
    int cb = sl * 16 + q * 4;
    float4 bb = *(const float4*)&b1[cb];
    ushort4_t o;
    o[0] = f2bf(elu1(acc[q * 4 + 0] * invd + bb.x));
    o[1] = f2bf(elu1(acc[q * 4 + 1] * invd + bb.y));
    o[2] = f2bf(elu1(acc[q * 4 + 2] * invd + bb.z));
    o[3] = f2bf(elu1(acc[q * 4 + 3] * invd + bb.w));
    *(ushort4_t*)&z1b[(size_t)d * C1 + cb] = o;
}

// ---------------- GEMM2: h2 = z1 @ W2 (bf16 in/out), fused a_src2/a_dst2 ----------------
__global__ __launch_bounds__(256) void gemm2_kernel(
        const unsigned short* __restrict__ z1b, const float* __restrict__ W2,
        const float* __restrict__ attS, const float* __restrict__ attD,
        unsigned short* __restrict__ h2b, float* __restrict__ aS2, float* __restrict__ aD2) {
    __shared__ float zs[32 * 260];
    __shared__ float wc[64 * HID];
    int t = threadIdx.x;
    int n0 = blockIdx.x * 32;
    {
        int f = t * 32, r = f >> 8, c = f & 255;
        if (n0 + r < NN) {
            const ushort8_t* zr = (const ushort8_t*)&z1b[(size_t)(n0 + r) * C1 + c];
            #pragma unroll
            for (int i = 0; i < 4; ++i) {
                ushort8_t u = zr[i];
                *(float4*)&zs[r * 260 + c + i * 8] =
                    make_float4(bf2f(u[0]), bf2f(u[1]), bf2f(u[2]), bf2f(u[3]));
                *(float4*)&zs[r * 260 + c + i * 8 + 4] =
                    make_float4(bf2f(u[4]), bf2f(u[5]), bf2f(u[6]), bf2f(u[7]));
            }
        } else {
            float4 z = make_float4(0.f, 0.f, 0.f, 0.f);
            #pragma unroll
            for (int i = 0; i < 8; ++i) *(float4*)&zs[r * 260 + c + i * 4] = z;
        }
    }
    int tn = t >> 3, tc = t & 7;
    float acc[4] = {0.f, 0.f, 0.f, 0.f};
    for (int kb = 0; kb < 4; ++kb) {
        __syncthreads();
        {
            const float4* w4 = (const float4*)(W2 + kb * 64 * HID);
            float4* s4 = (float4*)wc;
            s4[t] = w4[t]; s4[t + 256] = w4[t + 256];
        }
        __syncthreads();
        for (int k = 0; k < 64; ++k) {
            float zv = zs[tn * 260 + kb * 64 + k];
            float4 w = *(const float4*)&wc[k * HID + tc * 4];
            acc[0] += zv * w.x; acc[1] += zv * w.y;
            acc[2] += zv * w.z; acc[3] += zv * w.w;
        }
    }
    int n = n0 + tn;
    float ps = 0.f, pd = 0.f;
    #pragma unroll
    for (int j = 0; j < 4; ++j) { ps += acc[j] * attS[tc * 4 + j]; pd += acc[j] * attD[tc * 4 + j]; }
    ps += __shfl_xor(ps, 1, 64); ps += __shfl_xor(ps, 2, 64); ps += __shfl_xor(ps, 4, 64);
    pd += __shfl_xor(pd, 1, 64); pd += __shfl_xor(pd, 2, 64); pd += __shfl_xor(pd, 4, 64);
    if (n < NN) {
        ushort4_t o;
        o[0] = f2bf(acc[0]); o[1] = f2bf(acc[1]); o[2] = f2bf(acc[2]); o[3] = f2bf(acc[3]);
        *(ushort4_t*)&h2b[(size_t)n * HID + tc * 4] = o;
        if (tc == 0) { aS2[n] = ps; aD2[n] = pd; }
    }
}

// ---------------- Layer-2 aggregation: quarter-wave per edge, one wave per dst ----------------
__global__ __launch_bounds__(256) void agg2_kernel(
        const int* __restrict__ rowptr, const int* __restrict__ ssrc,
        const float* __restrict__ aS, const float* __restrict__ aD,
        const unsigned short* __restrict__ h2b, const float* __restrict__ b2,
        float* __restrict__ z2) {
    int d = (blockIdx.x * 256 + threadIdx.x) >> 6;
    int lane = threadIdx.x & 63;
    if (d >= NN) return;
    int start = rowptr[d], end = rowptr[d + 1];
    int q = lane >> 4, sl = lane & 15;      // quarter = edge slot, sl = 2-channel chunk
    float adv = aD[d];
    float a0 = 0.f, a1 = 0.f, den = 0.f;
    int j = start + q;
    for (; j + 4 < end; j += 8) {
        int s0 = ssrc[j], s1 = ssrc[j + 4];
        unsigned r0 = *(const unsigned*)&h2b[(size_t)s0 * HID + sl * 2];
        unsigned r1 = *(const unsigned*)&h2b[(size_t)s1 * HID + sl * 2];
        float e0 = __expf(lrelu(aS[s0] + adv));
        float e1 = __expf(lrelu(aS[s1] + adv));
        den += e0 + e1;
        a0 += e0 * bf2f((unsigned short)(r0 & 0xffff));
        a1 += e0 * bf2f((unsigned short)(r0 >> 16));
        a0 += e1 * bf2f((unsigned short)(r1 & 0xffff));
        a1 += e1 * bf2f((unsigned short)(r1 >> 16));
    }
    for (; j < end; j += 4) {
        int s = ssrc[j];
        unsigned r = *(const unsigned*)&h2b[(size_t)s * HID + sl * 2];
        float e = __expf(lrelu(aS[s] + adv));
        den += e;
        a0 += e * bf2f((unsigned short)(r & 0xffff));
        a1 += e * bf2f((unsigned short)(r >> 16));
    }
    den += __shfl_xor(den, 16, 64);
    den += __shfl_xor(den, 32, 64);
    a0 += __shfl_xor(a0, 16, 64); a0 += __shfl_xor(a0, 32, 64);
    a1 += __shfl_xor(a1, 16, 64); a1 += __shfl_xor(a1, 32, 64);
    if (q == 0) {
        float invd = 1.f / (den + 1e-16f);
        float2 o;
        o.x = elu1(a0 * invd + b2[sl * 2]);
        o.y = elu1(a1 * invd + b2[sl * 2 + 1]);
        *(float2*)&z2[(size_t)d * HID + sl * 2] = o;
    }
}

// ---------------- Pool partial: 16 blocks per group, LDS reduce + few atomics ----------------
__global__ __launch_bounds__(256) void pool_partial_kernel(
        const float* __restrict__ z2, const int* __restrict__ batch,
        float* __restrict__ pooled) {
    __shared__ float sm[256];
    int g = blockIdx.x >> 4, slice = blockIdx.x & 15;
    int t = threadIdx.x;
    int lo = 0, hi = NN;
    while (lo < hi) { int m = (lo + hi) >> 1; if (batch[m] < g) lo = m + 1; else hi = m; }
    int start = lo;
    hi = NN;
    while (lo < hi) { int m = (lo + hi) >> 1; if (batch[m] < g + 1) lo = m + 1; else hi = m; }
    int end = lo;
    int len = end - start;
    int s0 = start + (int)(((long long)len * slice) >> 4);
    int s1 = start + (int)(((long long)len * (slice + 1)) >> 4);
    int c = t & 31, r = t >> 5;
    float acc = 0.f;
    for (int n = s0 + r; n < s1; n += 8)
        acc += z2[(size_t)n * HID + c];
    sm[t] = acc;
    __syncthreads();
    if (t < 32) {
        float s = 0.f;
        #pragma unroll
        for (int i = 0; i < 8; ++i) s += sm[t + 32 * i];
        atomicAdd(&pooled[g * HID + t], s);
    }
}

// ---------------- Finish: mean + Wo + sigmoid ----------------
__global__ void pool_finish_kernel(const float* __restrict__ pooled,
                                   const int* __restrict__ batch,
                                   const float* __restrict__ Wo, const float* __restrict__ bo,
                                   float* __restrict__ out) {
    int g = threadIdx.x;
    if (g >= NG) return;
    int lo = 0, hi = NN;
    while (lo < hi) { int m = (lo + hi) >> 1; if (batch[m] < g) lo = m + 1; else hi = m; }
    int start = lo;
    hi = NN;
    while (lo < hi) { int m = (lo + hi) >> 1; if (batch[m] < g + 1) lo = m + 1; else hi = m; }
    int end = lo;
    float c = fmaxf((float)(end - start), 1.f);
    float acc = 0.f;
    for (int i = 0; i < HID; ++i) acc += (pooled[g * HID + i] / c) * Wo[i];
    acc += bo[0];
    out[g] = 1.f / (1.f + __expf(-acc));
}

extern "C" void kernel_launch(void* const* d_in, const int* in_sizes, int n_in,
                              void* d_out, int out_size, void* d_ws, size_t ws_size,
                              hipStream_t stream) {
    const float* x     = (const float*)d_in[0];
    const int*   ei    = (const int*)d_in[1];
    const int*   batch = (const int*)d_in[2];
    const float* W1    = (const float*)d_in[3];
    const float* attS1 = (const float*)d_in[4];
    const float* attD1 = (const float*)d_in[5];
    const float* b1    = (const float*)d_in[6];
    const float* W2    = (const float*)d_in[7];
    const float* attS2 = (const float*)d_in[8];
    const float* attD2 = (const float*)d_in[9];
    const float* b2    = (const float*)d_in[10];
    const float* Wo    = (const float*)d_in[11];
    const float* bo    = (const float*)d_in[12];
    float* out = (float*)d_out;

    char* p = (char*)d_ws;
    auto alloc = [&](size_t bytes) {
        char* r = p;
        p += (bytes + 255) & ~(size_t)255;
        return (void*)r;
    };
    unsigned char*  h1f8  = (unsigned char*)alloc((size_t)NN * C1);
    unsigned short* xb    = (unsigned short*)alloc((size_t)NN * FIN * 2);
    unsigned short* w1swz = (unsigned short*)alloc((size_t)FIN * C1 * 2);
    unsigned short* z1b   = (unsigned short*)alloc((size_t)NN * C1 * 2);
    unsigned short* h2b   = (unsigned short*)alloc((size_t)NN * HID * 2);
    float* aS1    = (float*)alloc((size_t)NN * HEADS * 4);
    float* aD1    = (float*)alloc((size_t)NN * HEADS * 4);
    float* z2     = (float*)alloc((size_t)NN * HID * 4);
    float* aS2    = (float*)alloc((size_t)NN * 4);
    float* aD2    = (float*)alloc((size_t)NN * 4);
    int*   rowptr = (int*)alloc((size_t)(NN + 1) * 4);
    int*   ssrc   = (int*)alloc((size_t)ET * 4);
    uint2* bkt    = (uint2*)alloc((size_t)NBKT * CAP * 8);
    int*   bbase  = (int*)alloc((size_t)NBKT * 4);
    // zero-init region: bcur + pooled (contiguous)
    int*   bcur   = (int*)alloc((size_t)NBKT * 4);
    float* pooled = (float*)alloc((size_t)NG * HID * 4);
    size_t zero_bytes = (size_t)(p - (char*)bcur);

    hipMemsetAsync(bcur, 0, zero_bytes, stream);
    bkt_scatter_kernel<<<(ET + EPB - 1) / EPB, 256, 0, stream>>>(ei, bcur, bkt);
    bkt_scan_kernel<<<1, 256, 0, stream>>>(bcur, bbase, rowptr);
    csr_kernel<<<NBKT, 256, 0, stream>>>(bkt, bcur, bbase, rowptr, ssrc);
    cvt_x_kernel<<<(NN * FIN / 8 + 255) / 256, 256, 0, stream>>>(x, xb);
    cvt_w1_kernel<<<16, 256, 0, stream>>>(W1, w1swz);
    gemm1_kernel<<<(NN + 63) / 64, 256, 0, stream>>>(xb, w1swz, attS1, attD1, h1f8, aS1, aD1);
    agg1_kernel<<<(NN * 64) / 256, 256, 0, stream>>>(rowptr, ssrc, aS1, aD1, h1f8, b1, z1b);
    gemm2_kernel<<<(NN + 31) / 32, 256, 0, stream>>>(z1b, W2, attS2, attD2, h2b, aS2, aD2);
    agg2_kernel<<<(NN * 64 + 255) / 256, 256, 0, stream>>>(rowptr, ssrc, aS2, aD2, h2b, b2, z2);
    pool_partial_kernel<<<NG * 16, 256, 0, stream>>>(z2, batch, pooled);
    pool_finish_kernel<<<1, 64, 0, stream>>>(pooled, batch, Wo, bo, out);
}

// Round 9
// 244.009 us; speedup vs baseline: 3.5343x; 1.0939x over previous
//
#include <hip/hip_runtime.h>
#include <hip/hip_bf16.h>
#include <math.h>

#define NN 50000
#define NE 800000
#define ET (NE + NN)
#define FIN 128
#define HEADS 8
#define HID 32
#define C1 (HEADS * HID)   // 256
#define NG 64
#define NEG 0.2f

#define EPB 4096           // edges per block in bucket scatter
#define NBKT 782           // ceil(NN/64)
#define CAP 2048           // slots per bucket (expected ~1087)

typedef __attribute__((ext_vector_type(8))) unsigned short ushort8_t;
typedef __attribute__((ext_vector_type(4))) unsigned short ushort4_t;
typedef __attribute__((ext_vector_type(2))) float float2_t;
typedef __attribute__((ext_vector_type(8))) short bf16x8;
typedef __attribute__((ext_vector_type(4))) float f32x4;

__device__ __forceinline__ float lrelu(float v) { return v > 0.f ? v : NEG * v; }
__device__ __forceinline__ float elu1(float v)  { return v > 0.f ? v : expm1f(v); }
__device__ __forceinline__ unsigned short f2bf(float f) {
    __hip_bfloat16 b = __float2bfloat16(f);
    return *reinterpret_cast<unsigned short*>(&b);
}
__device__ __forceinline__ float bf2f(unsigned short u) {
    return __uint_as_float(((unsigned)u) << 16);
}
// decode 16 fp8 (uint4), accumulate e*val into 8 float2 accumulators (v_pk_fma_f32)
__device__ __forceinline__ void dec_fma16(uint4 r, float e, float2_t* acc) {
    float2_t ev = {e, e};
    acc[0] += ev * __builtin_amdgcn_cvt_pk_f32_fp8((int)r.x, false);
    acc[1] += ev * __builtin_amdgcn_cvt_pk_f32_fp8((int)r.x, true);
    acc[2] += ev * __builtin_amdgcn_cvt_pk_f32_fp8((int)r.y, false);
    acc[3] += ev * __builtin_amdgcn_cvt_pk_f32_fp8((int)r.y, true);
    acc[4] += ev * __builtin_amdgcn_cvt_pk_f32_fp8((int)r.z, false);
    acc[5] += ev * __builtin_amdgcn_cvt_pk_f32_fp8((int)r.z, true);
    acc[6] += ev * __builtin_amdgcn_cvt_pk_f32_fp8((int)r.w, false);
    acc[7] += ev * __builtin_amdgcn_cvt_pk_f32_fp8((int)r.w, true);
}

// ---------------- CSR build: two-level counting sort (packed uint entries) ----------------
// packed edge: s(16 bits) | (d&63)<<16 | (d>>6)<<22  — NN<65536, NBKT<1024
__global__ __launch_bounds__(256) void bkt_scatter_kernel(const int* __restrict__ ei,
                                                          int* __restrict__ bcur,
                                                          unsigned* __restrict__ bkt) {
    __shared__ unsigned ep[EPB];   // 16 KB
    __shared__ int lh[NBKT];       // 3.1 KB
    int t = threadIdx.x;
    int base = blockIdx.x * EPB;
    int nloc = ET - base; if (nloc > EPB) nloc = EPB;
    for (int i = t; i < NBKT; i += 256) lh[i] = 0;
    __syncthreads();
    for (int k = t; k < nloc; k += 256) {
        int i = base + k;
        int s, d;
        if (i < NE) { s = ei[i]; d = ei[NE + i]; }
        else        { s = i - NE; d = s; }
        ep[k] = (unsigned)s | ((unsigned)(d & 63) << 16) | ((unsigned)(d >> 6) << 22);
        atomicAdd(&lh[d >> 6], 1);
    }
    __syncthreads();
    for (int i = t; i < NBKT; i += 256) {
        int c = lh[i];
        lh[i] = c ? atomicAdd(&bcur[i], c) : 0;
    }
    __syncthreads();
    for (int k = t; k < nloc; k += 256) {
        unsigned v = ep[k];
        int b = (int)(v >> 22);
        int pos = atomicAdd(&lh[b], 1);
        if (pos < CAP) bkt[(size_t)b * CAP + pos] = v & 0x3FFFFFu;  // s | dl<<16
    }
}

__global__ __launch_bounds__(256) void bkt_scan_kernel(const int* __restrict__ bcur,
                                                       int* __restrict__ bbase,
                                                       int* __restrict__ rowptr) {
    __shared__ int wsum[4];
    int t = threadIdx.x, lane = t & 63, w = t >> 6;
    int idx = t * 4;
    int a0 = (idx + 0 < NBKT) ? bcur[idx + 0] : 0;
    int a1 = (idx + 1 < NBKT) ? bcur[idx + 1] : 0;
    int a2 = (idx + 2 < NBKT) ? bcur[idx + 2] : 0;
    int a3 = (idx + 3 < NBKT) ? bcur[idx + 3] : 0;
    int v = a0 + a1 + a2 + a3;
    int inc = v;
    #pragma unroll
    for (int off = 1; off < 64; off <<= 1) {
        int u = __shfl_up(inc, off, 64);
        if (lane >= off) inc += u;
    }
    if (lane == 63) wsum[w] = inc;
    __syncthreads();
    int woff = 0;
    #pragma unroll
    for (int i = 0; i < 4; ++i) if (i < w) woff += wsum[i];
    int excl = woff + inc - v;
    if (idx + 0 < NBKT) bbase[idx + 0] = excl;
    if (idx + 1 < NBKT) bbase[idx + 1] = excl + a0;
    if (idx + 2 < NBKT) bbase[idx + 2] = excl + a0 + a1;
    if (idx + 3 < NBKT) bbase[idx + 3] = excl + a0 + a1 + a2;
    if (t == 255) rowptr[NN] = woff + inc;   // = ET
}

__global__ __launch_bounds__(256) void csr_kernel(const unsigned* __restrict__ bkt,
                                                  const int* __restrict__ bcur,
                                                  const int* __restrict__ bbase,
                                                  int* __restrict__ rowptr,
                                                  int* __restrict__ ssrc) {
    __shared__ int nb[64];
    __shared__ int nc[64];
    int b = blockIdx.x, t = threadIdx.x;
    int cnt = bcur[b]; if (cnt > CAP) cnt = CAP;
    int gbase = bbase[b];
    if (t < 64) nc[t] = 0;
    __syncthreads();
    const unsigned* e = bkt + (size_t)b * CAP;
    for (int k = t; k < cnt; k += 256)
        atomicAdd(&nc[e[k] >> 16], 1);
    __syncthreads();
    if (t < 64) {
        int v = nc[t];
        int inc = v;
        #pragma unroll
        for (int off = 1; off < 64; off <<= 1) {
            int u = __shfl_up(inc, off, 64);
            if (t >= off) inc += u;
        }
        int start = gbase + inc - v;
        nb[t] = start;
        int node = b * 64 + t;
        if (node < NN) rowptr[node] = start;
    }
    __syncthreads();
    for (int k = t; k < cnt; k += 256) {
        unsigned v = e[k];
        int pos = atomicAdd(&nb[v >> 16], 1);
        ssrc[pos] = (int)(v & 0xFFFFu);
    }
}

// ---------------- W1 fp32 -> bf16 swizzled B-fragments ----------------
__global__ __launch_bounds__(256) void cvt_w1_kernel(const float* __restrict__ W1,
                                                     unsigned short* __restrict__ w1swz) {
    int t = blockIdx.x * 256 + threadIdx.x;
    int fid = t >> 6, lane = t & 63;
    int tnt = fid >> 2, ks = fid & 3;
    int n = tnt * 16 + (lane & 15);
    int k0 = ks * 32 + (lane >> 4) * 8;
    ushort8_t o;
    #pragma unroll
    for (int j = 0; j < 8; ++j) o[j] = f2bf(W1[(k0 + j) * C1 + n]);
    *(ushort8_t*)&w1swz[(size_t)(fid * 64 + lane) * 8] = o;
}

// ---------------- W2 fp32 -> bf16 swizzled B-fragments (nt 0..1, ks 0..7) ----------------
__global__ __launch_bounds__(256) void cvt_w2_kernel(const float* __restrict__ W2,
                                                     unsigned short* __restrict__ w2swz) {
    int t = blockIdx.x * 256 + threadIdx.x;   // 1024 threads
    int fid = t >> 6, lane = t & 63;          // fid 0..15
    int nt = fid >> 3, ks = fid & 7;
    int n = nt * 16 + (lane & 15);
    int k0 = ks * 32 + (lane >> 4) * 8;
    ushort8_t o;
    #pragma unroll
    for (int j = 0; j < 8; ++j) o[j] = f2bf(W2[(k0 + j) * HID + n]);
    *(ushort8_t*)&w2swz[(size_t)(fid * 64 + lane) * 8] = o;
}

// ---------------- GEMM1 (MFMA bf16, f32 x in): h1 = x @ W1 (fp8 out), fused att1 ----------------
__global__ __launch_bounds__(256) void gemm1_kernel(
        const float* __restrict__ x, const unsigned short* __restrict__ w1swz,
        const float* __restrict__ attS, const float* __restrict__ attD,
        unsigned char* __restrict__ h1f8, float* __restrict__ aS, float* __restrict__ aD) {
    __shared__ float lds[4 * 16 * 132];
    int t = threadIdx.x, w = t >> 6, lane = t & 63;
    int mh = w & 1, nh = w >> 1;
    int m0 = blockIdx.x * 64 + mh * 32;
    int l15 = lane & 15, l4 = lane >> 4;

    f32x4 acc[2][8];
    #pragma unroll
    for (int mt = 0; mt < 2; ++mt)
        #pragma unroll
        for (int nt = 0; nt < 8; ++nt)
            acc[mt][nt] = (f32x4){0.f, 0.f, 0.f, 0.f};

    int ra = m0 + l15;       if (ra >= NN) ra = NN - 1;
    int rb = m0 + 16 + l15;  if (rb >= NN) rb = NN - 1;
    const float* a0p = x + (size_t)ra * FIN + l4 * 8;
    const float* a1p = x + (size_t)rb * FIN + l4 * 8;

    #pragma unroll
    for (int ks = 0; ks < 4; ++ks) {
        float4 f00 = *(const float4*)(a0p + ks * 32);
        float4 f01 = *(const float4*)(a0p + ks * 32 + 4);
        float4 f10 = *(const float4*)(a1p + ks * 32);
        float4 f11 = *(const float4*)(a1p + ks * 32 + 4);
        bf16x8 af0, af1;
        af0[0] = (short)f2bf(f00.x); af0[1] = (short)f2bf(f00.y);
        af0[2] = (short)f2bf(f00.z); af0[3] = (short)f2bf(f00.w);
        af0[4] = (short)f2bf(f01.x); af0[5] = (short)f2bf(f01.y);
        af0[6] = (short)f2bf(f01.z); af0[7] = (short)f2bf(f01.w);
        af1[0] = (short)f2bf(f10.x); af1[1] = (short)f2bf(f10.y);
        af1[2] = (short)f2bf(f10.z); af1[3] = (short)f2bf(f10.w);
        af1[4] = (short)f2bf(f11.x); af1[5] = (short)f2bf(f11.y);
        af1[6] = (short)f2bf(f11.z); af1[7] = (short)f2bf(f11.w);
        #pragma unroll
        for (int nt = 0; nt < 8; ++nt) {
            bf16x8 bf = *(const bf16x8*)&w1swz[(size_t)(((nh * 8 + nt) * 4 + ks) * 64 + lane) * 8];
            acc[0][nt] = __builtin_amdgcn_mfma_f32_16x16x32_bf16(af0, bf, acc[0][nt], 0, 0, 0);
            acc[1][nt] = __builtin_amdgcn_mfma_f32_16x16x32_bf16(af1, bf, acc[1][nt], 0, 0, 0);
        }
    }

    float* wl = lds + w * 16 * 132;
    #pragma unroll
    for (int mt = 0; mt < 2; ++mt) {
        __syncthreads();
        #pragma unroll
        for (int nt = 0; nt < 8; ++nt)
            #pragma unroll
            for (int r = 0; r < 4; ++r)
                wl[(l4 * 4 + r) * 132 + nt * 16 + l15] = acc[mt][nt][r];
        __syncthreads();
        int row_g = m0 + mt * 16 + l15;
        int cch = l4;
        float v[32];
        #pragma unroll
        for (int i = 0; i < 8; ++i) {
            float4 f = *(const float4*)&wl[l15 * 132 + cch * 32 + i * 4];
            v[i * 4 + 0] = f.x; v[i * 4 + 1] = f.y; v[i * 4 + 2] = f.z; v[i * 4 + 3] = f.w;
        }
        if (row_g < NN) {
            unsigned pk[8];
            #pragma unroll
            for (int i = 0; i < 8; ++i) {
                int p = __builtin_amdgcn_cvt_pk_fp8_f32(v[i * 4 + 0], v[i * 4 + 1], 0, false);
                p = __builtin_amdgcn_cvt_pk_fp8_f32(v[i * 4 + 2], v[i * 4 + 3], p, true);
                pk[i] = (unsigned)p;
            }
            size_t base = (size_t)row_g * C1 + nh * 128 + cch * 32;
            *(uint4*)&h1f8[base]      = make_uint4(pk[0], pk[1], pk[2], pk[3]);
            *(uint4*)&h1f8[base + 16] = make_uint4(pk[4], pk[5], pk[6], pk[7]);
            int h = nh * 4 + cch;
            float ps = 0.f, pd = 0.f;
            #pragma unroll
            for (int i = 0; i < 32; ++i) {
                ps += v[i] * attS[h * 32 + i];
                pd += v[i] * attD[h * 32 + i];
            }
            aS[row_g * HEADS + h] = ps;
            aD[row_g * HEADS + h] = pd;
        }
    }
}

// ---------------- Layer-1 aggregation: quarter-wave per edge, pk_fma accumulate ----------------
__global__ __launch_bounds__(256) void agg1_kernel(
        const int* __restrict__ rowptr, const int* __restrict__ ssrc,
        const float* __restrict__ aS, const float* __restrict__ aD,
        const unsigned char* __restrict__ h1f8, const float* __restrict__ b1,
        unsigned short* __restrict__ z1b) {
    int d = (blockIdx.x * 256 + threadIdx.x) >> 6;
    int lane = threadIdx.x & 63;
    if (d >= NN) return;
    int start = rowptr[d], end = rowptr[d + 1];
    int q = lane >> 4, sl = lane & 15;
    int h = sl >> 1;
    float adh = aD[d * HEADS + h];
    float2_t acc[8];
    #pragma unroll
    for (int i = 0; i < 8; ++i) acc[i] = (float2_t){0.f, 0.f};
    float den = 0.f;
    int j = start + q;
    for (; j + 4 < end; j += 8) {
        int s0 = ssrc[j], s1 = ssrc[j + 4];
        uint4 r0 = *(const uint4*)&h1f8[(size_t)s0 * C1 + sl * 16];
        uint4 r1 = *(const uint4*)&h1f8[(size_t)s1 * C1 + sl * 16];
        float e0 = __expf(lrelu(aS[s0 * HEADS + h] + adh));
        float e1 = __expf(lrelu(aS[s1 * HEADS + h] + adh));
        den += e0 + e1;
        dec_fma16(r0, e0, acc);
        dec_fma16(r1, e1, acc);
    }
    for (; j < end; j += 4) {
        int s = ssrc[j];
        uint4 r = *(const uint4*)&h1f8[(size_t)s * C1 + sl * 16];
        float e = __expf(lrelu(aS[s * HEADS + h] + adh));
        den += e;
        dec_fma16(r, e, acc);
    }
    den += __shfl_xor(den, 16, 64);
    den += __shfl_xor(den, 32, 64);
    #pragma unroll
    for (int i = 0; i < 8; ++i) {
        acc[i].x += __shfl_xor(acc[i].x, 16, 64);
        acc[i].y += __shfl_xor(acc[i].y, 16, 64);
        acc[i].x += __shfl_xor(acc[i].x, 32, 64);
        acc[i].y += __shfl_xor(acc[i].y, 32, 64);
    }
    float invd = 1.f / (den + 1e-16f);
    int cb = sl * 16 + q * 4;
    float4 bb = *(const float4*)&b1[cb];
    ushort4_t o;
    o[0] = f2bf(elu1(acc[q * 2 + 0].x * invd + bb.x));
    o[1] = f2bf(elu1(acc[q * 2 + 0].y * invd + bb.y));
    o[2] = f2bf(elu1(acc[q * 2 + 1].x * invd + bb.z));
    o[3] = f2bf(elu1(acc[q * 2 + 1].y * invd + bb.w));
    *(ushort4_t*)&z1b[(size_t)d * C1 + cb] = o;
}

// ---------------- GEMM2 (MFMA bf16): h2 = z1 @ W2 (bf16 out), fused att2 ----------------
// block = 256 (4 waves), each wave 16 rows; N=32 = 2 col-tiles; K=256 = 8 ks steps.
__global__ __launch_bounds__(256) void gemm2_kernel(
        const unsigned short* __restrict__ z1b, const unsigned short* __restrict__ w2swz,
        const float* __restrict__ attS, const float* __restrict__ attD,
        unsigned short* __restrict__ h2b, float* __restrict__ aS2, float* __restrict__ aD2) {
    __shared__ float lds[4 * 16 * 36];   // per-wave 16x36 transpose tile (9.2 KB)
    int t = threadIdx.x, w = t >> 6, lane = t & 63;
    int m0 = blockIdx.x * 64 + w * 16;
    int l15 = lane & 15, l4 = lane >> 4;

    f32x4 acc[2];
    acc[0] = (f32x4){0.f, 0.f, 0.f, 0.f};
    acc[1] = (f32x4){0.f, 0.f, 0.f, 0.f};

    int ra = m0 + l15; if (ra >= NN) ra = NN - 1;
    const unsigned short* ap = z1b + (size_t)ra * C1 + l4 * 8;

    #pragma unroll
    for (int ks = 0; ks < 8; ++ks) {
        bf16x8 af = *(const bf16x8*)(ap + ks * 32);
        #pragma unroll
        for (int nt = 0; nt < 2; ++nt) {
            bf16x8 bf = *(const bf16x8*)&w2swz[(size_t)((nt * 8 + ks) * 64 + lane) * 8];
            acc[nt] = __builtin_amdgcn_mfma_f32_16x16x32_bf16(af, bf, acc[nt], 0, 0, 0);
        }
    }
    // transpose via per-wave LDS tile: row_local = l4*4+r, col = nt*16+l15
    float* wl = lds + w * 16 * 36;
    #pragma unroll
    for (int nt = 0; nt < 2; ++nt)
        #pragma unroll
        for (int r = 0; r < 4; ++r)
            wl[(l4 * 4 + r) * 36 + nt * 16 + l15] = acc[nt][r];
    __syncthreads();   // also covers cross-wave none; ensures lgkm drain
    // lane (l4,l15): row l15, channel chunk l4*8
    int row_g = m0 + l15;
    float v[8];
    {
        float4 f0 = *(const float4*)&wl[l15 * 36 + l4 * 8];
        float4 f1 = *(const float4*)&wl[l15 * 36 + l4 * 8 + 4];
        v[0] = f0.x; v[1] = f0.y; v[2] = f0.z; v[3] = f0.w;
        v[4] = f1.x; v[5] = f1.y; v[6] = f1.z; v[7] = f1.w;
    }
    float ps = 0.f, pd = 0.f;
    #pragma unroll
    for (int i = 0; i < 8; ++i) {
        ps += v[i] * attS[l4 * 8 + i];
        pd += v[i] * attD[l4 * 8 + i];
    }
    ps += __shfl_xor(ps, 16, 64); ps += __shfl_xor(ps, 32, 64);
    pd += __shfl_xor(pd, 16, 64); pd += __shfl_xor(pd, 32, 64);
    if (row_g < NN) {
        ushort8_t o;
        #pragma unroll
        for (int i = 0; i < 8; ++i) o[i] = f2bf(v[i]);
        *(ushort8_t*)&h2b[(size_t)row_g * HID + l4 * 8] = o;
        if (l4 == 0) { aS2[row_g] = ps; aD2[row_g] = pd; }
    }
}

// ---------------- Layer-2 aggregation: quarter-wave per edge ----------------
__global__ __launch_bounds__(256) void agg2_kernel(
        const int* __restrict__ rowptr, const int* __restrict__ ssrc,
        const float* __restrict__ aS, const float* __restrict__ aD,
        const unsigned short* __restrict__ h2b, const float* __restrict__ b2,
        float* __restrict__ z2) {
    int d = (blockIdx.x * 256 + threadIdx.x) >> 6;
    int lane = threadIdx.x & 63;
    if (d >= NN) return;
    int start = rowptr[d], end = rowptr[d + 1];
    int q = lane >> 4, sl = lane & 15;
    float adv = aD[d];
    float2_t a = {0.f, 0.f};
    float den = 0.f;
    int j = start + q;
    for (; j + 4 < end; j += 8) {
        int s0 = ssrc[j], s1 = ssrc[j + 4];
        unsigned r0 = *(const unsigned*)&h2b[(size_t)s0 * HID + sl * 2];
        unsigned r1 = *(const unsigned*)&h2b[(size_t)s1 * HID + sl * 2];
        float e0 = __expf(lrelu(aS[s0] + adv));
        float e1 = __expf(lrelu(aS[s1] + adv));
        den += e0 + e1;
        float2_t v0 = {bf2f((unsigned short)(r0 & 0xffff)), bf2f((unsigned short)(r0 >> 16))};
        float2_t v1 = {bf2f((unsigned short)(r1 & 0xffff)), bf2f((unsigned short)(r1 >> 16))};
        a += (float2_t){e0, e0} * v0;
        a += (float2_t){e1, e1} * v1;
    }
    for (; j < end; j += 4) {
        int s = ssrc[j];
        unsigned r = *(const unsigned*)&h2b[(size_t)s * HID + sl * 2];
        float e = __expf(lrelu(aS[s] + adv));
        den += e;
        float2_t v = {bf2f((unsigned short)(r & 0xffff)), bf2f((unsigned short)(r >> 16))};
        a += (float2_t){e, e} * v;
    }
    den += __shfl_xor(den, 16, 64);
    den += __shfl_xor(den, 32, 64);
    a.x += __shfl_xor(a.x, 16, 64); a.x += __shfl_xor(a.x, 32, 64);
    a.y += __shfl_xor(a.y, 16, 64); a.y += __shfl_xor(a.y, 32, 64);
    if (q == 0) {
        float invd = 1.f / (den + 1e-16f);
        float2 o;
        o.x = elu1(a.x * invd + b2[sl * 2]);
        o.y = elu1(a.y * invd + b2[sl * 2 + 1]);
        *(float2*)&z2[(size_t)d * HID + sl * 2] = o;
    }
}

// ---------------- Pool partial: 16 blocks per group, LDS reduce + few atomics ----------------
__global__ __launch_bounds__(256) void pool_partial_kernel(
        const float* __restrict__ z2, const int* __restrict__ batch,
        float* __restrict__ pooled) {
    __shared__ float sm[256];
    int g = blockIdx.x >> 4, slice = blockIdx.x & 15;
    int t = threadIdx.x;
    int lo = 0, hi = NN;
    while (lo < hi) { int m = (lo + hi) >> 1; if (batch[m] < g) lo = m + 1; else hi = m; }
    int start = lo;
    hi = NN;
    while (lo < hi) { int m = (lo + hi) >> 1; if (batch[m] < g + 1) lo = m + 1; else hi = m; }
    int end = lo;
    int len = end - start;
    int s0 = start + (int)(((long long)len * slice) >> 4);
    int s1 = start + (int)(((long long)len * (slice + 1)) >> 4);
    int c = t & 31, r = t >> 5;
    float acc = 0.f;
    for (int n = s0 + r; n < s1; n += 8)
        acc += z2[(size_t)n * HID + c];
    sm[t] = acc;
    __syncthreads();
    if (t < 32) {
        float s = 0.f;
        #pragma unroll
        for (int i = 0; i < 8; ++i) s += sm[t + 32 * i];
        atomicAdd(&pooled[g * HID + t], s);
    }
}

// ---------------- Finish: mean + Wo + sigmoid ----------------
__global__ void pool_finish_kernel(const float* __restrict__ pooled,
                                   const int* __restrict__ batch,
                                   const float* __restrict__ Wo, const float* __restrict__ bo,
                                   float* __restrict__ out) {
    int g = threadIdx.x;
    if (g >= NG) return;
    int lo = 0, hi = NN;
    while (lo < hi) { int m = (lo + hi) >> 1; if (batch[m] < g) lo = m + 1; else hi = m; }
    int start = lo;
    hi = NN;
    while (lo < hi) { int m = (lo + hi) >> 1; if (batch[m] < g + 1) lo = m + 1; else hi = m; }
    int end = lo;
    float c = fmaxf((float)(end - start), 1.f);
    float acc = 0.f;
    for (int i = 0; i < HID; ++i) acc += (pooled[g * HID + i] / c) * Wo[i];
    acc += bo[0];
    out[g] = 1.f / (1.f + __expf(-acc));
}

extern "C" void kernel_launch(void* const* d_in, const int* in_sizes, int n_in,
                              void* d_out, int out_size, void* d_ws, size_t ws_size,
                              hipStream_t stream) {
    const float* x     = (const float*)d_in[0];
    const int*   ei    = (const int*)d_in[1];
    const int*   batch = (const int*)d_in[2];
    const float* W1    = (const float*)d_in[3];
    const float* attS1 = (const float*)d_in[4];
    const float* attD1 = (const float*)d_in[5];
    const float* b1    = (const float*)d_in[6];
    const float* W2    = (const float*)d_in[7];
    const float* attS2 = (const float*)d_in[8];
    const float* attD2 = (const float*)d_in[9];
    const float* b2    = (const float*)d_in[10];
    const float* Wo    = (const float*)d_in[11];
    const float* bo    = (const float*)d_in[12];
    float* out = (float*)d_out;

    char* p = (char*)d_ws;
    auto alloc = [&](size_t bytes) {
        char* r = p;
        p += (bytes + 255) & ~(size_t)255;
        return (void*)r;
    };
    unsigned char*  h1f8  = (unsigned char*)alloc((size_t)NN * C1);
    unsigned short* w1swz = (unsigned short*)alloc((size_t)FIN * C1 * 2);
    unsigned short* w2swz = (unsigned short*)alloc((size_t)C1 * HID * 2);
    unsigned short* z1b   = (unsigned short*)alloc((size_t)NN * C1 * 2);
    unsigned short* h2b   = (unsigned short*)alloc((size_t)NN * HID * 2);
    float* aS1    = (float*)alloc((size_t)NN * HEADS * 4);
    float* aD1    = (float*)alloc((size_t)NN * HEADS * 4);
    float* z2     = (float*)alloc((size_t)NN * HID * 4);
    float* aS2    = (float*)alloc((size_t)NN * 4);
    float* aD2    = (float*)alloc((size_t)NN * 4);
    int*   rowptr = (int*)alloc((size_t)(NN + 1) * 4);
    int*   ssrc   = (int*)alloc((size_t)ET * 4);
    unsigned* bkt = (unsigned*)alloc((size_t)NBKT * CAP * 4);
    int*   bbase  = (int*)alloc((size_t)NBKT * 4);
    // zero-init region: bcur + pooled (contiguous)
    int*   bcur   = (int*)alloc((size_t)NBKT * 4);
    float* pooled = (float*)alloc((size_t)NG * HID * 4);
    size_t zero_bytes = (size_t)(p - (char*)bcur);

    hipMemsetAsync(bcur, 0, zero_bytes, stream);
    bkt_scatter_kernel<<<(ET + EPB - 1) / EPB, 256, 0, stream>>>(ei, bcur, bkt);
    bkt_scan_kernel<<<1, 256, 0, stream>>>(bcur, bbase, rowptr);
    csr_kernel<<<NBKT, 256, 0, stream>>>(bkt, bcur, bbase, rowptr, ssrc);
    cvt_w1_kernel<<<16, 256, 0, stream>>>(W1, w1swz);
    cvt_w2_kernel<<<4, 256, 0, stream>>>(W2, w2swz);
    gemm1_kernel<<<(NN + 63) / 64, 256, 0, stream>>>(x, w1swz, attS1, attD1, h1f8, aS1, aD1);
    agg1_kernel<<<(NN * 64) / 256, 256, 0, stream>>>(rowptr, ssrc, aS1, aD1, h1f8, b1, z1b);
    gemm2_kernel<<<(NN + 63) / 64, 256, 0, stream>>>(z1b, w2swz, attS2, attD2, h2b, aS2, aD2);
    agg2_kernel<<<(NN * 64 + 255) / 256, 256, 0, stream>>>(rowptr, ssrc, aS2, aD2, h2b, b2, z2);
    pool_partial_kernel<<<NG * 16, 256, 0, stream>>>(z2, batch, pooled);
    pool_finish_kernel<<<1, 64, 0, stream>>>(pooled, batch, Wo, bo, out);
}